// Round 7
// baseline (576.554 us; speedup 1.0000x reference)
//
#include <hip/hip_runtime.h>

// Problem constants
static constexpr int L_ = 3, B_ = 8, C_ = 64, N_ = 1024;
static constexpr int PLANE = C_ * N_;       // 65536
static constexpr int SZ    = L_ * B_ * PLANE; // 1572864 (srcs size, also per-stack-slot count)
static constexpr int BPL   = B_ * PLANE;    // 524288

#define DI __device__ __forceinline__

typedef __attribute__((ext_vector_type(8))) short short8;   // 8 bf16 (MFMA A/B frag)
typedef __attribute__((ext_vector_type(4))) float f32x4;    // MFMA C/D frag
typedef unsigned int uint32;

DI float wred_sum(float v) {
#pragma unroll
  for (int m = 1; m < 64; m <<= 1) v += __shfl_xor(v, m, 64);
  return v;
}

// bf16 helpers (RNE)
DI unsigned short f2bf(float f) {
  uint32 u = __builtin_bit_cast(uint32, f);
  return (unsigned short)((u + 0x7FFFu + ((u >> 16) & 1u)) >> 16);
}
DI float bf2f(unsigned short h) {
  uint32 u = ((uint32)h) << 16;
  return __builtin_bit_cast(float, u);
}
DI uint32 pkbf(float a, float b) {
  return (uint32)f2bf(a) | ((uint32)f2bf(b) << 16);
}
DI short8 bcs8(uint4 v) { return __builtin_bit_cast(short8, v); }

DI f32x4 mfma16(short8 a, short8 b, f32x4 c) {
  return __builtin_amdgcn_mfma_f32_16x16x32_bf16(a, b, c, 0, 0, 0);
}

// ---------------------------------------------------------------------------
// Weight transpose: w[co][ci][k9] -> wT[ci][k9][co]  (64 x 128 x 9 each)
// grid (288, 2)
// ---------------------------------------------------------------------------
__global__ __launch_bounds__(256) void wtrans_kernel(
    const float* __restrict__ w_s, const float* __restrict__ w_t,
    float* __restrict__ wT_s, float* __restrict__ wT_t)
{
  const float* w = blockIdx.y ? w_t : w_s;
  float* wT = blockIdx.y ? wT_t : wT_s;
  const int e = blockIdx.x * 256 + threadIdx.x;   // 0..73727
  const int co = e & 63;
  const int q = e >> 6;
  const int k9 = q % 9;
  const int ci = q / 9;
  wT[e] = w[(co * 128 + ci) * 9 + k9];
}

// ---------------------------------------------------------------------------
// conv0: 3x3 stride-2 pad-1, Cin=128 -> Cout=64, 64x64 -> 32x32.
// ---------------------------------------------------------------------------
__global__ __launch_bounds__(256) void conv0_kernel(
    const float* __restrict__ in_s, const float* __restrict__ wT_s, const float* __restrict__ b_s,
    float* __restrict__ outA_s, float* __restrict__ outB_s,
    const float* __restrict__ in_t, const float* __restrict__ wT_t, const float* __restrict__ b_t,
    float* __restrict__ outA_t, float* __restrict__ outB_t)
{
  const int tsel = blockIdx.y;
  const float* in   = tsel ? in_t  : in_s;
  const float* wT   = tsel ? wT_t  : wT_s;
  const float* bias = tsel ? b_t   : b_s;
  float* outA = tsel ? outA_t : outA_s;
  float* outB = tsel ? outB_t : outB_s;

  const int bx = blockIdx.x;
  const int b  = bx >> 4;
  const int y0 = (bx & 15) * 2;
  const int t  = threadIdx.x;
  const int x  = t & 31;
  const int cg = t >> 5;            // 0..7 -> co = cg*8..+7

  __shared__ float wch[4608];       // [cc][k9][co] = [8][9][64], flat
  __shared__ float inch[8][5][64];  // [ci_chunk][row][ix]

  float acc[2][8];
#pragma unroll
  for (int yy = 0; yy < 2; ++yy)
#pragma unroll
    for (int o = 0; o < 8; ++o) acc[yy][o] = 0.f;

  for (int ci0 = 0; ci0 < 128; ci0 += 8) {
    __syncthreads();
    {
      const float* wsrc = wT + ci0 * 576;
#pragma unroll 4
      for (int r = 0; r < 18; ++r) {
        const int e = t + 256 * r;
        wch[e] = wsrc[e];
      }
    }
#pragma unroll 2
    for (int r = 0; r < 10; ++r) {
      const int e = t + 256 * r;
      const int ix = e & 63;
      const int q = e >> 6;         // 0..39
      const int ry = q % 5;
      const int cc = q / 5;
      const int iy = 2 * y0 - 1 + ry;
      float v = 0.f;
      if (iy >= 0 && iy < 64) v = in[((b * 128 + ci0 + cc) * 64 + iy) * 64 + ix];
      inch[cc][ry][ix] = v;
    }
    __syncthreads();
#pragma unroll 1
    for (int cc = 0; cc < 8; ++cc) {
      float iv[5][3];
#pragma unroll
      for (int ry = 0; ry < 5; ++ry) {
#pragma unroll
        for (int kx = 0; kx < 3; ++kx) {
          const int ix = 2 * x + kx - 1;   // [-1, 63]
          iv[ry][kx] = (ix >= 0) ? inch[cc][ry][ix] : 0.f;
        }
      }
#pragma unroll
      for (int ky = 0; ky < 3; ++ky) {
#pragma unroll
        for (int kx = 0; kx < 3; ++kx) {
          const int k9 = ky * 3 + kx;
          const float4 wa = *reinterpret_cast<const float4*>(&wch[(cc * 9 + k9) * 64 + cg * 8]);
          const float4 wb = *reinterpret_cast<const float4*>(&wch[(cc * 9 + k9) * 64 + cg * 8 + 4]);
          const float wv[8] = {wa.x, wa.y, wa.z, wa.w, wb.x, wb.y, wb.z, wb.w};
          const float i0 = iv[ky][kx];
          const float i1 = iv[ky + 2][kx];
#pragma unroll
          for (int o = 0; o < 8; ++o) {
            acc[0][o] = fmaf(i0, wv[o], acc[0][o]);
            acc[1][o] = fmaf(i1, wv[o], acc[1][o]);
          }
        }
      }
    }
  }
#pragma unroll
  for (int o = 0; o < 8; ++o) {
    const int co = cg * 8 + o;
    const float bv = bias[co];
#pragma unroll
    for (int yy = 0; yy < 2; ++yy) {
      const int idx = (b * 64 + co) * 1024 + (y0 + yy) * 32 + x;
      const float val = acc[yy][o] + bv;
      outA[idx] = val;
      if (outB) outB[idx] = val;
    }
  }
}

// ---------------------------------------------------------------------------
// Generic out[g][64][1024] = W[g/wdiv][64][K] @ X[g][K][1024] + bias
// ---------------------------------------------------------------------------
__global__ __launch_bounds__(256) void gemm64_kernel(
    const float* __restrict__ W, int wstride, int wdiv,
    const float* __restrict__ X, int xstride,
    float* __restrict__ out, int ostride,
    float* __restrict__ out2, int o2stride,
    const float* __restrict__ bias, int bstride,
    int K)
{
  const int g  = blockIdx.x;
  const int n0 = blockIdx.y * 64;
  const float* Wg = W + (size_t)(g / wdiv) * wstride;
  const float* Xg = X + (size_t)g * xstride;
  const int t = threadIdx.x;
  __shared__ float Xs[32][64];
  __shared__ float Ws[32][64];
  const int tn = t & 15, cgp = t >> 4;
  const int n4 = tn * 4, co4 = cgp * 4;
  float acc[4][4] = {};

  for (int k0 = 0; k0 < K; k0 += 32) {
    {
      const int kk = t >> 4;
      const int nn = (t & 15) * 4;
      *reinterpret_cast<float4*>(&Xs[kk][nn]) =
          *reinterpret_cast<const float4*>(Xg + (size_t)(k0 + kk) * N_ + n0 + nn);
      *reinterpret_cast<float4*>(&Xs[kk + 16][nn]) =
          *reinterpret_cast<const float4*>(Xg + (size_t)(k0 + kk + 16) * N_ + n0 + nn);
    }
    {
      const int co = t & 63, q4 = t >> 6;
      const float* wp = Wg + (size_t)co * K + k0 + q4 * 8;
      const float4 a = *reinterpret_cast<const float4*>(wp);
      const float4 c = *reinterpret_cast<const float4*>(wp + 4);
      const int kb = q4 * 8;
      Ws[kb + 0][co] = a.x; Ws[kb + 1][co] = a.y; Ws[kb + 2][co] = a.z; Ws[kb + 3][co] = a.w;
      Ws[kb + 4][co] = c.x; Ws[kb + 5][co] = c.y; Ws[kb + 6][co] = c.z; Ws[kb + 7][co] = c.w;
    }
    __syncthreads();
#pragma unroll
    for (int kk = 0; kk < 32; ++kk) {
      const float4 xv = *reinterpret_cast<const float4*>(&Xs[kk][n4]);
      const float4 wv = *reinterpret_cast<const float4*>(&Ws[kk][co4]);
      const float xa[4] = {xv.x, xv.y, xv.z, xv.w};
      const float wa[4] = {wv.x, wv.y, wv.z, wv.w};
#pragma unroll
      for (int a = 0; a < 4; ++a)
#pragma unroll
        for (int b2 = 0; b2 < 4; ++b2)
          acc[a][b2] = fmaf(wa[a], xa[b2], acc[a][b2]);
    }
    __syncthreads();
  }

  float bv[4] = {0.f, 0.f, 0.f, 0.f};
  if (bias) {
    const float* bg = bias + (size_t)(g / wdiv) * bstride;
    bv[0] = bg[co4]; bv[1] = bg[co4 + 1]; bv[2] = bg[co4 + 2]; bv[3] = bg[co4 + 3];
  }
#pragma unroll
  for (int ii = 0; ii < 4; ++ii) {
    float4 o4;
    o4.x = acc[ii][0] + bv[ii]; o4.y = acc[ii][1] + bv[ii];
    o4.z = acc[ii][2] + bv[ii]; o4.w = acc[ii][3] + bv[ii];
    const int idx = (co4 + ii) * N_ + n0 + n4;
    *reinterpret_cast<float4*>(out + (size_t)g * ostride + idx) = o4;
    if (out2) {
      float* o2 = out2 + (size_t)g * o2stride + idx;
      o2[0] = o4.x; o2[1] = o4.y; o2[2] = o4.z; o2[3] = o4.w;
    }
  }
}

// ---------------------------------------------------------------------------
// kprep: k[g][64c][1024m] -> kT_hi/kT_lo[g][1024m][64c] (split bf16);
//        v[g] -> vbf[g] (bf16). grid (24, 4): per block 256-m chunk.
// ---------------------------------------------------------------------------
__global__ __launch_bounds__(256) void kprep_kernel(
    const float* __restrict__ kb, const float* __restrict__ vb,
    unsigned short* __restrict__ kTh, unsigned short* __restrict__ kTl,
    unsigned short* __restrict__ vbf)
{
  const int g = blockIdx.x;
  const int ch = blockIdx.y;
  const int t = threadIdx.x;
  const float* kg = kb + (size_t)g * PLANE;
  __shared__ float tl[64][65];

#pragma unroll 1
  for (int tile = 0; tile < 4; ++tile) {
    const int m0 = ch * 256 + tile * 64;
    __syncthreads();
#pragma unroll 4
    for (int r = 0; r < 16; ++r) {
      const int c = r * 4 + (t >> 6);
      tl[c][t & 63] = kg[c * N_ + m0 + (t & 63)];
    }
    __syncthreads();
    const int mm = t >> 2, cseg = (t & 3) * 16;
    uint32 hw[8], lw[8];
#pragma unroll
    for (int ii = 0; ii < 16; ++ii) {
      const float f = tl[cseg + ii][mm];
      const unsigned short h = f2bf(f);
      const unsigned short l = f2bf(f - bf2f(h));
      if (ii & 1) { hw[ii >> 1] |= (uint32)h << 16; lw[ii >> 1] |= (uint32)l << 16; }
      else        { hw[ii >> 1] = h;                lw[ii >> 1] = l; }
    }
    const size_t o = ((size_t)g * 1024 + m0 + mm) * 64 + cseg;
    uint4 h0; h0.x = hw[0]; h0.y = hw[1]; h0.z = hw[2]; h0.w = hw[3];
    uint4 h1; h1.x = hw[4]; h1.y = hw[5]; h1.z = hw[6]; h1.w = hw[7];
    uint4 l0; l0.x = lw[0]; l0.y = lw[1]; l0.z = lw[2]; l0.w = lw[3];
    uint4 l1; l1.x = lw[4]; l1.y = lw[5]; l1.z = lw[6]; l1.w = lw[7];
    *reinterpret_cast<uint4*>(kTh + o)     = h0;
    *reinterpret_cast<uint4*>(kTh + o + 8) = h1;
    *reinterpret_cast<uint4*>(kTl + o)     = l0;
    *reinterpret_cast<uint4*>(kTl + o + 8) = l1;
  }

  // v -> bf16 (8 elems/thread/iter, packed 16B stores)
  const float* vg = vb + (size_t)g * PLANE;
  unsigned short* vo = vbf + (size_t)g * PLANE;
  for (int e8 = ch * 2048 + t; e8 < (ch + 1) * 2048; e8 += 256) {
    const float4 a = *reinterpret_cast<const float4*>(vg + (size_t)e8 * 8);
    const float4 b = *reinterpret_cast<const float4*>(vg + (size_t)e8 * 8 + 4);
    uint4 u;
    u.x = pkbf(a.x, a.y); u.y = pkbf(a.z, a.w);
    u.z = pkbf(b.x, b.y); u.w = pkbf(b.z, b.w);
    *reinterpret_cast<uint4*>(vo + (size_t)e8 * 8) = u;
  }
}

// ---------------------------------------------------------------------------
// e_cam[i,j,b][c][d] = sum_n T[i,b,c,n] * S[j,b,d,n];  also atomic raw-sum.
// ---------------------------------------------------------------------------
__global__ __launch_bounds__(256) void ecam_kernel(
    const float* __restrict__ T, const float* __restrict__ S,
    float* __restrict__ ecam, float* __restrict__ esum_cam)
{
  const int bx = blockIdx.x;
  const int b = bx & 7;
  const int j = (bx >> 3) % 3;
  const int i = bx / 24;
  const float* Tg = T + (size_t)(i * 8 + b) * PLANE;
  const float* Sg = S + (size_t)(j * 8 + b) * PLANE;
  const int t = threadIdx.x;
  __shared__ float Ts[64 * 68];
  __shared__ float Ss[64 * 68];
  __shared__ float rs[4];
  float acc[4][4] = {};
  const int c0 = (t & 15) * 4, d0 = (t >> 4) * 4;

  for (int nb = 0; nb < 1024; nb += 64) {
    __syncthreads();
    {
      const int nn = t & 63, rb = t >> 6;
#pragma unroll
      for (int r = 0; r < 16; ++r) {
        const int row = rb * 16 + r;
        Ts[nn * 68 + row] = Tg[row * N_ + nb + nn];
        Ss[nn * 68 + row] = Sg[row * N_ + nb + nn];
      }
    }
    __syncthreads();
#pragma unroll 8
    for (int nn = 0; nn < 64; ++nn) {
      const float4 tv = *reinterpret_cast<const float4*>(&Ts[nn * 68 + c0]);
      const float4 sv = *reinterpret_cast<const float4*>(&Ss[nn * 68 + d0]);
      const float ta[4] = {tv.x, tv.y, tv.z, tv.w};
      const float sa[4] = {sv.x, sv.y, sv.z, sv.w};
#pragma unroll
      for (int ci = 0; ci < 4; ++ci)
#pragma unroll
        for (int di = 0; di < 4; ++di)
          acc[ci][di] = fmaf(ta[ci], sa[di], acc[ci][di]);
    }
  }
  float s = 0.f;
#pragma unroll
  for (int ci = 0; ci < 4; ++ci)
#pragma unroll
    for (int di = 0; di < 4; ++di) s += acc[ci][di];
  s = wred_sum(s);
  if ((t & 63) == 0) rs[t >> 6] = s;
  __syncthreads();
  if (t == 0) atomicAdd(esum_cam + i * 3 + j, rs[0] + rs[1] + rs[2] + rs[3]);

  float* eo = ecam + (size_t)((i * 3 + j) * 8 + b) * 4096;
#pragma unroll
  for (int ci = 0; ci < 4; ++ci) {
    float4 o4; o4.x = acc[ci][0]; o4.y = acc[ci][1]; o4.z = acc[ci][2]; o4.w = acc[ci][3];
    *reinterpret_cast<float4*>(eo + (c0 + ci) * 64 + d0) = o4;
  }
}

// ---------------------------------------------------------------------------
// attn_cam[i,b][c][d] = sum_j softmax_d(e_cam[i,j,b,c,:])[d]     grid 24
// ---------------------------------------------------------------------------
__global__ __launch_bounds__(256) void acam_kernel(
    const float* __restrict__ ecam, float* __restrict__ acam)
{
  const int bx = blockIdx.x;
  const int b = bx & 7, i = bx >> 3;
  const int t = threadIdx.x;
  const int c = t >> 2, seg = t & 3;
  float acc[16] = {};
#pragma unroll
  for (int j = 0; j < 3; ++j) {
    const float* e = ecam + (size_t)((i * 3 + j) * 8 + b) * 4096 + c * 64 + seg * 16;
    float ev[16];
#pragma unroll
    for (int r = 0; r < 4; ++r) {
      const float4 v4 = *reinterpret_cast<const float4*>(e + r * 4);
      ev[4 * r] = v4.x; ev[4 * r + 1] = v4.y; ev[4 * r + 2] = v4.z; ev[4 * r + 3] = v4.w;
    }
    float mx = ev[0];
#pragma unroll
    for (int r = 1; r < 16; ++r) mx = fmaxf(mx, ev[r]);
    mx = fmaxf(mx, __shfl_xor(mx, 1, 4));
    mx = fmaxf(mx, __shfl_xor(mx, 2, 4));
    float pv[16], ss = 0.f;
#pragma unroll
    for (int r = 0; r < 16; ++r) { pv[r] = __expf(ev[r] - mx); ss += pv[r]; }
    ss += __shfl_xor(ss, 1, 4);
    ss += __shfl_xor(ss, 2, 4);
    const float rc = 1.f / ss;
#pragma unroll
    for (int r = 0; r < 16; ++r) acc[r] += pv[r] * rc;
  }
  float* ao = acam + (size_t)(i * 8 + b) * 4096 + c * 64 + seg * 16;
#pragma unroll
  for (int r = 0; r < 4; ++r) {
    float4 o4; o4.x = acc[4 * r]; o4.y = acc[4 * r + 1]; o4.z = acc[4 * r + 2]; o4.w = acc[4 * r + 3];
    *reinterpret_cast<float4*>(ao + r * 4) = o4;
  }
}

// ---------------------------------------------------------------------------
// PAM via MFMA, per-j PV accumulation (no pacc array -> fits 4 blocks/CU).
// grid 1536 = (i, b, qt). Per j: QK logits (l4, 64 regs) -> softmax ->
// scale in place -> stage 512-m halves through 16KB swizzled LDS -> PV MFMA
// accumulating oa across j and halves.
// ---------------------------------------------------------------------------
__global__ __launch_bounds__(256, 4) void pam_mfma_kernel(
    const float* __restrict__ q, const unsigned short* __restrict__ kTh,
    const unsigned short* __restrict__ kTl, const unsigned short* __restrict__ vbf,
    const float* __restrict__ ocam, float* __restrict__ tgts, float* __restrict__ esum_pam)
{
  const int bx = blockIdx.x;
  const int qt = bx & 63;
  const int b  = (bx >> 6) & 7;
  const int i  = bx >> 9;
  const int n0 = qt * 16;
  const int t = threadIdx.x;
  const int lane = t & 63;
  const int wv = t >> 6;
  const int nl = lane & 15;          // n within tile (operand col / D col)
  const int g16 = lane >> 4;         // k-group

  __shared__ unsigned short Plds[512 * 16];  // 16 KB, [n][mloc ^ (8n)]
  __shared__ float qlds[64 * 17];
  __shared__ float redmx[3][64];
  __shared__ float redse[3][64];
  __shared__ float redes[3][4];

  const size_t ibo = (size_t)(i * 8 + b) * PLANE;

  // stage q tile [64c][16n]
  const float* qg = q + ibo;
  for (int e = t; e < 1024; e += 256)
    qlds[(e >> 4) * 17 + (e & 15)] = qg[(e >> 4) * N_ + n0 + (e & 15)];
  __syncthreads();

  // Q B-fragments, split hi/lo: col n = nl, k(c) = ks*32 + g16*8 + idx
  short8 qhi[2], qlo[2];
#pragma unroll
  for (int ks = 0; ks < 2; ++ks) {
#pragma unroll
    for (int idx = 0; idx < 8; ++idx) {
      const float f = qlds[(ks * 32 + g16 * 8 + idx) * 17 + nl];
      const unsigned short h = f2bf(f);
      qhi[ks][idx] = (short)h;
      qlo[ks][idx] = (short)f2bf(f - bf2f(h));
    }
  }

  const int wm0 = wv * 256;  // wave's m-range base
  const unsigned short* vg = vbf + ibo + (size_t)(16 * wv + nl) * 1024 + g16 * 8;
  f32x4 oa = f32x4{0.f, 0.f, 0.f, 0.f};
  f32x4 ob = f32x4{0.f, 0.f, 0.f, 0.f};

#pragma unroll 1
  for (int j = 0; j < 3; ++j) {
    const size_t ko = ((size_t)(j * 8 + b) * 1024 + wm0 + nl) * 64 + g16 * 8;
    const unsigned short* kh = kTh + ko;
    const unsigned short* kl = kTl + ko;

    f32x4 l4[16];
#pragma unroll
    for (int tt = 0; tt < 16; ++tt) {
      const int off = tt * 1024;  // 16 m-rows * 64 c
      const short8 kh0 = bcs8(*reinterpret_cast<const uint4*>(kh + off));
      const short8 kl0 = bcs8(*reinterpret_cast<const uint4*>(kl + off));
      const short8 kh1 = bcs8(*reinterpret_cast<const uint4*>(kh + off + 32));
      const short8 kl1 = bcs8(*reinterpret_cast<const uint4*>(kl + off + 32));
      f32x4 a = f32x4{0.f, 0.f, 0.f, 0.f};
      f32x4 c = f32x4{0.f, 0.f, 0.f, 0.f};
      a = mfma16(kh0, qhi[0], a);
      c = mfma16(kh1, qhi[1], c);
      a = mfma16(kh0, qlo[0], a);
      c = mfma16(kh1, qlo[1], c);
      a = mfma16(kl0, qhi[0], a);
      c = mfma16(kl1, qhi[1], c);
#pragma unroll
      for (int r = 0; r < 4; ++r) a[r] += c[r];
      l4[tt] = a;
    }

    // stats: per-n max over this wave's 256 m (4-lane group), raw sum (wave)
    float pm = -3.4e38f, es = 0.f;
#pragma unroll
    for (int tt = 0; tt < 16; ++tt) {
#pragma unroll
      for (int r = 0; r < 4; ++r) { pm = fmaxf(pm, l4[tt][r]); es += l4[tt][r]; }
    }
    pm = fmaxf(pm, __shfl_xor(pm, 16, 64));
    pm = fmaxf(pm, __shfl_xor(pm, 32, 64));
    es = wred_sum(es);
    if (lane < 16) redmx[j][wv * 16 + lane] = pm;
    if (lane == 0) redes[j][wv] = es;
    __syncthreads();
    const float mx = fmaxf(fmaxf(redmx[j][nl], redmx[j][16 + nl]),
                           fmaxf(redmx[j][32 + nl], redmx[j][48 + nl]));
    if (t == 0)
      atomicAdd(esum_pam + i * 3 + j,
                redes[j][0] + redes[j][1] + redes[j][2] + redes[j][3]);

    float ps = 0.f;
#pragma unroll
    for (int tt = 0; tt < 16; ++tt) {
#pragma unroll
      for (int r = 0; r < 4; ++r) {
        l4[tt][r] = __expf(l4[tt][r] - mx);
        ps += l4[tt][r];
      }
    }
    ps += __shfl_xor(ps, 16, 64);
    ps += __shfl_xor(ps, 32, 64);
    if (lane < 16) redse[j][wv * 16 + lane] = ps;
    __syncthreads();
    const float rs = 1.f / (redse[j][nl] + redse[j][16 + nl] +
                            redse[j][32 + nl] + redse[j][48 + nl]);
#pragma unroll
    for (int tt = 0; tt < 16; ++tt) {
#pragma unroll
      for (int r = 0; r < 4; ++r) l4[tt][r] *= rs;
    }

    // stage P_j (bf16, swizzled) in two 512-m halves + PV MFMA per half
#pragma unroll 1
    for (int half = 0; half < 2; ++half) {
      __syncthreads();   // prior PV reads of Plds complete
      if ((wv >> 1) == half) {
#pragma unroll
        for (int tt = 0; tt < 16; ++tt) {
          const int mloc = (wv & 1) * 256 + tt * 16 + g16 * 4;
          uint2 w2;
          w2.x = pkbf(l4[tt][0], l4[tt][1]);
          w2.y = pkbf(l4[tt][2], l4[tt][3]);
          *reinterpret_cast<uint2*>(&Plds[nl * 512 + (mloc ^ (nl * 8))]) = w2;
        }
      }
      __syncthreads();   // Plds ready
#pragma unroll
      for (int ks = 0; ks < 16; ks += 2) {
        const int ml0 = ks * 32 + g16 * 8;
        const int ml1 = ml0 + 32;
        const short8 va0 = bcs8(*reinterpret_cast<const uint4*>(vg + half * 512 + ks * 32));
        const short8 pf0 = bcs8(*reinterpret_cast<const uint4*>(&Plds[nl * 512 + (ml0 ^ (nl * 8))]));
        const short8 va1 = bcs8(*reinterpret_cast<const uint4*>(vg + half * 512 + ks * 32 + 32));
        const short8 pf1 = bcs8(*reinterpret_cast<const uint4*>(&Plds[nl * 512 + (ml1 ^ (nl * 8))]));
        oa = mfma16(va0, pf0, oa);
        ob = mfma16(va1, pf1, ob);
      }
    }
  }

#pragma unroll
  for (int r = 0; r < 4; ++r) oa[r] += ob[r];

  // epilogue: fuse with out_cam, write tgts even slot
  const float* og = ocam + ibo;
  float* outg = tgts + (size_t)(2 * i * 8 + b) * PLANE;
#pragma unroll
  for (int r = 0; r < 4; ++r) {
    const int c = 16 * wv + g16 * 4 + r;
    const int idx = c * N_ + n0 + nl;
    outg[idx] = 0.5f * (oa[r] + og[idx]);
  }
}

// ---------------------------------------------------------------------------
// alpha[i][j] = 0.5*(softmax_j(mean e_pam) + softmax_j(mean e_cam))
// ---------------------------------------------------------------------------
__global__ void alpha_kernel(const float* __restrict__ esum, float* __restrict__ alpha)
{
  const int t = threadIdx.x;
  if (t >= 9) return;
  const int i = t / 3, j = t % 3;
  float p[3], c[3];
#pragma unroll
  for (int jj = 0; jj < 3; ++jj) {
    p[jj] = esum[i * 3 + jj] * (1.0f / 8388608.0f);
    c[jj] = esum[9 + i * 3 + jj] * (1.0f / 32768.0f);
  }
  const float mp = fmaxf(p[0], fmaxf(p[1], p[2]));
  const float mc = fmaxf(c[0], fmaxf(c[1], c[2]));
  float sp = 0.f, sc = 0.f;
#pragma unroll
  for (int jj = 0; jj < 3; ++jj) { sp += __expf(p[jj] - mp); sc += __expf(c[jj] - mc); }
  alpha[t] = 0.5f * (__expf(p[j] - mp) / sp + __expf(c[j] - mc) / sc);
}

// ---------------------------------------------------------------------------
extern "C" void kernel_launch(void* const* d_in, const int* in_sizes, int n_in,
                              void* d_out, int out_size, void* d_ws, size_t ws_size,
                              hipStream_t stream)
{
  const float* src0 = (const float*)d_in[0];
  const float* src1 = (const float*)d_in[1];
  const float* src2 = (const float*)d_in[2];
  const float* tgt0 = (const float*)d_in[3];
  const float* tgt1 = (const float*)d_in[4];
  const float* tgt2 = (const float*)d_in[5];
  const float* fs0_w = (const float*)d_in[6];  const float* fs0_b = (const float*)d_in[7];
  const float* fs1_w = (const float*)d_in[8];  const float* fs1_b = (const float*)d_in[9];
  const float* fs2_w = (const float*)d_in[10]; const float* fs2_b = (const float*)d_in[11];
  const float* ft0_w = (const float*)d_in[12]; const float* ft0_b = (const float*)d_in[13];
  const float* ft1_w = (const float*)d_in[14]; const float* ft1_b = (const float*)d_in[15];
  const float* ft2_w = (const float*)d_in[16]; const float* ft2_b = (const float*)d_in[17];
  const float* pq_w = (const float*)d_in[18];  const float* pq_b = (const float*)d_in[19];
  const float* pk_w = (const float*)d_in[20];  const float* pk_b = (const float*)d_in[21];
  const float* pv_w = (const float*)d_in[22];  const float* pv_b = (const float*)d_in[23];
  const float* cv_w = (const float*)d_in[24];  const float* cv_b = (const float*)d_in[25];

  float* out = (float*)d_out;
  float* S     = out;                 // srcs region doubles as S storage
  float* alpha = out + SZ;            // 9 floats
  float* tgts  = out + SZ + 9;        // [2L][B][PLANE]

  float* ws   = (float*)d_ws;
  float* T    = ws;
  float* qb   = ws + (size_t)SZ;
  float* kb   = ws + (size_t)2 * SZ;
  float* vb   = ws + (size_t)3 * SZ;
  float* vcb  = ws + (size_t)4 * SZ;
  float* ocam = ws + (size_t)5 * SZ;
  float* ecam = ws + (size_t)6 * SZ;                 // 294912
  float* acam = ws + (size_t)6 * SZ + 294912;        // 98304
  float* esum = ws + (size_t)6 * SZ + 393216;        // 18 (pam 9, cam 9)

  // bf16 buffers appended after the fp32 region
  unsigned short* kTh = (unsigned short*)(ws + (size_t)6 * SZ + 393216 + 256);
  unsigned short* kTl = kTh + (size_t)24 * PLANE;
  unsigned short* vbf = kTl + (size_t)24 * PLANE;

  // Transposed conv0 weights live temporarily in qb (overwritten later by q proj)
  float* wTs = qb;
  float* wTt = qb + 73728;

  hipMemsetAsync(esum, 0, 18 * sizeof(float), stream);

  // Pre-transpose the 3x3 weights for coalesced, math-free LDS staging
  wtrans_kernel<<<dim3(288, 2), 256, 0, stream>>>(fs0_w, ft0_w, wTs, wTt);

  // Fit convs (S goes straight into d_out; T dual-written into tgts odd slots)
  conv0_kernel<<<dim3(128, 2), 256, 0, stream>>>(
      src0, wTs, fs0_b, S, nullptr,
      tgt0, wTt, ft0_b, T, tgts + (size_t)1 * BPL);
  gemm64_kernel<<<dim3(8, 16), 256, 0, stream>>>(fs1_w, 0, 1, src1, 256 * N_, S + BPL, PLANE,
                                                 nullptr, 0, fs1_b, 0, 256);
  gemm64_kernel<<<dim3(8, 16), 256, 0, stream>>>(fs2_w, 0, 1, src2, 512 * N_, S + 2 * BPL, PLANE,
                                                 nullptr, 0, fs2_b, 0, 512);
  gemm64_kernel<<<dim3(8, 16), 256, 0, stream>>>(ft1_w, 0, 1, tgt1, 256 * N_, T + BPL, PLANE,
                                                 tgts + (size_t)3 * BPL, PLANE, ft1_b, 0, 256);
  gemm64_kernel<<<dim3(8, 16), 256, 0, stream>>>(ft2_w, 0, 1, tgt2, 512 * N_, T + 2 * BPL, PLANE,
                                                 tgts + (size_t)5 * BPL, PLANE, ft2_b, 0, 512);

  // Projections q,k,v,vc
  gemm64_kernel<<<dim3(24, 16), 256, 0, stream>>>(pq_w, 4096, 8, T, PLANE, qb, PLANE,
                                                  nullptr, 0, pq_b, 64, 64);
  gemm64_kernel<<<dim3(24, 16), 256, 0, stream>>>(pk_w, 4096, 8, S, PLANE, kb, PLANE,
                                                  nullptr, 0, pk_b, 64, 64);
  gemm64_kernel<<<dim3(24, 16), 256, 0, stream>>>(pv_w, 4096, 8, T, PLANE, vb, PLANE,
                                                  nullptr, 0, pv_b, 64, 64);
  gemm64_kernel<<<dim3(24, 16), 256, 0, stream>>>(cv_w, 4096, 8, T, PLANE, vcb, PLANE,
                                                  nullptr, 0, cv_b, 64, 64);

  // Pack k (transposed, split-bf16) and v (bf16) for the MFMA attention
  kprep_kernel<<<dim3(24, 4), 256, 0, stream>>>(kb, vb, kTh, kTl, vbf);

  // CAM
  ecam_kernel<<<72, 256, 0, stream>>>(T, S, ecam, esum + 9);
  acam_kernel<<<24, 256, 0, stream>>>(ecam, acam);
  gemm64_kernel<<<dim3(24, 16), 256, 0, stream>>>(acam, 4096, 1, vcb, PLANE, ocam, PLANE,
                                                  nullptr, 0, nullptr, 0, 64);

  // PAM + fuse (writes tgts even slots = 0.5*(out_pam + out_cam))
  pam_mfma_kernel<<<1536, 256, 0, stream>>>(qb, kTh, kTl, vbf, ocam, tgts, esum);

  alpha_kernel<<<1, 64, 0, stream>>>(esum, alpha);
}

// Round 8
// 500.547 us; speedup vs baseline: 1.1518x; 1.1518x over previous
//
#include <hip/hip_runtime.h>

// Problem constants
static constexpr int L_ = 3, B_ = 8, C_ = 64, N_ = 1024;
static constexpr int PLANE = C_ * N_;       // 65536
static constexpr int SZ    = L_ * B_ * PLANE; // 1572864 (srcs size, also per-stack-slot count)
static constexpr int BPL   = B_ * PLANE;    // 524288

#define DI __device__ __forceinline__

typedef __attribute__((ext_vector_type(8))) short short8;   // 8 bf16 (MFMA A/B frag)
typedef __attribute__((ext_vector_type(4))) float f32x4;    // MFMA C/D frag
typedef unsigned int uint32;

DI float wred_sum(float v) {
#pragma unroll
  for (int m = 1; m < 64; m <<= 1) v += __shfl_xor(v, m, 64);
  return v;
}

// bf16 helpers (RNE)
DI unsigned short f2bf(float f) {
  uint32 u = __builtin_bit_cast(uint32, f);
  return (unsigned short)((u + 0x7FFFu + ((u >> 16) & 1u)) >> 16);
}
DI float bf2f(unsigned short h) {
  uint32 u = ((uint32)h) << 16;
  return __builtin_bit_cast(float, u);
}
DI uint32 pkbf(float a, float b) {
  return (uint32)f2bf(a) | ((uint32)f2bf(b) << 16);
}
DI short8 bcs8(uint4 v) { return __builtin_bit_cast(short8, v); }

DI f32x4 mfma16(short8 a, short8 b, f32x4 c) {
  return __builtin_amdgcn_mfma_f32_16x16x32_bf16(a, b, c, 0, 0, 0);
}

// ---------------------------------------------------------------------------
// Weight transpose: w[co][ci][k9] -> wT[ci][k9][co]  (64 x 128 x 9 each)
// grid (288, 2)
// ---------------------------------------------------------------------------
__global__ __launch_bounds__(256) void wtrans_kernel(
    const float* __restrict__ w_s, const float* __restrict__ w_t,
    float* __restrict__ wT_s, float* __restrict__ wT_t)
{
  const float* w = blockIdx.y ? w_t : w_s;
  float* wT = blockIdx.y ? wT_t : wT_s;
  const int e = blockIdx.x * 256 + threadIdx.x;   // 0..73727
  const int co = e & 63;
  const int q = e >> 6;
  const int k9 = q % 9;
  const int ci = q / 9;
  wT[e] = w[(co * 128 + ci) * 9 + k9];
}

// ---------------------------------------------------------------------------
// conv0: 3x3 stride-2 pad-1, Cin=128 -> Cout=64, 64x64 -> 32x32.
// grid (128, 2, 2): x = b*16 + 2-row slab, y = co-half, z = (src,tgt).
// co-split doubles blocks/CU (1 -> 2): the 256-block version left each CU
// with a single wave per SIMD (pure latency exposure at ~170 us).
// ---------------------------------------------------------------------------
__global__ __launch_bounds__(256) void conv0_kernel(
    const float* __restrict__ in_s, const float* __restrict__ wT_s, const float* __restrict__ b_s,
    float* __restrict__ outA_s, float* __restrict__ outB_s,
    const float* __restrict__ in_t, const float* __restrict__ wT_t, const float* __restrict__ b_t,
    float* __restrict__ outA_t, float* __restrict__ outB_t)
{
  const int tsel = blockIdx.z;
  const int ch   = blockIdx.y;      // co half: co in [ch*32, ch*32+32)
  const float* in   = tsel ? in_t  : in_s;
  const float* wT   = tsel ? wT_t  : wT_s;
  const float* bias = tsel ? b_t   : b_s;
  float* outA = tsel ? outA_t : outA_s;
  float* outB = tsel ? outB_t : outB_s;

  const int bx = blockIdx.x;
  const int b  = bx >> 4;
  const int y0 = (bx & 15) * 2;
  const int t  = threadIdx.x;
  const int x  = t & 31;
  const int cg = t >> 5;            // 0..7 -> co = ch*32 + cg*4 .. +3

  __shared__ float wch[2304];       // [cc][k9][cl<32] flat
  __shared__ float inch[8][5][64];  // [ci_chunk][row][ix]

  float acc[2][4];
#pragma unroll
  for (int yy = 0; yy < 2; ++yy)
#pragma unroll
    for (int o = 0; o < 4; ++o) acc[yy][o] = 0.f;

  for (int ci0 = 0; ci0 < 128; ci0 += 8) {
    __syncthreads();
    // Weights for this co-half: 2304 floats, 32-float coalesced runs
#pragma unroll 3
    for (int r = 0; r < 9; ++r) {
      const int e = t + 256 * r;
      const int cc = e / 288;
      const int rem = e - cc * 288;
      const int k9 = rem >> 5;
      const int cl = rem & 31;
      wch[e] = wT[(ci0 + cc) * 576 + k9 * 64 + ch * 32 + cl];
    }
    // Inputs: 8 ci x 5 rows x 64 x, coalesced over x
#pragma unroll 2
    for (int r = 0; r < 10; ++r) {
      const int e = t + 256 * r;
      const int ix = e & 63;
      const int q = e >> 6;         // 0..39
      const int ry = q % 5;
      const int cc = q / 5;
      const int iy = 2 * y0 - 1 + ry;
      float v = 0.f;
      if (iy >= 0 && iy < 64) v = in[((b * 128 + ci0 + cc) * 64 + iy) * 64 + ix];
      inch[cc][ry][ix] = v;
    }
    __syncthreads();
#pragma unroll 1
    for (int cc = 0; cc < 8; ++cc) {
      float iv[5][3];
#pragma unroll
      for (int ry = 0; ry < 5; ++ry) {
#pragma unroll
        for (int kx = 0; kx < 3; ++kx) {
          const int ix = 2 * x + kx - 1;   // [-1, 63]
          iv[ry][kx] = (ix >= 0) ? inch[cc][ry][ix] : 0.f;
        }
      }
#pragma unroll
      for (int ky = 0; ky < 3; ++ky) {
#pragma unroll
        for (int kx = 0; kx < 3; ++kx) {
          const int k9 = ky * 3 + kx;
          const float4 w4 = *reinterpret_cast<const float4*>(&wch[(cc * 9 + k9) * 32 + cg * 4]);
          const float wv[4] = {w4.x, w4.y, w4.z, w4.w};
          const float i0 = iv[ky][kx];
          const float i1 = iv[ky + 2][kx];
#pragma unroll
          for (int o = 0; o < 4; ++o) {
            acc[0][o] = fmaf(i0, wv[o], acc[0][o]);
            acc[1][o] = fmaf(i1, wv[o], acc[1][o]);
          }
        }
      }
    }
  }
#pragma unroll
  for (int o = 0; o < 4; ++o) {
    const int co = ch * 32 + cg * 4 + o;
    const float bv = bias[co];
#pragma unroll
    for (int yy = 0; yy < 2; ++yy) {
      const int idx = (b * 64 + co) * 1024 + (y0 + yy) * 32 + x;
      const float val = acc[yy][o] + bv;
      outA[idx] = val;
      if (outB) outB[idx] = val;
    }
  }
}

// ---------------------------------------------------------------------------
// Generic out[g][64][1024] = W[g/wdiv][64][K] @ X[g][K][1024] + bias
// ---------------------------------------------------------------------------
__global__ __launch_bounds__(256) void gemm64_kernel(
    const float* __restrict__ W, int wstride, int wdiv,
    const float* __restrict__ X, int xstride,
    float* __restrict__ out, int ostride,
    float* __restrict__ out2, int o2stride,
    const float* __restrict__ bias, int bstride,
    int K)
{
  const int g  = blockIdx.x;
  const int n0 = blockIdx.y * 64;
  const float* Wg = W + (size_t)(g / wdiv) * wstride;
  const float* Xg = X + (size_t)g * xstride;
  const int t = threadIdx.x;
  __shared__ float Xs[32][64];
  __shared__ float Ws[32][64];
  const int tn = t & 15, cgp = t >> 4;
  const int n4 = tn * 4, co4 = cgp * 4;
  float acc[4][4] = {};

  for (int k0 = 0; k0 < K; k0 += 32) {
    {
      const int kk = t >> 4;
      const int nn = (t & 15) * 4;
      *reinterpret_cast<float4*>(&Xs[kk][nn]) =
          *reinterpret_cast<const float4*>(Xg + (size_t)(k0 + kk) * N_ + n0 + nn);
      *reinterpret_cast<float4*>(&Xs[kk + 16][nn]) =
          *reinterpret_cast<const float4*>(Xg + (size_t)(k0 + kk + 16) * N_ + n0 + nn);
    }
    {
      const int co = t & 63, q4 = t >> 6;
      const float* wp = Wg + (size_t)co * K + k0 + q4 * 8;
      const float4 a = *reinterpret_cast<const float4*>(wp);
      const float4 c = *reinterpret_cast<const float4*>(wp + 4);
      const int kb = q4 * 8;
      Ws[kb + 0][co] = a.x; Ws[kb + 1][co] = a.y; Ws[kb + 2][co] = a.z; Ws[kb + 3][co] = a.w;
      Ws[kb + 4][co] = c.x; Ws[kb + 5][co] = c.y; Ws[kb + 6][co] = c.z; Ws[kb + 7][co] = c.w;
    }
    __syncthreads();
#pragma unroll
    for (int kk = 0; kk < 32; ++kk) {
      const float4 xv = *reinterpret_cast<const float4*>(&Xs[kk][n4]);
      const float4 wv = *reinterpret_cast<const float4*>(&Ws[kk][co4]);
      const float xa[4] = {xv.x, xv.y, xv.z, xv.w};
      const float wa[4] = {wv.x, wv.y, wv.z, wv.w};
#pragma unroll
      for (int a = 0; a < 4; ++a)
#pragma unroll
        for (int b2 = 0; b2 < 4; ++b2)
          acc[a][b2] = fmaf(wa[a], xa[b2], acc[a][b2]);
    }
    __syncthreads();
  }

  float bv[4] = {0.f, 0.f, 0.f, 0.f};
  if (bias) {
    const float* bg = bias + (size_t)(g / wdiv) * bstride;
    bv[0] = bg[co4]; bv[1] = bg[co4 + 1]; bv[2] = bg[co4 + 2]; bv[3] = bg[co4 + 3];
  }
#pragma unroll
  for (int ii = 0; ii < 4; ++ii) {
    float4 o4;
    o4.x = acc[ii][0] + bv[ii]; o4.y = acc[ii][1] + bv[ii];
    o4.z = acc[ii][2] + bv[ii]; o4.w = acc[ii][3] + bv[ii];
    const int idx = (co4 + ii) * N_ + n0 + n4;
    *reinterpret_cast<float4*>(out + (size_t)g * ostride + idx) = o4;
    if (out2) {
      float* o2 = out2 + (size_t)g * o2stride + idx;
      o2[0] = o4.x; o2[1] = o4.y; o2[2] = o4.z; o2[3] = o4.w;
    }
  }
}

// ---------------------------------------------------------------------------
// kprep: k[g][64c][1024m] -> kT_hi/kT_lo[g][1024m][64c] (split bf16);
//        v[g] -> vbf[g] (bf16). grid (24, 4): per block 256-m chunk.
// ---------------------------------------------------------------------------
__global__ __launch_bounds__(256) void kprep_kernel(
    const float* __restrict__ kb, const float* __restrict__ vb,
    unsigned short* __restrict__ kTh, unsigned short* __restrict__ kTl,
    unsigned short* __restrict__ vbf)
{
  const int g = blockIdx.x;
  const int ch = blockIdx.y;
  const int t = threadIdx.x;
  const float* kg = kb + (size_t)g * PLANE;
  __shared__ float tl[64][65];

#pragma unroll 1
  for (int tile = 0; tile < 4; ++tile) {
    const int m0 = ch * 256 + tile * 64;
    __syncthreads();
#pragma unroll 4
    for (int r = 0; r < 16; ++r) {
      const int c = r * 4 + (t >> 6);
      tl[c][t & 63] = kg[c * N_ + m0 + (t & 63)];
    }
    __syncthreads();
    const int mm = t >> 2, cseg = (t & 3) * 16;
    uint32 hw[8], lw[8];
#pragma unroll
    for (int ii = 0; ii < 16; ++ii) {
      const float f = tl[cseg + ii][mm];
      const unsigned short h = f2bf(f);
      const unsigned short l = f2bf(f - bf2f(h));
      if (ii & 1) { hw[ii >> 1] |= (uint32)h << 16; lw[ii >> 1] |= (uint32)l << 16; }
      else        { hw[ii >> 1] = h;                lw[ii >> 1] = l; }
    }
    const size_t o = ((size_t)g * 1024 + m0 + mm) * 64 + cseg;
    uint4 h0; h0.x = hw[0]; h0.y = hw[1]; h0.z = hw[2]; h0.w = hw[3];
    uint4 h1; h1.x = hw[4]; h1.y = hw[5]; h1.z = hw[6]; h1.w = hw[7];
    uint4 l0; l0.x = lw[0]; l0.y = lw[1]; l0.z = lw[2]; l0.w = lw[3];
    uint4 l1; l1.x = lw[4]; l1.y = lw[5]; l1.z = lw[6]; l1.w = lw[7];
    *reinterpret_cast<uint4*>(kTh + o)     = h0;
    *reinterpret_cast<uint4*>(kTh + o + 8) = h1;
    *reinterpret_cast<uint4*>(kTl + o)     = l0;
    *reinterpret_cast<uint4*>(kTl + o + 8) = l1;
  }

  // v -> bf16 (8 elems/thread/iter, packed 16B stores)
  const float* vg = vb + (size_t)g * PLANE;
  unsigned short* vo = vbf + (size_t)g * PLANE;
  for (int e8 = ch * 2048 + t; e8 < (ch + 1) * 2048; e8 += 256) {
    const float4 a = *reinterpret_cast<const float4*>(vg + (size_t)e8 * 8);
    const float4 b = *reinterpret_cast<const float4*>(vg + (size_t)e8 * 8 + 4);
    uint4 u;
    u.x = pkbf(a.x, a.y); u.y = pkbf(a.z, a.w);
    u.z = pkbf(b.x, b.y); u.w = pkbf(b.z, b.w);
    *reinterpret_cast<uint4*>(vo + (size_t)e8 * 8) = u;
  }
}

// ---------------------------------------------------------------------------
// e_cam[i,j,b][c][d] = sum_n T[i,b,c,n] * S[j,b,d,n];  also atomic raw-sum.
// ---------------------------------------------------------------------------
__global__ __launch_bounds__(256) void ecam_kernel(
    const float* __restrict__ T, const float* __restrict__ S,
    float* __restrict__ ecam, float* __restrict__ esum_cam)
{
  const int bx = blockIdx.x;
  const int b = bx & 7;
  const int j = (bx >> 3) % 3;
  const int i = bx / 24;
  const float* Tg = T + (size_t)(i * 8 + b) * PLANE;
  const float* Sg = S + (size_t)(j * 8 + b) * PLANE;
  const int t = threadIdx.x;
  __shared__ float Ts[64 * 68];
  __shared__ float Ss[64 * 68];
  __shared__ float rs[4];
  float acc[4][4] = {};
  const int c0 = (t & 15) * 4, d0 = (t >> 4) * 4;

  for (int nb = 0; nb < 1024; nb += 64) {
    __syncthreads();
    {
      const int nn = t & 63, rb = t >> 6;
#pragma unroll
      for (int r = 0; r < 16; ++r) {
        const int row = rb * 16 + r;
        Ts[nn * 68 + row] = Tg[row * N_ + nb + nn];
        Ss[nn * 68 + row] = Sg[row * N_ + nb + nn];
      }
    }
    __syncthreads();
#pragma unroll 8
    for (int nn = 0; nn < 64; ++nn) {
      const float4 tv = *reinterpret_cast<const float4*>(&Ts[nn * 68 + c0]);
      const float4 sv = *reinterpret_cast<const float4*>(&Ss[nn * 68 + d0]);
      const float ta[4] = {tv.x, tv.y, tv.z, tv.w};
      const float sa[4] = {sv.x, sv.y, sv.z, sv.w};
#pragma unroll
      for (int ci = 0; ci < 4; ++ci)
#pragma unroll
        for (int di = 0; di < 4; ++di)
          acc[ci][di] = fmaf(ta[ci], sa[di], acc[ci][di]);
    }
  }
  float s = 0.f;
#pragma unroll
  for (int ci = 0; ci < 4; ++ci)
#pragma unroll
    for (int di = 0; di < 4; ++di) s += acc[ci][di];
  s = wred_sum(s);
  if ((t & 63) == 0) rs[t >> 6] = s;
  __syncthreads();
  if (t == 0) atomicAdd(esum_cam + i * 3 + j, rs[0] + rs[1] + rs[2] + rs[3]);

  float* eo = ecam + (size_t)((i * 3 + j) * 8 + b) * 4096;
#pragma unroll
  for (int ci = 0; ci < 4; ++ci) {
    float4 o4; o4.x = acc[ci][0]; o4.y = acc[ci][1]; o4.z = acc[ci][2]; o4.w = acc[ci][3];
    *reinterpret_cast<float4*>(eo + (c0 + ci) * 64 + d0) = o4;
  }
}

// ---------------------------------------------------------------------------
// attn_cam[i,b][c][d] = sum_j softmax_d(e_cam[i,j,b,c,:])[d]     grid 24
// ---------------------------------------------------------------------------
__global__ __launch_bounds__(256) void acam_kernel(
    const float* __restrict__ ecam, float* __restrict__ acam)
{
  const int bx = blockIdx.x;
  const int b = bx & 7, i = bx >> 3;
  const int t = threadIdx.x;
  const int c = t >> 2, seg = t & 3;
  float acc[16] = {};
#pragma unroll
  for (int j = 0; j < 3; ++j) {
    const float* e = ecam + (size_t)((i * 3 + j) * 8 + b) * 4096 + c * 64 + seg * 16;
    float ev[16];
#pragma unroll
    for (int r = 0; r < 4; ++r) {
      const float4 v4 = *reinterpret_cast<const float4*>(e + r * 4);
      ev[4 * r] = v4.x; ev[4 * r + 1] = v4.y; ev[4 * r + 2] = v4.z; ev[4 * r + 3] = v4.w;
    }
    float mx = ev[0];
#pragma unroll
    for (int r = 1; r < 16; ++r) mx = fmaxf(mx, ev[r]);
    mx = fmaxf(mx, __shfl_xor(mx, 1, 4));
    mx = fmaxf(mx, __shfl_xor(mx, 2, 4));
    float pv[16], ss = 0.f;
#pragma unroll
    for (int r = 0; r < 16; ++r) { pv[r] = __expf(ev[r] - mx); ss += pv[r]; }
    ss += __shfl_xor(ss, 1, 4);
    ss += __shfl_xor(ss, 2, 4);
    const float rc = 1.f / ss;
#pragma unroll
    for (int r = 0; r < 16; ++r) acc[r] += pv[r] * rc;
  }
  float* ao = acam + (size_t)(i * 8 + b) * 4096 + c * 64 + seg * 16;
#pragma unroll
  for (int r = 0; r < 4; ++r) {
    float4 o4; o4.x = acc[4 * r]; o4.y = acc[4 * r + 1]; o4.z = acc[4 * r + 2]; o4.w = acc[4 * r + 3];
    *reinterpret_cast<float4*>(ao + r * 4) = o4;
  }
}

// ---------------------------------------------------------------------------
// PAM via MFMA, 8 waves x 128 m: l4 shrinks to 32 regs so the whole kernel
// fits the 128-reg budget of 4 waves/SIMD (prior rounds spilled at 256thr/4blk).
// grid 1536 = (i, b, qt), 512 threads.
// Per j: QK logits -> block softmax (8-wave reduce) -> P (bf16, swizzled LDS)
// -> PV MFMA (wave = c-tile x m-half), oa accumulated across j.
// ---------------------------------------------------------------------------
__global__ __launch_bounds__(512, 4) void pam_mfma_kernel(
    const float* __restrict__ q, const unsigned short* __restrict__ kTh,
    const unsigned short* __restrict__ kTl, const unsigned short* __restrict__ vbf,
    const float* __restrict__ ocam, float* __restrict__ tgts, float* __restrict__ esum_pam)
{
  const int bx = blockIdx.x;
  const int qt = bx & 63;
  const int b  = (bx >> 6) & 7;
  const int i  = bx >> 9;
  const int n0 = qt * 16;
  const int t = threadIdx.x;
  const int lane = t & 63;
  const int wv = t >> 6;             // 0..7
  const int nl = lane & 15;          // n within tile (operand col / D col)
  const int g16 = lane >> 4;         // k-group

  __shared__ unsigned short Plds[16 * 1024];  // 32 KB, [n][m ^ (8n)]
  __shared__ float qlds[64 * 17];
  __shared__ float redmx[128];
  __shared__ float redse[128];
  __shared__ float redes[8];
  __shared__ float osum[64 * 16];             // m-half combine buffer

  const size_t ibo = (size_t)(i * 8 + b) * PLANE;

  // stage q tile [64c][16n]
  const float* qg = q + ibo;
  for (int e = t; e < 1024; e += 512)
    qlds[(e >> 4) * 17 + (e & 15)] = qg[(e >> 4) * N_ + n0 + (e & 15)];
  __syncthreads();

  // Q B-fragments, split hi/lo: col n = nl, k(c) = ks*32 + g16*8 + idx
  short8 qhi[2], qlo[2];
#pragma unroll
  for (int ks = 0; ks < 2; ++ks) {
#pragma unroll
    for (int idx = 0; idx < 8; ++idx) {
      const float f = qlds[(ks * 32 + g16 * 8 + idx) * 17 + nl];
      const unsigned short h = f2bf(f);
      qhi[ks][idx] = (short)h;
      qlo[ks][idx] = (short)f2bf(f - bf2f(h));
    }
  }

  const int wm0 = wv * 128;          // wave's m-range base (QK)
  const int ct = wv & 3;             // PV c-tile
  const int mh = wv >> 2;            // PV m-half
  const unsigned short* vg = vbf + ibo + (size_t)(ct * 16 + nl) * 1024 + mh * 512 + g16 * 8;
  f32x4 oa = f32x4{0.f, 0.f, 0.f, 0.f};
  f32x4 ob = f32x4{0.f, 0.f, 0.f, 0.f};

#pragma unroll 1
  for (int j = 0; j < 3; ++j) {
    const size_t ko = ((size_t)(j * 8 + b) * 1024 + wm0 + nl) * 64 + g16 * 8;
    const unsigned short* kh = kTh + ko;
    const unsigned short* kl = kTl + ko;

    f32x4 l4[8];
#pragma unroll 2
    for (int tt = 0; tt < 8; ++tt) {
      const int off = tt * 1024;  // 16 m-rows * 64 c
      const short8 kh0 = bcs8(*reinterpret_cast<const uint4*>(kh + off));
      const short8 kl0 = bcs8(*reinterpret_cast<const uint4*>(kl + off));
      const short8 kh1 = bcs8(*reinterpret_cast<const uint4*>(kh + off + 32));
      const short8 kl1 = bcs8(*reinterpret_cast<const uint4*>(kl + off + 32));
      f32x4 a = f32x4{0.f, 0.f, 0.f, 0.f};
      f32x4 c = f32x4{0.f, 0.f, 0.f, 0.f};
      a = mfma16(kh0, qhi[0], a);
      c = mfma16(kh1, qhi[1], c);
      a = mfma16(kh0, qlo[0], a);
      c = mfma16(kh1, qlo[1], c);
      a = mfma16(kl0, qhi[0], a);
      c = mfma16(kl1, qhi[1], c);
#pragma unroll
      for (int r = 0; r < 4; ++r) a[r] += c[r];
      l4[tt] = a;
    }

    // stats: per-n max over this wave's 128 m (4-lane group), raw sum (wave)
    float pm = -3.4e38f, es = 0.f;
#pragma unroll
    for (int tt = 0; tt < 8; ++tt) {
#pragma unroll
      for (int r = 0; r < 4; ++r) { pm = fmaxf(pm, l4[tt][r]); es += l4[tt][r]; }
    }
    pm = fmaxf(pm, __shfl_xor(pm, 16, 64));
    pm = fmaxf(pm, __shfl_xor(pm, 32, 64));
    es = wred_sum(es);
    if (lane < 16) redmx[wv * 16 + lane] = pm;
    if (lane == 0) redes[wv] = es;
    __syncthreads();
    float mx = redmx[nl];
#pragma unroll
    for (int w = 1; w < 8; ++w) mx = fmaxf(mx, redmx[w * 16 + nl]);
    if (t == 0) {
      float s = 0.f;
#pragma unroll
      for (int w = 0; w < 8; ++w) s += redes[w];
      atomicAdd(esum_pam + i * 3 + j, s);
    }

    float ps = 0.f;
#pragma unroll
    for (int tt = 0; tt < 8; ++tt) {
#pragma unroll
      for (int r = 0; r < 4; ++r) {
        l4[tt][r] = __expf(l4[tt][r] - mx);
        ps += l4[tt][r];
      }
    }
    ps += __shfl_xor(ps, 16, 64);
    ps += __shfl_xor(ps, 32, 64);
    if (lane < 16) redse[wv * 16 + lane] = ps;
    __syncthreads();
    float den = redse[nl];
#pragma unroll
    for (int w = 1; w < 8; ++w) den += redse[w * 16 + nl];
    const float rs = 1.f / den;

    // normalize, convert, stage P (bf16, swizzled)
#pragma unroll
    for (int tt = 0; tt < 8; ++tt) {
      const int m = wm0 + tt * 16 + g16 * 4;
      uint2 w2;
      w2.x = pkbf(l4[tt][0] * rs, l4[tt][1] * rs);
      w2.y = pkbf(l4[tt][2] * rs, l4[tt][3] * rs);
      *reinterpret_cast<uint2*>(&Plds[nl * 1024 + (m ^ (nl * 8))]) = w2;
    }
    __syncthreads();

    // PV: this wave covers c-tile ct, m in [mh*512, mh*512+512)
#pragma unroll 2
    for (int ks = 0; ks < 16; ks += 2) {
      const int ml0 = mh * 512 + ks * 32 + g16 * 8;
      const int ml1 = ml0 + 32;
      const short8 va0 = bcs8(*reinterpret_cast<const uint4*>(vg + ks * 32));
      const short8 pf0 = bcs8(*reinterpret_cast<const uint4*>(&Plds[nl * 1024 + (ml0 ^ (nl * 8))]));
      const short8 va1 = bcs8(*reinterpret_cast<const uint4*>(vg + ks * 32 + 32));
      const short8 pf1 = bcs8(*reinterpret_cast<const uint4*>(&Plds[nl * 1024 + (ml1 ^ (nl * 8))]));
      oa = mfma16(va0, pf0, oa);
      ob = mfma16(va1, pf1, ob);
    }
  }

#pragma unroll
  for (int r = 0; r < 4; ++r) oa[r] += ob[r];

  // combine m-halves through LDS, fuse with out_cam, write tgts even slot
  if (mh == 0) {
#pragma unroll
    for (int r = 0; r < 4; ++r)
      osum[(ct * 16 + g16 * 4 + r) * 16 + nl] = oa[r];
  }
  __syncthreads();
  if (mh == 1) {
    const float* og = ocam + ibo;
    float* outg = tgts + (size_t)(2 * i * 8 + b) * PLANE;
#pragma unroll
    for (int r = 0; r < 4; ++r) {
      const int c = ct * 16 + g16 * 4 + r;
      const int idx = c * N_ + n0 + nl;
      outg[idx] = 0.5f * (oa[r] + osum[c * 16 + nl] + og[idx]);
    }
  }
}

// ---------------------------------------------------------------------------
// alpha[i][j] = 0.5*(softmax_j(mean e_pam) + softmax_j(mean e_cam))
// ---------------------------------------------------------------------------
__global__ void alpha_kernel(const float* __restrict__ esum, float* __restrict__ alpha)
{
  const int t = threadIdx.x;
  if (t >= 9) return;
  const int i = t / 3, j = t % 3;
  float p[3], c[3];
#pragma unroll
  for (int jj = 0; jj < 3; ++jj) {
    p[jj] = esum[i * 3 + jj] * (1.0f / 8388608.0f);
    c[jj] = esum[9 + i * 3 + jj] * (1.0f / 32768.0f);
  }
  const float mp = fmaxf(p[0], fmaxf(p[1], p[2]));
  const float mc = fmaxf(c[0], fmaxf(c[1], c[2]));
  float sp = 0.f, sc = 0.f;
#pragma unroll
  for (int jj = 0; jj < 3; ++jj) { sp += __expf(p[jj] - mp); sc += __expf(c[jj] - mc); }
  alpha[t] = 0.5f * (__expf(p[j] - mp) / sp + __expf(c[j] - mc) / sc);
}

// ---------------------------------------------------------------------------
extern "C" void kernel_launch(void* const* d_in, const int* in_sizes, int n_in,
                              void* d_out, int out_size, void* d_ws, size_t ws_size,
                              hipStream_t stream)
{
  const float* src0 = (const float*)d_in[0];
  const float* src1 = (const float*)d_in[1];
  const float* src2 = (const float*)d_in[2];
  const float* tgt0 = (const float*)d_in[3];
  const float* tgt1 = (const float*)d_in[4];
  const float* tgt2 = (const float*)d_in[5];
  const float* fs0_w = (const float*)d_in[6];  const float* fs0_b = (const float*)d_in[7];
  const float* fs1_w = (const float*)d_in[8];  const float* fs1_b = (const float*)d_in[9];
  const float* fs2_w = (const float*)d_in[10]; const float* fs2_b = (const float*)d_in[11];
  const float* ft0_w = (const float*)d_in[12]; const float* ft0_b = (const float*)d_in[13];
  const float* ft1_w = (const float*)d_in[14]; const float* ft1_b = (const float*)d_in[15];
  const float* ft2_w = (const float*)d_in[16]; const float* ft2_b = (const float*)d_in[17];
  const float* pq_w = (const float*)d_in[18];  const float* pq_b = (const float*)d_in[19];
  const float* pk_w = (const float*)d_in[20];  const float* pk_b = (const float*)d_in[21];
  const float* pv_w = (const float*)d_in[22];  const float* pv_b = (const float*)d_in[23];
  const float* cv_w = (const float*)d_in[24];  const float* cv_b = (const float*)d_in[25];

  float* out = (float*)d_out;
  float* S     = out;                 // srcs region doubles as S storage
  float* alpha = out + SZ;            // 9 floats
  float* tgts  = out + SZ + 9;        // [2L][B][PLANE]

  float* ws   = (float*)d_ws;
  float* T    = ws;
  float* qb   = ws + (size_t)SZ;
  float* kb   = ws + (size_t)2 * SZ;
  float* vb   = ws + (size_t)3 * SZ;
  float* vcb  = ws + (size_t)4 * SZ;
  float* ocam = ws + (size_t)5 * SZ;
  float* ecam = ws + (size_t)6 * SZ;                 // 294912
  float* acam = ws + (size_t)6 * SZ + 294912;        // 98304
  float* esum = ws + (size_t)6 * SZ + 393216;        // 18 (pam 9, cam 9)

  // bf16 buffers appended after the fp32 region
  unsigned short* kTh = (unsigned short*)(ws + (size_t)6 * SZ + 393216 + 256);
  unsigned short* kTl = kTh + (size_t)24 * PLANE;
  unsigned short* vbf = kTl + (size_t)24 * PLANE;

  // Transposed conv0 weights live temporarily in qb (overwritten later by q proj)
  float* wTs = qb;
  float* wTt = qb + 73728;

  hipMemsetAsync(esum, 0, 18 * sizeof(float), stream);

  // Pre-transpose the 3x3 weights for coalesced, math-free LDS staging
  wtrans_kernel<<<dim3(288, 2), 256, 0, stream>>>(fs0_w, ft0_w, wTs, wTt);

  // Fit convs (S goes straight into d_out; T dual-written into tgts odd slots)
  conv0_kernel<<<dim3(128, 2, 2), 256, 0, stream>>>(
      src0, wTs, fs0_b, S, nullptr,
      tgt0, wTt, ft0_b, T, tgts + (size_t)1 * BPL);
  gemm64_kernel<<<dim3(8, 16), 256, 0, stream>>>(fs1_w, 0, 1, src1, 256 * N_, S + BPL, PLANE,
                                                 nullptr, 0, fs1_b, 0, 256);
  gemm64_kernel<<<dim3(8, 16), 256, 0, stream>>>(fs2_w, 0, 1, src2, 512 * N_, S + 2 * BPL, PLANE,
                                                 nullptr, 0, fs2_b, 0, 512);
  gemm64_kernel<<<dim3(8, 16), 256, 0, stream>>>(ft1_w, 0, 1, tgt1, 256 * N_, T + BPL, PLANE,
                                                 tgts + (size_t)3 * BPL, PLANE, ft1_b, 0, 256);
  gemm64_kernel<<<dim3(8, 16), 256, 0, stream>>>(ft2_w, 0, 1, tgt2, 512 * N_, T + 2 * BPL, PLANE,
                                                 tgts + (size_t)5 * BPL, PLANE, ft2_b, 0, 512);

  // Projections q,k,v,vc
  gemm64_kernel<<<dim3(24, 16), 256, 0, stream>>>(pq_w, 4096, 8, T, PLANE, qb, PLANE,
                                                  nullptr, 0, pq_b, 64, 64);
  gemm64_kernel<<<dim3(24, 16), 256, 0, stream>>>(pk_w, 4096, 8, S, PLANE, kb, PLANE,
                                                  nullptr, 0, pk_b, 64, 64);
  gemm64_kernel<<<dim3(24, 16), 256, 0, stream>>>(pv_w, 4096, 8, T, PLANE, vb, PLANE,
                                                  nullptr, 0, pv_b, 64, 64);
  gemm64_kernel<<<dim3(24, 16), 256, 0, stream>>>(cv_w, 4096, 8, T, PLANE, vcb, PLANE,
                                                  nullptr, 0, cv_b, 64, 64);

  // Pack k (transposed, split-bf16) and v (bf16) for the MFMA attention
  kprep_kernel<<<dim3(24, 4), 256, 0, stream>>>(kb, vb, kTh, kTl, vbf);

  // CAM
  ecam_kernel<<<72, 256, 0, stream>>>(T, S, ecam, esum + 9);
  acam_kernel<<<24, 256, 0, stream>>>(ecam, acam);
  gemm64_kernel<<<dim3(24, 16), 256, 0, stream>>>(acam, 4096, 1, vcb, PLANE, ocam, PLANE,
                                                  nullptr, 0, nullptr, 0, 64);

  // PAM + fuse (writes tgts even slots = 0.5*(out_pam + out_cam))
  pam_mfma_kernel<<<1536, 512, 0, stream>>>(qb, kTh, kTl, vbf, ocam, tgts, esum);

  alpha_kernel<<<1, 64, 0, stream>>>(esum, alpha);
}

// Round 9
// 434.407 us; speedup vs baseline: 1.3272x; 1.1523x over previous
//
#include <hip/hip_runtime.h>

// Problem constants
static constexpr int L_ = 3, B_ = 8, C_ = 64, N_ = 1024;
static constexpr int PLANE = C_ * N_;       // 65536
static constexpr int SZ    = L_ * B_ * PLANE; // 1572864 (srcs size, also per-stack-slot count)
static constexpr int BPL   = B_ * PLANE;    // 524288

#define DI __device__ __forceinline__

typedef _Float16 h8 __attribute__((ext_vector_type(8)));   // 8 fp16 (MFMA A/B frag)
typedef __attribute__((ext_vector_type(4))) float f32x4;   // MFMA C/D frag
typedef unsigned int uint32;

DI float wred_sum(float v) {
#pragma unroll
  for (int m = 1; m < 64; m <<= 1) v += __shfl_xor(v, m, 64);
  return v;
}

// fp16 helpers (RNE via v_cvt_f16_f32)
DI uint32 pkh(float a, float b) {
  const _Float16 ha = (_Float16)a, hb = (_Float16)b;
  return (uint32)__builtin_bit_cast(unsigned short, ha) |
         ((uint32)__builtin_bit_cast(unsigned short, hb) << 16);
}
DI h8 bch8(uint4 v) { return __builtin_bit_cast(h8, v); }

DI f32x4 mfmah(h8 a, h8 b, f32x4 c) {
  return __builtin_amdgcn_mfma_f32_16x16x32_f16(a, b, c, 0, 0, 0);
}

// ---------------------------------------------------------------------------
// Weight transpose: w[co][ci][k9] -> wT[ci][k9][co]  (64 x 128 x 9 each)
// grid (288, 2)
// ---------------------------------------------------------------------------
__global__ __launch_bounds__(256) void wtrans_kernel(
    const float* __restrict__ w_s, const float* __restrict__ w_t,
    float* __restrict__ wT_s, float* __restrict__ wT_t)
{
  const float* w = blockIdx.y ? w_t : w_s;
  float* wT = blockIdx.y ? wT_t : wT_s;
  const int e = blockIdx.x * 256 + threadIdx.x;   // 0..73727
  const int co = e & 63;
  const int q = e >> 6;
  const int k9 = q % 9;
  const int ci = q / 9;
  wT[e] = w[(co * 128 + ci) * 9 + k9];
}

// ---------------------------------------------------------------------------
// conv0: 3x3 stride-2 pad-1, Cin=128 -> Cout=64, 64x64 -> 32x32.
// grid (128, 2, 2): x = b*16 + 2-row slab, y = co-half, z = (src,tgt).
// ---------------------------------------------------------------------------
__global__ __launch_bounds__(256) void conv0_kernel(
    const float* __restrict__ in_s, const float* __restrict__ wT_s, const float* __restrict__ b_s,
    float* __restrict__ outA_s, float* __restrict__ outB_s,
    const float* __restrict__ in_t, const float* __restrict__ wT_t, const float* __restrict__ b_t,
    float* __restrict__ outA_t, float* __restrict__ outB_t)
{
  const int tsel = blockIdx.z;
  const int ch   = blockIdx.y;      // co half: co in [ch*32, ch*32+32)
  const float* in   = tsel ? in_t  : in_s;
  const float* wT   = tsel ? wT_t  : wT_s;
  const float* bias = tsel ? b_t   : b_s;
  float* outA = tsel ? outA_t : outA_s;
  float* outB = tsel ? outB_t : outB_s;

  const int bx = blockIdx.x;
  const int b  = bx >> 4;
  const int y0 = (bx & 15) * 2;
  const int t  = threadIdx.x;
  const int x  = t & 31;
  const int cg = t >> 5;            // 0..7 -> co = ch*32 + cg*4 .. +3

  __shared__ float wch[2304];       // [cc][k9][cl<32] flat
  __shared__ float inch[8][5][64];  // [ci_chunk][row][ix]

  float acc[2][4];
#pragma unroll
  for (int yy = 0; yy < 2; ++yy)
#pragma unroll
    for (int o = 0; o < 4; ++o) acc[yy][o] = 0.f;

  for (int ci0 = 0; ci0 < 128; ci0 += 8) {
    __syncthreads();
    // Weights for this co-half: 2304 floats, 32-float coalesced runs
#pragma unroll 3
    for (int r = 0; r < 9; ++r) {
      const int e = t + 256 * r;
      const int cc = e / 288;
      const int rem = e - cc * 288;
      const int k9 = rem >> 5;
      const int cl = rem & 31;
      wch[e] = wT[(ci0 + cc) * 576 + k9 * 64 + ch * 32 + cl];
    }
    // Inputs: 8 ci x 5 rows x 64 x, coalesced over x
#pragma unroll 2
    for (int r = 0; r < 10; ++r) {
      const int e = t + 256 * r;
      const int ix = e & 63;
      const int q = e >> 6;         // 0..39
      const int ry = q % 5;
      const int cc = q / 5;
      const int iy = 2 * y0 - 1 + ry;
      float v = 0.f;
      if (iy >= 0 && iy < 64) v = in[((b * 128 + ci0 + cc) * 64 + iy) * 64 + ix];
      inch[cc][ry][ix] = v;
    }
    __syncthreads();
#pragma unroll 1
    for (int cc = 0; cc < 8; ++cc) {
      float iv[5][3];
#pragma unroll
      for (int ry = 0; ry < 5; ++ry) {
#pragma unroll
        for (int kx = 0; kx < 3; ++kx) {
          const int ix = 2 * x + kx - 1;   // [-1, 63]
          iv[ry][kx] = (ix >= 0) ? inch[cc][ry][ix] : 0.f;
        }
      }
#pragma unroll
      for (int ky = 0; ky < 3; ++ky) {
#pragma unroll
        for (int kx = 0; kx < 3; ++kx) {
          const int k9 = ky * 3 + kx;
          const float4 w4 = *reinterpret_cast<const float4*>(&wch[(cc * 9 + k9) * 32 + cg * 4]);
          const float wv[4] = {w4.x, w4.y, w4.z, w4.w};
          const float i0 = iv[ky][kx];
          const float i1 = iv[ky + 2][kx];
#pragma unroll
          for (int o = 0; o < 4; ++o) {
            acc[0][o] = fmaf(i0, wv[o], acc[0][o]);
            acc[1][o] = fmaf(i1, wv[o], acc[1][o]);
          }
        }
      }
    }
  }
#pragma unroll
  for (int o = 0; o < 4; ++o) {
    const int co = ch * 32 + cg * 4 + o;
    const float bv = bias[co];
#pragma unroll
    for (int yy = 0; yy < 2; ++yy) {
      const int idx = (b * 64 + co) * 1024 + (y0 + yy) * 32 + x;
      const float val = acc[yy][o] + bv;
      outA[idx] = val;
      if (outB) outB[idx] = val;
    }
  }
}

// ---------------------------------------------------------------------------
// Generic out[g][64][1024] = W[g/wdiv][64][K] @ X[g][K][1024] + bias
// ---------------------------------------------------------------------------
__global__ __launch_bounds__(256) void gemm64_kernel(
    const float* __restrict__ W, int wstride, int wdiv,
    const float* __restrict__ X, int xstride,
    float* __restrict__ out, int ostride,
    float* __restrict__ out2, int o2stride,
    const float* __restrict__ bias, int bstride,
    int K)
{
  const int g  = blockIdx.x;
  const int n0 = blockIdx.y * 64;
  const float* Wg = W + (size_t)(g / wdiv) * wstride;
  const float* Xg = X + (size_t)g * xstride;
  const int t = threadIdx.x;
  __shared__ float Xs[32][64];
  __shared__ float Ws[32][64];
  const int tn = t & 15, cgp = t >> 4;
  const int n4 = tn * 4, co4 = cgp * 4;
  float acc[4][4] = {};

  for (int k0 = 0; k0 < K; k0 += 32) {
    {
      const int kk = t >> 4;
      const int nn = (t & 15) * 4;
      *reinterpret_cast<float4*>(&Xs[kk][nn]) =
          *reinterpret_cast<const float4*>(Xg + (size_t)(k0 + kk) * N_ + n0 + nn);
      *reinterpret_cast<float4*>(&Xs[kk + 16][nn]) =
          *reinterpret_cast<const float4*>(Xg + (size_t)(k0 + kk + 16) * N_ + n0 + nn);
    }
    {
      const int co = t & 63, q4 = t >> 6;
      const float* wp = Wg + (size_t)co * K + k0 + q4 * 8;
      const float4 a = *reinterpret_cast<const float4*>(wp);
      const float4 c = *reinterpret_cast<const float4*>(wp + 4);
      const int kb = q4 * 8;
      Ws[kb + 0][co] = a.x; Ws[kb + 1][co] = a.y; Ws[kb + 2][co] = a.z; Ws[kb + 3][co] = a.w;
      Ws[kb + 4][co] = c.x; Ws[kb + 5][co] = c.y; Ws[kb + 6][co] = c.z; Ws[kb + 7][co] = c.w;
    }
    __syncthreads();
#pragma unroll
    for (int kk = 0; kk < 32; ++kk) {
      const float4 xv = *reinterpret_cast<const float4*>(&Xs[kk][n4]);
      const float4 wv = *reinterpret_cast<const float4*>(&Ws[kk][co4]);
      const float xa[4] = {xv.x, xv.y, xv.z, xv.w};
      const float wa[4] = {wv.x, wv.y, wv.z, wv.w};
#pragma unroll
      for (int a = 0; a < 4; ++a)
#pragma unroll
        for (int b2 = 0; b2 < 4; ++b2)
          acc[a][b2] = fmaf(wa[a], xa[b2], acc[a][b2]);
    }
    __syncthreads();
  }

  float bv[4] = {0.f, 0.f, 0.f, 0.f};
  if (bias) {
    const float* bg = bias + (size_t)(g / wdiv) * bstride;
    bv[0] = bg[co4]; bv[1] = bg[co4 + 1]; bv[2] = bg[co4 + 2]; bv[3] = bg[co4 + 3];
  }
#pragma unroll
  for (int ii = 0; ii < 4; ++ii) {
    float4 o4;
    o4.x = acc[ii][0] + bv[ii]; o4.y = acc[ii][1] + bv[ii];
    o4.z = acc[ii][2] + bv[ii]; o4.w = acc[ii][3] + bv[ii];
    const int idx = (co4 + ii) * N_ + n0 + n4;
    *reinterpret_cast<float4*>(out + (size_t)g * ostride + idx) = o4;
    if (out2) {
      float* o2 = out2 + (size_t)g * o2stride + idx;
      o2[0] = o4.x; o2[1] = o4.y; o2[2] = o4.z; o2[3] = o4.w;
    }
  }
}

// ---------------------------------------------------------------------------
// kprep: k[g][64c][1024m] -> kT[g][1024m][64c] (fp16);  v[g] -> vh[g] (fp16).
// grid (24, 4): per block 256-m chunk.
// ---------------------------------------------------------------------------
__global__ __launch_bounds__(256) void kprep_kernel(
    const float* __restrict__ kb, const float* __restrict__ vb,
    unsigned short* __restrict__ kT, unsigned short* __restrict__ vh)
{
  const int g = blockIdx.x;
  const int ch = blockIdx.y;
  const int t = threadIdx.x;
  const float* kg = kb + (size_t)g * PLANE;
  __shared__ float tl[64][65];

#pragma unroll 1
  for (int tile = 0; tile < 4; ++tile) {
    const int m0 = ch * 256 + tile * 64;
    __syncthreads();
#pragma unroll 4
    for (int r = 0; r < 16; ++r) {
      const int c = r * 4 + (t >> 6);
      tl[c][t & 63] = kg[c * N_ + m0 + (t & 63)];
    }
    __syncthreads();
    const int mm = t >> 2, cseg = (t & 3) * 16;
    uint32 hw[8];
#pragma unroll
    for (int ii = 0; ii < 8; ++ii)
      hw[ii] = pkh(tl[cseg + 2 * ii][mm], tl[cseg + 2 * ii + 1][mm]);
    const size_t o = ((size_t)g * 1024 + m0 + mm) * 64 + cseg;
    uint4 h0; h0.x = hw[0]; h0.y = hw[1]; h0.z = hw[2]; h0.w = hw[3];
    uint4 h1; h1.x = hw[4]; h1.y = hw[5]; h1.z = hw[6]; h1.w = hw[7];
    *reinterpret_cast<uint4*>(kT + o)     = h0;
    *reinterpret_cast<uint4*>(kT + o + 8) = h1;
  }

  // v -> fp16 (8 elems/thread/iter, packed 16B stores)
  const float* vg = vb + (size_t)g * PLANE;
  unsigned short* vo = vh + (size_t)g * PLANE;
  for (int e8 = ch * 2048 + t; e8 < (ch + 1) * 2048; e8 += 256) {
    const float4 a = *reinterpret_cast<const float4*>(vg + (size_t)e8 * 8);
    const float4 b = *reinterpret_cast<const float4*>(vg + (size_t)e8 * 8 + 4);
    uint4 u;
    u.x = pkh(a.x, a.y); u.y = pkh(a.z, a.w);
    u.z = pkh(b.x, b.y); u.w = pkh(b.z, b.w);
    *reinterpret_cast<uint4*>(vo + (size_t)e8 * 8) = u;
  }
}

// ---------------------------------------------------------------------------
// e_cam[i,j,b][c][d] = sum_n T[i,b,c,n] * S[j,b,d,n];  also atomic raw-sum.
// ---------------------------------------------------------------------------
__global__ __launch_bounds__(256) void ecam_kernel(
    const float* __restrict__ T, const float* __restrict__ S,
    float* __restrict__ ecam, float* __restrict__ esum_cam)
{
  const int bx = blockIdx.x;
  const int b = bx & 7;
  const int j = (bx >> 3) % 3;
  const int i = bx / 24;
  const float* Tg = T + (size_t)(i * 8 + b) * PLANE;
  const float* Sg = S + (size_t)(j * 8 + b) * PLANE;
  const int t = threadIdx.x;
  __shared__ float Ts[64 * 68];
  __shared__ float Ss[64 * 68];
  __shared__ float rs[4];
  float acc[4][4] = {};
  const int c0 = (t & 15) * 4, d0 = (t >> 4) * 4;

  for (int nb = 0; nb < 1024; nb += 64) {
    __syncthreads();
    {
      const int nn = t & 63, rb = t >> 6;
#pragma unroll
      for (int r = 0; r < 16; ++r) {
        const int row = rb * 16 + r;
        Ts[nn * 68 + row] = Tg[row * N_ + nb + nn];
        Ss[nn * 68 + row] = Sg[row * N_ + nb + nn];
      }
    }
    __syncthreads();
#pragma unroll 8
    for (int nn = 0; nn < 64; ++nn) {
      const float4 tv = *reinterpret_cast<const float4*>(&Ts[nn * 68 + c0]);
      const float4 sv = *reinterpret_cast<const float4*>(&Ss[nn * 68 + d0]);
      const float ta[4] = {tv.x, tv.y, tv.z, tv.w};
      const float sa[4] = {sv.x, sv.y, sv.z, sv.w};
#pragma unroll
      for (int ci = 0; ci < 4; ++ci)
#pragma unroll
        for (int di = 0; di < 4; ++di)
          acc[ci][di] = fmaf(ta[ci], sa[di], acc[ci][di]);
    }
  }
  float s = 0.f;
#pragma unroll
  for (int ci = 0; ci < 4; ++ci)
#pragma unroll
    for (int di = 0; di < 4; ++di) s += acc[ci][di];
  s = wred_sum(s);
  if ((t & 63) == 0) rs[t >> 6] = s;
  __syncthreads();
  if (t == 0) atomicAdd(esum_cam + i * 3 + j, rs[0] + rs[1] + rs[2] + rs[3]);

  float* eo = ecam + (size_t)((i * 3 + j) * 8 + b) * 4096;
#pragma unroll
  for (int ci = 0; ci < 4; ++ci) {
    float4 o4; o4.x = acc[ci][0]; o4.y = acc[ci][1]; o4.z = acc[ci][2]; o4.w = acc[ci][3];
    *reinterpret_cast<float4*>(eo + (c0 + ci) * 64 + d0) = o4;
  }
}

// ---------------------------------------------------------------------------
// attn_cam[i,b][c][d] = sum_j softmax_d(e_cam[i,j,b,c,:])[d]     grid 24
// ---------------------------------------------------------------------------
__global__ __launch_bounds__(256) void acam_kernel(
    const float* __restrict__ ecam, float* __restrict__ acam)
{
  const int bx = blockIdx.x;
  const int b = bx & 7, i = bx >> 3;
  const int t = threadIdx.x;
  const int c = t >> 2, seg = t & 3;
  float acc[16] = {};
#pragma unroll
  for (int j = 0; j < 3; ++j) {
    const float* e = ecam + (size_t)((i * 3 + j) * 8 + b) * 4096 + c * 64 + seg * 16;
    float ev[16];
#pragma unroll
    for (int r = 0; r < 4; ++r) {
      const float4 v4 = *reinterpret_cast<const float4*>(e + r * 4);
      ev[4 * r] = v4.x; ev[4 * r + 1] = v4.y; ev[4 * r + 2] = v4.z; ev[4 * r + 3] = v4.w;
    }
    float mx = ev[0];
#pragma unroll
    for (int r = 1; r < 16; ++r) mx = fmaxf(mx, ev[r]);
    mx = fmaxf(mx, __shfl_xor(mx, 1, 4));
    mx = fmaxf(mx, __shfl_xor(mx, 2, 4));
    float pv[16], ss = 0.f;
#pragma unroll
    for (int r = 0; r < 16; ++r) { pv[r] = __expf(ev[r] - mx); ss += pv[r]; }
    ss += __shfl_xor(ss, 1, 4);
    ss += __shfl_xor(ss, 2, 4);
    const float rc = 1.f / ss;
#pragma unroll
    for (int r = 0; r < 16; ++r) acc[r] += pv[r] * rc;
  }
  float* ao = acam + (size_t)(i * 8 + b) * 4096 + c * 64 + seg * 16;
#pragma unroll
  for (int r = 0; r < 4; ++r) {
    float4 o4; o4.x = acc[4 * r]; o4.y = acc[4 * r + 1]; o4.z = acc[4 * r + 2]; o4.w = acc[4 * r + 3];
    *reinterpret_cast<float4*>(ao + r * 4) = o4;
  }
}

// ---------------------------------------------------------------------------
// PAM via single-pass fp16 MFMA. grid 1536 = (i, b, qt), 512 threads (8 waves
// x 128 m). Per j: QK logits (16 loads, 16 MFMA, unroll-4 -> 8-load windows)
// -> block softmax (2 barriers) -> stage UNNORMALIZED P (fp16, swizzled LDS)
// -> PV MFMA; 1/den applied to PV output per lane (D col == n == lane&15).
// ---------------------------------------------------------------------------
__global__ __launch_bounds__(512, 4) void pam_mfma_kernel(
    const float* __restrict__ q, const unsigned short* __restrict__ kT,
    const unsigned short* __restrict__ vh,
    const float* __restrict__ ocam, float* __restrict__ tgts, float* __restrict__ esum_pam)
{
  const int bx = blockIdx.x;
  const int qt = bx & 63;
  const int b  = (bx >> 6) & 7;
  const int i  = bx >> 9;
  const int n0 = qt * 16;
  const int t = threadIdx.x;
  const int lane = t & 63;
  const int wv = t >> 6;             // 0..7
  const int nl = lane & 15;          // n within tile (operand col / D col)
  const int g16 = lane >> 4;         // k-group

  __shared__ unsigned short Plds[16 * 1024];  // 32 KB fp16, [n][m ^ (8n)]
  __shared__ float qlds[64 * 17];
  __shared__ float redmx[128];
  __shared__ float redse[128];
  __shared__ float redes[8];
  __shared__ float osum[64 * 16];             // m-half combine buffer

  const size_t ibo = (size_t)(i * 8 + b) * PLANE;

  // stage q tile [64c][16n]
  const float* qg = q + ibo;
  for (int e = t; e < 1024; e += 512)
    qlds[(e >> 4) * 17 + (e & 15)] = qg[(e >> 4) * N_ + n0 + (e & 15)];
  __syncthreads();

  // Q B-fragments (fp16): col n = nl, k(c) = ks*32 + g16*8 + idx
  h8 qh[2];
#pragma unroll
  for (int ks = 0; ks < 2; ++ks) {
#pragma unroll
    for (int idx = 0; idx < 8; ++idx)
      qh[ks][idx] = (_Float16)qlds[(ks * 32 + g16 * 8 + idx) * 17 + nl];
  }

  const int wm0 = wv * 128;          // wave's m-range base (QK)
  const int ct = wv & 3;             // PV c-tile
  const int mh = wv >> 2;            // PV m-half
  const unsigned short* vg = vh + ibo + (size_t)(ct * 16 + nl) * 1024 + mh * 512 + g16 * 8;
  f32x4 oat = f32x4{0.f, 0.f, 0.f, 0.f};

#pragma unroll 1
  for (int j = 0; j < 3; ++j) {
    const unsigned short* kp =
        kT + ((size_t)(j * 8 + b) * 1024 + wm0 + nl) * 64 + g16 * 8;

    f32x4 l4[8];
#pragma unroll 4
    for (int tt = 0; tt < 8; ++tt) {
      const int off = tt * 1024;  // 16 m-rows * 64 c (halves)
      const uint4 k0 = *reinterpret_cast<const uint4*>(kp + off);
      const uint4 k1 = *reinterpret_cast<const uint4*>(kp + off + 32);
      f32x4 a = f32x4{0.f, 0.f, 0.f, 0.f};
      a = mfmah(bch8(k0), qh[0], a);
      a = mfmah(bch8(k1), qh[1], a);
      l4[tt] = a;
    }

    // stats: per-n max over this wave's 128 m (4-lane group), raw sum (wave)
    float pm = -3.4e38f, es = 0.f;
#pragma unroll
    for (int tt = 0; tt < 8; ++tt) {
#pragma unroll
      for (int r = 0; r < 4; ++r) { pm = fmaxf(pm, l4[tt][r]); es += l4[tt][r]; }
    }
    pm = fmaxf(pm, __shfl_xor(pm, 16, 64));
    pm = fmaxf(pm, __shfl_xor(pm, 32, 64));
    es = wred_sum(es);
    if (lane < 16) redmx[wv * 16 + lane] = pm;
    if (lane == 0) redes[wv] = es;
    __syncthreads();   // sync1: mx ready; also guarantees prior PV reads done
    float mx = redmx[nl];
#pragma unroll
    for (int w = 1; w < 8; ++w) mx = fmaxf(mx, redmx[w * 16 + nl]);
    if (t == 0) {
      float s = 0.f;
#pragma unroll
      for (int w = 0; w < 8; ++w) s += redes[w];
      atomicAdd(esum_pam + i * 3 + j, s);
    }

    // exp (unnormalized, <= 1), stage P, then publish per-wave sums
    float ps = 0.f;
#pragma unroll
    for (int tt = 0; tt < 8; ++tt) {
#pragma unroll
      for (int r = 0; r < 4; ++r) {
        l4[tt][r] = __expf(l4[tt][r] - mx);
        ps += l4[tt][r];
      }
    }
#pragma unroll
    for (int tt = 0; tt < 8; ++tt) {
      const int m = wm0 + tt * 16 + g16 * 4;
      uint2 w2;
      w2.x = pkh(l4[tt][0], l4[tt][1]);
      w2.y = pkh(l4[tt][2], l4[tt][3]);
      *reinterpret_cast<uint2*>(&Plds[nl * 1024 + (m ^ (nl * 8))]) = w2;
    }
    ps += __shfl_xor(ps, 16, 64);
    ps += __shfl_xor(ps, 32, 64);
    if (lane < 16) redse[wv * 16 + lane] = ps;
    __syncthreads();   // sync2: P staged + den ready
    float den = redse[nl];
#pragma unroll
    for (int w = 1; w < 8; ++w) den += redse[w * 16 + nl];
    const float rs = 1.f / den;

    // PV: this wave covers c-tile ct, m in [mh*512, mh*512+512)
    f32x4 oa = f32x4{0.f, 0.f, 0.f, 0.f};
    f32x4 ob = f32x4{0.f, 0.f, 0.f, 0.f};
#pragma unroll 4
    for (int ks = 0; ks < 16; ks += 2) {
      const int ml0 = mh * 512 + ks * 32 + g16 * 8;
      const int ml1 = ml0 + 32;
      const uint4 va0 = *reinterpret_cast<const uint4*>(vg + ks * 32);
      const uint4 pf0 = *reinterpret_cast<const uint4*>(&Plds[nl * 1024 + (ml0 ^ (nl * 8))]);
      const uint4 va1 = *reinterpret_cast<const uint4*>(vg + ks * 32 + 32);
      const uint4 pf1 = *reinterpret_cast<const uint4*>(&Plds[nl * 1024 + (ml1 ^ (nl * 8))]);
      oa = mfmah(bch8(va0), bch8(pf0), oa);
      ob = mfmah(bch8(va1), bch8(pf1), ob);
    }
#pragma unroll
    for (int r = 0; r < 4; ++r) oat[r] += rs * (oa[r] + ob[r]);
  }

  // combine m-halves through LDS, fuse with out_cam, write tgts even slot
  if (mh == 0) {
#pragma unroll
    for (int r = 0; r < 4; ++r)
      osum[(ct * 16 + g16 * 4 + r) * 16 + nl] = oat[r];
  }
  __syncthreads();
  if (mh == 1) {
    const float* og = ocam + ibo;
    float* outg = tgts + (size_t)(2 * i * 8 + b) * PLANE;
#pragma unroll
    for (int r = 0; r < 4; ++r) {
      const int c = ct * 16 + g16 * 4 + r;
      const int idx = c * N_ + n0 + nl;
      outg[idx] = 0.5f * (oat[r] + osum[c * 16 + nl] + og[idx]);
    }
  }
}

// ---------------------------------------------------------------------------
// alpha[i][j] = 0.5*(softmax_j(mean e_pam) + softmax_j(mean e_cam))
// ---------------------------------------------------------------------------
__global__ void alpha_kernel(const float* __restrict__ esum, float* __restrict__ alpha)
{
  const int t = threadIdx.x;
  if (t >= 9) return;
  const int i = t / 3, j = t % 3;
  float p[3], c[3];
#pragma unroll
  for (int jj = 0; jj < 3; ++jj) {
    p[jj] = esum[i * 3 + jj] * (1.0f / 8388608.0f);
    c[jj] = esum[9 + i * 3 + jj] * (1.0f / 32768.0f);
  }
  const float mp = fmaxf(p[0], fmaxf(p[1], p[2]));
  const float mc = fmaxf(c[0], fmaxf(c[1], c[2]));
  float sp = 0.f, sc = 0.f;
#pragma unroll
  for (int jj = 0; jj < 3; ++jj) { sp += __expf(p[jj] - mp); sc += __expf(c[jj] - mc); }
  alpha[t] = 0.5f * (__expf(p[j] - mp) / sp + __expf(c[j] - mc) / sc);
}

// ---------------------------------------------------------------------------
extern "C" void kernel_launch(void* const* d_in, const int* in_sizes, int n_in,
                              void* d_out, int out_size, void* d_ws, size_t ws_size,
                              hipStream_t stream)
{
  const float* src0 = (const float*)d_in[0];
  const float* src1 = (const float*)d_in[1];
  const float* src2 = (const float*)d_in[2];
  const float* tgt0 = (const float*)d_in[3];
  const float* tgt1 = (const float*)d_in[4];
  const float* tgt2 = (const float*)d_in[5];
  const float* fs0_w = (const float*)d_in[6];  const float* fs0_b = (const float*)d_in[7];
  const float* fs1_w = (const float*)d_in[8];  const float* fs1_b = (const float*)d_in[9];
  const float* fs2_w = (const float*)d_in[10]; const float* fs2_b = (const float*)d_in[11];
  const float* ft0_w = (const float*)d_in[12]; const float* ft0_b = (const float*)d_in[13];
  const float* ft1_w = (const float*)d_in[14]; const float* ft1_b = (const float*)d_in[15];
  const float* ft2_w = (const float*)d_in[16]; const float* ft2_b = (const float*)d_in[17];
  const float* pq_w = (const float*)d_in[18];  const float* pq_b = (const float*)d_in[19];
  const float* pk_w = (const float*)d_in[20];  const float* pk_b = (const float*)d_in[21];
  const float* pv_w = (const float*)d_in[22];  const float* pv_b = (const float*)d_in[23];
  const float* cv_w = (const float*)d_in[24];  const float* cv_b = (const float*)d_in[25];

  float* out = (float*)d_out;
  float* S     = out;                 // srcs region doubles as S storage
  float* alpha = out + SZ;            // 9 floats
  float* tgts  = out + SZ + 9;        // [2L][B][PLANE]

  float* ws   = (float*)d_ws;
  float* T    = ws;
  float* qb   = ws + (size_t)SZ;
  float* kb   = ws + (size_t)2 * SZ;
  float* vb   = ws + (size_t)3 * SZ;
  float* vcb  = ws + (size_t)4 * SZ;
  float* ocam = ws + (size_t)5 * SZ;
  float* ecam = ws + (size_t)6 * SZ;                 // 294912
  float* acam = ws + (size_t)6 * SZ + 294912;        // 98304
  float* esum = ws + (size_t)6 * SZ + 393216;        // 18 (pam 9, cam 9)

  // fp16 buffers appended after the fp32 region
  unsigned short* kT = (unsigned short*)(ws + (size_t)6 * SZ + 393216 + 256);
  unsigned short* vh = kT + (size_t)24 * PLANE;

  // Transposed conv0 weights live temporarily in qb (overwritten later by q proj)
  float* wTs = qb;
  float* wTt = qb + 73728;

  hipMemsetAsync(esum, 0, 18 * sizeof(float), stream);

  // Pre-transpose the 3x3 weights for coalesced, math-free LDS staging
  wtrans_kernel<<<dim3(288, 2), 256, 0, stream>>>(fs0_w, ft0_w, wTs, wTt);

  // Fit convs (S goes straight into d_out; T dual-written into tgts odd slots)
  conv0_kernel<<<dim3(128, 2, 2), 256, 0, stream>>>(
      src0, wTs, fs0_b, S, nullptr,
      tgt0, wTt, ft0_b, T, tgts + (size_t)1 * BPL);
  gemm64_kernel<<<dim3(8, 16), 256, 0, stream>>>(fs1_w, 0, 1, src1, 256 * N_, S + BPL, PLANE,
                                                 nullptr, 0, fs1_b, 0, 256);
  gemm64_kernel<<<dim3(8, 16), 256, 0, stream>>>(fs2_w, 0, 1, src2, 512 * N_, S + 2 * BPL, PLANE,
                                                 nullptr, 0, fs2_b, 0, 512);
  gemm64_kernel<<<dim3(8, 16), 256, 0, stream>>>(ft1_w, 0, 1, tgt1, 256 * N_, T + BPL, PLANE,
                                                 tgts + (size_t)3 * BPL, PLANE, ft1_b, 0, 256);
  gemm64_kernel<<<dim3(8, 16), 256, 0, stream>>>(ft2_w, 0, 1, tgt2, 512 * N_, T + 2 * BPL, PLANE,
                                                 tgts + (size_t)5 * BPL, PLANE, ft2_b, 0, 512);

  // Projections q,k,v,vc
  gemm64_kernel<<<dim3(24, 16), 256, 0, stream>>>(pq_w, 4096, 8, T, PLANE, qb, PLANE,
                                                  nullptr, 0, pq_b, 64, 64);
  gemm64_kernel<<<dim3(24, 16), 256, 0, stream>>>(pk_w, 4096, 8, S, PLANE, kb, PLANE,
                                                  nullptr, 0, pk_b, 64, 64);
  gemm64_kernel<<<dim3(24, 16), 256, 0, stream>>>(pv_w, 4096, 8, T, PLANE, vb, PLANE,
                                                  nullptr, 0, pv_b, 64, 64);
  gemm64_kernel<<<dim3(24, 16), 256, 0, stream>>>(cv_w, 4096, 8, T, PLANE, vcb, PLANE,
                                                  nullptr, 0, cv_b, 64, 64);

  // Pack k (transposed fp16) and v (fp16) for the MFMA attention
  kprep_kernel<<<dim3(24, 4), 256, 0, stream>>>(kb, vb, kT, vh);

  // CAM
  ecam_kernel<<<72, 256, 0, stream>>>(T, S, ecam, esum + 9);
  acam_kernel<<<24, 256, 0, stream>>>(ecam, acam);
  gemm64_kernel<<<dim3(24, 16), 256, 0, stream>>>(acam, 4096, 1, vcb, PLANE, ocam, PLANE,
                                                  nullptr, 0, nullptr, 0, 64);

  // PAM + fuse (writes tgts even slots = 0.5*(out_pam + out_cam))
  pam_mfma_kernel<<<1536, 512, 0, stream>>>(qb, kT, vh, ocam, tgts, esum);

  alpha_kernel<<<1, 64, 0, stream>>>(esum, alpha);
}

// Round 10
// 400.732 us; speedup vs baseline: 1.4388x; 1.0840x over previous
//
#include <hip/hip_runtime.h>

// Problem constants
static constexpr int L_ = 3, B_ = 8, C_ = 64, N_ = 1024;
static constexpr int PLANE = C_ * N_;       // 65536
static constexpr int SZ    = L_ * B_ * PLANE; // 1572864 (srcs size, also per-stack-slot count)
static constexpr int BPL   = B_ * PLANE;    // 524288

#define DI __device__ __forceinline__

typedef _Float16 h8 __attribute__((ext_vector_type(8)));   // 8 fp16 (MFMA A/B frag)
typedef __attribute__((ext_vector_type(4))) float f32x4;   // MFMA C/D frag
typedef unsigned int uint32;

DI float wred_sum(float v) {
#pragma unroll
  for (int m = 1; m < 64; m <<= 1) v += __shfl_xor(v, m, 64);
  return v;
}

// fp16 helpers (RNE via v_cvt_f16_f32)
DI uint32 pkh(float a, float b) {
  const _Float16 ha = (_Float16)a, hb = (_Float16)b;
  return (uint32)__builtin_bit_cast(unsigned short, ha) |
         ((uint32)__builtin_bit_cast(unsigned short, hb) << 16);
}
DI h8 bch8(uint4 v) { return __builtin_bit_cast(h8, v); }

DI f32x4 mfmah(h8 a, h8 b, f32x4 c) {
  return __builtin_amdgcn_mfma_f32_16x16x32_f16(a, b, c, 0, 0, 0);
}

// ---------------------------------------------------------------------------
// Weight transpose: w[co][ci][k9] -> wT[ci][k9][co]  (64 x 128 x 9 each)
// grid (288, 2)
// ---------------------------------------------------------------------------
__global__ __launch_bounds__(256) void wtrans_kernel(
    const float* __restrict__ w_s, const float* __restrict__ w_t,
    float* __restrict__ wT_s, float* __restrict__ wT_t)
{
  const float* w = blockIdx.y ? w_t : w_s;
  float* wT = blockIdx.y ? wT_t : wT_s;
  const int e = blockIdx.x * 256 + threadIdx.x;   // 0..73727
  const int co = e & 63;
  const int q = e >> 6;
  const int k9 = q % 9;
  const int ci = q / 9;
  wT[e] = w[(co * 128 + ci) * 9 + k9];
}

// ---------------------------------------------------------------------------
// conv0: 3x3 stride-2 pad-1, Cin=128 -> Cout=64, 64x64 -> 32x32.
// grid (128, 2, 2): x = b*16 + 2-row slab, y = co-half, z = (src,tgt).
// ---------------------------------------------------------------------------
__global__ __launch_bounds__(256) void conv0_kernel(
    const float* __restrict__ in_s, const float* __restrict__ wT_s, const float* __restrict__ b_s,
    float* __restrict__ outA_s, float* __restrict__ outB_s,
    const float* __restrict__ in_t, const float* __restrict__ wT_t, const float* __restrict__ b_t,
    float* __restrict__ outA_t, float* __restrict__ outB_t)
{
  const int tsel = blockIdx.z;
  const int ch   = blockIdx.y;      // co half: co in [ch*32, ch*32+32)
  const float* in   = tsel ? in_t  : in_s;
  const float* wT   = tsel ? wT_t  : wT_s;
  const float* bias = tsel ? b_t   : b_s;
  float* outA = tsel ? outA_t : outA_s;
  float* outB = tsel ? outB_t : outB_s;

  const int bx = blockIdx.x;
  const int b  = bx >> 4;
  const int y0 = (bx & 15) * 2;
  const int t  = threadIdx.x;
  const int x  = t & 31;
  const int cg = t >> 5;            // 0..7 -> co = ch*32 + cg*4 .. +3

  __shared__ float wch[2304];       // [cc][k9][cl<32] flat
  __shared__ float inch[8][5][64];  // [ci_chunk][row][ix]

  float acc[2][4];
#pragma unroll
  for (int yy = 0; yy < 2; ++yy)
#pragma unroll
    for (int o = 0; o < 4; ++o) acc[yy][o] = 0.f;

  for (int ci0 = 0; ci0 < 128; ci0 += 8) {
    __syncthreads();
    // Weights for this co-half: 2304 floats, 32-float coalesced runs
#pragma unroll 3
    for (int r = 0; r < 9; ++r) {
      const int e = t + 256 * r;
      const int cc = e / 288;
      const int rem = e - cc * 288;
      const int k9 = rem >> 5;
      const int cl = rem & 31;
      wch[e] = wT[(ci0 + cc) * 576 + k9 * 64 + ch * 32 + cl];
    }
    // Inputs: 8 ci x 5 rows x 64 x, coalesced over x
#pragma unroll 2
    for (int r = 0; r < 10; ++r) {
      const int e = t + 256 * r;
      const int ix = e & 63;
      const int q = e >> 6;         // 0..39
      const int ry = q % 5;
      const int cc = q / 5;
      const int iy = 2 * y0 - 1 + ry;
      float v = 0.f;
      if (iy >= 0 && iy < 64) v = in[((b * 128 + ci0 + cc) * 64 + iy) * 64 + ix];
      inch[cc][ry][ix] = v;
    }
    __syncthreads();
#pragma unroll 1
    for (int cc = 0; cc < 8; ++cc) {
      float iv[5][3];
#pragma unroll
      for (int ry = 0; ry < 5; ++ry) {
#pragma unroll
        for (int kx = 0; kx < 3; ++kx) {
          const int ix = 2 * x + kx - 1;   // [-1, 63]
          iv[ry][kx] = (ix >= 0) ? inch[cc][ry][ix] : 0.f;
        }
      }
#pragma unroll
      for (int ky = 0; ky < 3; ++ky) {
#pragma unroll
        for (int kx = 0; kx < 3; ++kx) {
          const int k9 = ky * 3 + kx;
          const float4 w4 = *reinterpret_cast<const float4*>(&wch[(cc * 9 + k9) * 32 + cg * 4]);
          const float wv[4] = {w4.x, w4.y, w4.z, w4.w};
          const float i0 = iv[ky][kx];
          const float i1 = iv[ky + 2][kx];
#pragma unroll
          for (int o = 0; o < 4; ++o) {
            acc[0][o] = fmaf(i0, wv[o], acc[0][o]);
            acc[1][o] = fmaf(i1, wv[o], acc[1][o]);
          }
        }
      }
    }
  }
#pragma unroll
  for (int o = 0; o < 4; ++o) {
    const int co = ch * 32 + cg * 4 + o;
    const float bv = bias[co];
#pragma unroll
    for (int yy = 0; yy < 2; ++yy) {
      const int idx = (b * 64 + co) * 1024 + (y0 + yy) * 32 + x;
      const float val = acc[yy][o] + bv;
      outA[idx] = val;
      if (outB) outB[idx] = val;
    }
  }
}

// ---------------------------------------------------------------------------
// Generic fp32 out[g][64][1024] = W[g/wdiv][64][K] @ X[g][K][1024] + bias
// (kept for the small K=64 projections and the attn_cam@vc GEMM)
// ---------------------------------------------------------------------------
__global__ __launch_bounds__(256) void gemm64_kernel(
    const float* __restrict__ W, int wstride, int wdiv,
    const float* __restrict__ X, int xstride,
    float* __restrict__ out, int ostride,
    float* __restrict__ out2, int o2stride,
    const float* __restrict__ bias, int bstride,
    int K)
{
  const int g  = blockIdx.x;
  const int n0 = blockIdx.y * 64;
  const float* Wg = W + (size_t)(g / wdiv) * wstride;
  const float* Xg = X + (size_t)g * xstride;
  const int t = threadIdx.x;
  __shared__ float Xs[32][64];
  __shared__ float Ws[32][64];
  const int tn = t & 15, cgp = t >> 4;
  const int n4 = tn * 4, co4 = cgp * 4;
  float acc[4][4] = {};

  for (int k0 = 0; k0 < K; k0 += 32) {
    {
      const int kk = t >> 4;
      const int nn = (t & 15) * 4;
      *reinterpret_cast<float4*>(&Xs[kk][nn]) =
          *reinterpret_cast<const float4*>(Xg + (size_t)(k0 + kk) * N_ + n0 + nn);
      *reinterpret_cast<float4*>(&Xs[kk + 16][nn]) =
          *reinterpret_cast<const float4*>(Xg + (size_t)(k0 + kk + 16) * N_ + n0 + nn);
    }
    {
      const int co = t & 63, q4 = t >> 6;
      const float* wp = Wg + (size_t)co * K + k0 + q4 * 8;
      const float4 a = *reinterpret_cast<const float4*>(wp);
      const float4 c = *reinterpret_cast<const float4*>(wp + 4);
      const int kb = q4 * 8;
      Ws[kb + 0][co] = a.x; Ws[kb + 1][co] = a.y; Ws[kb + 2][co] = a.z; Ws[kb + 3][co] = a.w;
      Ws[kb + 4][co] = c.x; Ws[kb + 5][co] = c.y; Ws[kb + 6][co] = c.z; Ws[kb + 7][co] = c.w;
    }
    __syncthreads();
#pragma unroll
    for (int kk = 0; kk < 32; ++kk) {
      const float4 xv = *reinterpret_cast<const float4*>(&Xs[kk][n4]);
      const float4 wv = *reinterpret_cast<const float4*>(&Ws[kk][co4]);
      const float xa[4] = {xv.x, xv.y, xv.z, xv.w};
      const float wa[4] = {wv.x, wv.y, wv.z, wv.w};
#pragma unroll
      for (int a = 0; a < 4; ++a)
#pragma unroll
        for (int b2 = 0; b2 < 4; ++b2)
          acc[a][b2] = fmaf(wa[a], xa[b2], acc[a][b2]);
    }
    __syncthreads();
  }

  float bv[4] = {0.f, 0.f, 0.f, 0.f};
  if (bias) {
    const float* bg = bias + (size_t)(g / wdiv) * bstride;
    bv[0] = bg[co4]; bv[1] = bg[co4 + 1]; bv[2] = bg[co4 + 2]; bv[3] = bg[co4 + 3];
  }
#pragma unroll
  for (int ii = 0; ii < 4; ++ii) {
    float4 o4;
    o4.x = acc[ii][0] + bv[ii]; o4.y = acc[ii][1] + bv[ii];
    o4.z = acc[ii][2] + bv[ii]; o4.w = acc[ii][3] + bv[ii];
    const int idx = (co4 + ii) * N_ + n0 + n4;
    *reinterpret_cast<float4*>(out + (size_t)g * ostride + idx) = o4;
    if (out2) {
      float* o2 = out2 + (size_t)g * o2stride + idx;
      o2[0] = o4.x; o2[1] = o4.y; o2[2] = o4.z; o2[3] = o4.w;
    }
  }
}

// ---------------------------------------------------------------------------
// xprep: transpose+convert X[g][K][1024] fp32 -> out[g][1024][K] fp16.
// grid (8, K/64, 16); 64x64 tile per block (kprep's verified tile pattern).
// ---------------------------------------------------------------------------
__global__ __launch_bounds__(256) void xprep_kernel(
    const float* __restrict__ in, unsigned short* __restrict__ out, int K)
{
  const int g = blockIdx.x, kc = blockIdx.y, nc = blockIdx.z;
  const int t = threadIdx.x;
  __shared__ float tl[64][65];
  const float* ing = in + (size_t)g * K * 1024 + (size_t)(kc * 64) * 1024 + nc * 64;
#pragma unroll 4
  for (int r = 0; r < 16; ++r) {
    const int kk = r * 4 + (t >> 6);
    tl[kk][t & 63] = ing[kk * 1024 + (t & 63)];
  }
  __syncthreads();
  const int mm = t >> 2, kseg = (t & 3) * 16;
  uint32 hw[8];
#pragma unroll
  for (int ii = 0; ii < 8; ++ii)
    hw[ii] = pkh(tl[kseg + 2 * ii][mm], tl[kseg + 2 * ii + 1][mm]);
  unsigned short* o = out + ((size_t)g * 1024 + nc * 64 + mm) * K + kc * 64 + kseg;
  uint4 h0; h0.x = hw[0]; h0.y = hw[1]; h0.z = hw[2]; h0.w = hw[3];
  uint4 h1; h1.x = hw[4]; h1.y = hw[5]; h1.z = hw[6]; h1.w = hw[7];
  *reinterpret_cast<uint4*>(o)     = h0;
  *reinterpret_cast<uint4*>(o + 8) = h1;
}

// ---------------------------------------------------------------------------
// whconv: convert the 4 fit-GEMM weight matrices to fp16, packed layout:
// wh1s @0 (64x256), wh2s @16384 (64x512), wh1t @49152, wh2t @65536.
// grid 192 (pair-indexed segments).
// ---------------------------------------------------------------------------
__global__ __launch_bounds__(256) void whconv_kernel(
    const float* __restrict__ w1s, const float* __restrict__ w2s,
    const float* __restrict__ w1t, const float* __restrict__ w2t,
    unsigned short* __restrict__ wh)
{
  const int p = blockIdx.x * 256 + threadIdx.x;  // pair index 0..49151
  const float* in; int local; unsigned short* out;
  if (p < 8192)       { in = w1s; local = p;         out = wh; }
  else if (p < 24576) { in = w2s; local = p - 8192;  out = wh + 16384; }
  else if (p < 32768) { in = w1t; local = p - 24576; out = wh + 49152; }
  else                { in = w2t; local = p - 32768; out = wh + 65536; }
  const float2 v = *reinterpret_cast<const float2*>(in + 2 * local);
  *reinterpret_cast<uint32*>(out + 2 * local) = pkh(v.x, v.y);
}

// ---------------------------------------------------------------------------
// gemmh: fp16 MFMA fit-GEMM. out[g][64co][1024n] = W[64][K] @ X^T (Xh[n][K]).
// grid (16, 16): g<8 = src half (Xa/Wa/oa), g>=8 = tgt half (+dual write o2b).
// 256 threads = 4 waves; wave = 16 n x 64 co. Both fragments are direct
// contiguous uint4 loads (Xh[n][K], Wh[co][K]) - no LDS.
// ---------------------------------------------------------------------------
__global__ __launch_bounds__(256) void gemmh_kernel(
    const unsigned short* __restrict__ Xa, const unsigned short* __restrict__ Xb,
    const unsigned short* __restrict__ Wa, const unsigned short* __restrict__ Wb,
    const float* __restrict__ ba, const float* __restrict__ bb,
    float* __restrict__ oa, float* __restrict__ ob, float* __restrict__ o2b,
    int K)
{
  const int g = blockIdx.x;
  const bool isb = g >= 8;
  const int gl = g & 7;
  const unsigned short* X = (isb ? Xb : Xa) + (size_t)gl * 1024 * K;
  const unsigned short* W = isb ? Wb : Wa;
  const float* bias = isb ? bb : ba;
  float* out = (isb ? ob : oa) + (size_t)gl * PLANE;
  float* out2 = isb ? o2b + (size_t)gl * PLANE : nullptr;

  const int t = threadIdx.x, lane = t & 63, wv = t >> 6;
  const int nl = lane & 15, g16 = lane >> 4;
  const int n0w = blockIdx.y * 64 + wv * 16;

  const unsigned short* xp = X + (size_t)(n0w + nl) * K + g16 * 8;
  const unsigned short* wp = W + (size_t)nl * K + g16 * 8;

  f32x4 acc[4];
#pragma unroll
  for (int ct = 0; ct < 4; ++ct) acc[ct] = f32x4{0.f, 0.f, 0.f, 0.f};

#pragma unroll 4
  for (int kk = 0; kk < K; kk += 32) {
    const h8 a = bch8(*reinterpret_cast<const uint4*>(xp + kk));
#pragma unroll
    for (int ct = 0; ct < 4; ++ct) {
      const h8 bfr = bch8(*reinterpret_cast<const uint4*>(wp + (size_t)ct * 16 * K + kk));
      acc[ct] = mfmah(a, bfr, acc[ct]);
    }
  }

#pragma unroll
  for (int ct = 0; ct < 4; ++ct) {
    const int co = ct * 16 + nl;
    const float bv = bias[co];
    float4 o4;
    o4.x = acc[ct][0] + bv; o4.y = acc[ct][1] + bv;
    o4.z = acc[ct][2] + bv; o4.w = acc[ct][3] + bv;
    const int idx = co * N_ + n0w + g16 * 4;
    *reinterpret_cast<float4*>(out + idx) = o4;
    if (out2) {           // tgts region is 4B-aligned only -> scalar writes
      out2[idx] = o4.x; out2[idx + 1] = o4.y;
      out2[idx + 2] = o4.z; out2[idx + 3] = o4.w;
    }
  }
}

// ---------------------------------------------------------------------------
// kprep: k[g][64c][1024m] -> kT[g][1024m][64c] (fp16);  v[g] -> vh[g] (fp16).
// grid (24, 4): per block 256-m chunk.
// ---------------------------------------------------------------------------
__global__ __launch_bounds__(256) void kprep_kernel(
    const float* __restrict__ kb, const float* __restrict__ vb,
    unsigned short* __restrict__ kT, unsigned short* __restrict__ vh)
{
  const int g = blockIdx.x;
  const int ch = blockIdx.y;
  const int t = threadIdx.x;
  const float* kg = kb + (size_t)g * PLANE;
  __shared__ float tl[64][65];

#pragma unroll 1
  for (int tile = 0; tile < 4; ++tile) {
    const int m0 = ch * 256 + tile * 64;
    __syncthreads();
#pragma unroll 4
    for (int r = 0; r < 16; ++r) {
      const int c = r * 4 + (t >> 6);
      tl[c][t & 63] = kg[c * N_ + m0 + (t & 63)];
    }
    __syncthreads();
    const int mm = t >> 2, cseg = (t & 3) * 16;
    uint32 hw[8];
#pragma unroll
    for (int ii = 0; ii < 8; ++ii)
      hw[ii] = pkh(tl[cseg + 2 * ii][mm], tl[cseg + 2 * ii + 1][mm]);
    const size_t o = ((size_t)g * 1024 + m0 + mm) * 64 + cseg;
    uint4 h0; h0.x = hw[0]; h0.y = hw[1]; h0.z = hw[2]; h0.w = hw[3];
    uint4 h1; h1.x = hw[4]; h1.y = hw[5]; h1.z = hw[6]; h1.w = hw[7];
    *reinterpret_cast<uint4*>(kT + o)     = h0;
    *reinterpret_cast<uint4*>(kT + o + 8) = h1;
  }

  // v -> fp16 (8 elems/thread/iter, packed 16B stores)
  const float* vg = vb + (size_t)g * PLANE;
  unsigned short* vo = vh + (size_t)g * PLANE;
  for (int e8 = ch * 2048 + t; e8 < (ch + 1) * 2048; e8 += 256) {
    const float4 a = *reinterpret_cast<const float4*>(vg + (size_t)e8 * 8);
    const float4 b = *reinterpret_cast<const float4*>(vg + (size_t)e8 * 8 + 4);
    uint4 u;
    u.x = pkh(a.x, a.y); u.y = pkh(a.z, a.w);
    u.z = pkh(b.x, b.y); u.w = pkh(b.z, b.w);
    *reinterpret_cast<uint4*>(vo + (size_t)e8 * 8) = u;
  }
}

// ---------------------------------------------------------------------------
// e_cam[i,j,b][c][d] = sum_n T[i,b,c,n] * S[j,b,d,n];  also atomic raw-sum.
// ---------------------------------------------------------------------------
__global__ __launch_bounds__(256) void ecam_kernel(
    const float* __restrict__ T, const float* __restrict__ S,
    float* __restrict__ ecam, float* __restrict__ esum_cam)
{
  const int bx = blockIdx.x;
  const int b = bx & 7;
  const int j = (bx >> 3) % 3;
  const int i = bx / 24;
  const float* Tg = T + (size_t)(i * 8 + b) * PLANE;
  const float* Sg = S + (size_t)(j * 8 + b) * PLANE;
  const int t = threadIdx.x;
  __shared__ float Ts[64 * 68];
  __shared__ float Ss[64 * 68];
  __shared__ float rs[4];
  float acc[4][4] = {};
  const int c0 = (t & 15) * 4, d0 = (t >> 4) * 4;

  for (int nb = 0; nb < 1024; nb += 64) {
    __syncthreads();
    {
      const int nn = t & 63, rb = t >> 6;
#pragma unroll
      for (int r = 0; r < 16; ++r) {
        const int row = rb * 16 + r;
        Ts[nn * 68 + row] = Tg[row * N_ + nb + nn];
        Ss[nn * 68 + row] = Sg[row * N_ + nb + nn];
      }
    }
    __syncthreads();
#pragma unroll 8
    for (int nn = 0; nn < 64; ++nn) {
      const float4 tv = *reinterpret_cast<const float4*>(&Ts[nn * 68 + c0]);
      const float4 sv = *reinterpret_cast<const float4*>(&Ss[nn * 68 + d0]);
      const float ta[4] = {tv.x, tv.y, tv.z, tv.w};
      const float sa[4] = {sv.x, sv.y, sv.z, sv.w};
#pragma unroll
      for (int ci = 0; ci < 4; ++ci)
#pragma unroll
        for (int di = 0; di < 4; ++di)
          acc[ci][di] = fmaf(ta[ci], sa[di], acc[ci][di]);
    }
  }
  float s = 0.f;
#pragma unroll
  for (int ci = 0; ci < 4; ++ci)
#pragma unroll
    for (int di = 0; di < 4; ++di) s += acc[ci][di];
  s = wred_sum(s);
  if ((t & 63) == 0) rs[t >> 6] = s;
  __syncthreads();
  if (t == 0) atomicAdd(esum_cam + i * 3 + j, rs[0] + rs[1] + rs[2] + rs[3]);

  float* eo = ecam + (size_t)((i * 3 + j) * 8 + b) * 4096;
#pragma unroll
  for (int ci = 0; ci < 4; ++ci) {
    float4 o4; o4.x = acc[ci][0]; o4.y = acc[ci][1]; o4.z = acc[ci][2]; o4.w = acc[ci][3];
    *reinterpret_cast<float4*>(eo + (c0 + ci) * 64 + d0) = o4;
  }
}

// ---------------------------------------------------------------------------
// attn_cam[i,b][c][d] = sum_j softmax_d(e_cam[i,j,b,c,:])[d]     grid 24
// ---------------------------------------------------------------------------
__global__ __launch_bounds__(256) void acam_kernel(
    const float* __restrict__ ecam, float* __restrict__ acam)
{
  const int bx = blockIdx.x;
  const int b = bx & 7, i = bx >> 3;
  const int t = threadIdx.x;
  const int c = t >> 2, seg = t & 3;
  float acc[16] = {};
#pragma unroll
  for (int j = 0; j < 3; ++j) {
    const float* e = ecam + (size_t)((i * 3 + j) * 8 + b) * 4096 + c * 64 + seg * 16;
    float ev[16];
#pragma unroll
    for (int r = 0; r < 4; ++r) {
      const float4 v4 = *reinterpret_cast<const float4*>(e + r * 4);
      ev[4 * r] = v4.x; ev[4 * r + 1] = v4.y; ev[4 * r + 2] = v4.z; ev[4 * r + 3] = v4.w;
    }
    float mx = ev[0];
#pragma unroll
    for (int r = 1; r < 16; ++r) mx = fmaxf(mx, ev[r]);
    mx = fmaxf(mx, __shfl_xor(mx, 1, 4));
    mx = fmaxf(mx, __shfl_xor(mx, 2, 4));
    float pv[16], ss = 0.f;
#pragma unroll
    for (int r = 0; r < 16; ++r) { pv[r] = __expf(ev[r] - mx); ss += pv[r]; }
    ss += __shfl_xor(ss, 1, 4);
    ss += __shfl_xor(ss, 2, 4);
    const float rc = 1.f / ss;
#pragma unroll
    for (int r = 0; r < 16; ++r) acc[r] += pv[r] * rc;
  }
  float* ao = acam + (size_t)(i * 8 + b) * 4096 + c * 64 + seg * 16;
#pragma unroll
  for (int r = 0; r < 4; ++r) {
    float4 o4; o4.x = acc[4 * r]; o4.y = acc[4 * r + 1]; o4.z = acc[4 * r + 2]; o4.w = acc[4 * r + 3];
    *reinterpret_cast<float4*>(ao + r * 4) = o4;
  }
}

// ---------------------------------------------------------------------------
// PAM via single-pass fp16 MFMA. grid 1536 = (i, b, qt), 512 threads (8 waves
// x 128 m). osum aliases qlds (dead after Q-frag extraction) -> 38.2 KB LDS
// -> 4 blocks/CU (was 3 at 42.5 KB).
// ---------------------------------------------------------------------------
__global__ __launch_bounds__(512, 4) void pam_mfma_kernel(
    const float* __restrict__ q, const unsigned short* __restrict__ kT,
    const unsigned short* __restrict__ vh,
    const float* __restrict__ ocam, float* __restrict__ tgts, float* __restrict__ esum_pam)
{
  const int bx = blockIdx.x;
  const int qt = bx & 63;
  const int b  = (bx >> 6) & 7;
  const int i  = bx >> 9;
  const int n0 = qt * 16;
  const int t = threadIdx.x;
  const int lane = t & 63;
  const int wv = t >> 6;             // 0..7
  const int nl = lane & 15;          // n within tile (operand col / D col)
  const int g16 = lane >> 4;         // k-group

  __shared__ unsigned short Plds[16 * 1024];  // 32 KB fp16, [n][m ^ (8n)]
  __shared__ float qlds[64 * 17];             // q staging; aliased as osum later
  __shared__ float redmx[128];
  __shared__ float redse[128];
  __shared__ float redes[8];
  float* osum = qlds;                         // m-half combine buffer (1024 floats)

  const size_t ibo = (size_t)(i * 8 + b) * PLANE;

  // stage q tile [64c][16n]
  const float* qg = q + ibo;
  for (int e = t; e < 1024; e += 512)
    qlds[(e >> 4) * 17 + (e & 15)] = qg[(e >> 4) * N_ + n0 + (e & 15)];
  __syncthreads();

  // Q B-fragments (fp16): col n = nl, k(c) = ks*32 + g16*8 + idx
  h8 qh[2];
#pragma unroll
  for (int ks = 0; ks < 2; ++ks) {
#pragma unroll
    for (int idx = 0; idx < 8; ++idx)
      qh[ks][idx] = (_Float16)qlds[(ks * 32 + g16 * 8 + idx) * 17 + nl];
  }

  const int wm0 = wv * 128;          // wave's m-range base (QK)
  const int ct = wv & 3;             // PV c-tile
  const int mh = wv >> 2;            // PV m-half
  const unsigned short* vg = vh + ibo + (size_t)(ct * 16 + nl) * 1024 + mh * 512 + g16 * 8;
  f32x4 oat = f32x4{0.f, 0.f, 0.f, 0.f};

#pragma unroll 1
  for (int j = 0; j < 3; ++j) {
    const unsigned short* kp =
        kT + ((size_t)(j * 8 + b) * 1024 + wm0 + nl) * 64 + g16 * 8;

    f32x4 l4[8];
#pragma unroll 4
    for (int tt = 0; tt < 8; ++tt) {
      const int off = tt * 1024;  // 16 m-rows * 64 c (halves)
      const uint4 k0 = *reinterpret_cast<const uint4*>(kp + off);
      const uint4 k1 = *reinterpret_cast<const uint4*>(kp + off + 32);
      f32x4 a = f32x4{0.f, 0.f, 0.f, 0.f};
      a = mfmah(bch8(k0), qh[0], a);
      a = mfmah(bch8(k1), qh[1], a);
      l4[tt] = a;
    }

    // stats: per-n max over this wave's 128 m (4-lane group), raw sum (wave)
    float pm = -3.4e38f, es = 0.f;
#pragma unroll
    for (int tt = 0; tt < 8; ++tt) {
#pragma unroll
      for (int r = 0; r < 4; ++r) { pm = fmaxf(pm, l4[tt][r]); es += l4[tt][r]; }
    }
    pm = fmaxf(pm, __shfl_xor(pm, 16, 64));
    pm = fmaxf(pm, __shfl_xor(pm, 32, 64));
    es = wred_sum(es);
    if (lane < 16) redmx[wv * 16 + lane] = pm;
    if (lane == 0) redes[wv] = es;
    __syncthreads();   // sync1: mx ready; also guarantees prior PV reads done
    float mx = redmx[nl];
#pragma unroll
    for (int w = 1; w < 8; ++w) mx = fmaxf(mx, redmx[w * 16 + nl]);
    if (t == 0) {
      float s = 0.f;
#pragma unroll
      for (int w = 0; w < 8; ++w) s += redes[w];
      atomicAdd(esum_pam + i * 3 + j, s);
    }

    // exp (unnormalized, <= 1), stage P, then publish per-wave sums
    float ps = 0.f;
#pragma unroll
    for (int tt = 0; tt < 8; ++tt) {
#pragma unroll
      for (int r = 0; r < 4; ++r) {
        l4[tt][r] = __expf(l4[tt][r] - mx);
        ps += l4[tt][r];
      }
    }
#pragma unroll
    for (int tt = 0; tt < 8; ++tt) {
      const int m = wm0 + tt * 16 + g16 * 4;
      uint2 w2;
      w2.x = pkh(l4[tt][0], l4[tt][1]);
      w2.y = pkh(l4[tt][2], l4[tt][3]);
      *reinterpret_cast<uint2*>(&Plds[nl * 1024 + (m ^ (nl * 8))]) = w2;
    }
    ps += __shfl_xor(ps, 16, 64);
    ps += __shfl_xor(ps, 32, 64);
    if (lane < 16) redse[wv * 16 + lane] = ps;
    __syncthreads();   // sync2: P staged + den ready
    float den = redse[nl];
#pragma unroll
    for (int w = 1; w < 8; ++w) den += redse[w * 16 + nl];
    const float rs = 1.f / den;

    // PV: this wave covers c-tile ct, m in [mh*512, mh*512+512)
    f32x4 oa = f32x4{0.f, 0.f, 0.f, 0.f};
    f32x4 ob = f32x4{0.f, 0.f, 0.f, 0.f};
#pragma unroll 4
    for (int ks = 0; ks < 16; ks += 2) {
      const int ml0 = mh * 512 + ks * 32 + g16 * 8;
      const int ml1 = ml0 + 32;
      const uint4 va0 = *reinterpret_cast<const uint4*>(vg + ks * 32);
      const uint4 pf0 = *reinterpret_cast<const uint4*>(&Plds[nl * 1024 + (ml0 ^ (nl * 8))]);
      const uint4 va1 = *reinterpret_cast<const uint4*>(vg + ks * 32 + 32);
      const uint4 pf1 = *reinterpret_cast<const uint4*>(&Plds[nl * 1024 + (ml1 ^ (nl * 8))]);
      oa = mfmah(bch8(va0), bch8(pf0), oa);
      ob = mfmah(bch8(va1), bch8(pf1), ob);
    }
#pragma unroll
    for (int r = 0; r < 4; ++r) oat[r] += rs * (oa[r] + ob[r]);
  }

  // combine m-halves through LDS (osum aliases qlds), fuse with out_cam
  if (mh == 0) {
#pragma unroll
    for (int r = 0; r < 4; ++r)
      osum[(ct * 16 + g16 * 4 + r) * 16 + nl] = oat[r];
  }
  __syncthreads();
  if (mh == 1) {
    const float* og = ocam + ibo;
    float* outg = tgts + (size_t)(2 * i * 8 + b) * PLANE;
#pragma unroll
    for (int r = 0; r < 4; ++r) {
      const int c = ct * 16 + g16 * 4 + r;
      const int idx = c * N_ + n0 + nl;
      outg[idx] = 0.5f * (oat[r] + osum[c * 16 + nl] + og[idx]);
    }
  }
}

// ---------------------------------------------------------------------------
// alpha[i][j] = 0.5*(softmax_j(mean e_pam) + softmax_j(mean e_cam))
// ---------------------------------------------------------------------------
__global__ void alpha_kernel(const float* __restrict__ esum, float* __restrict__ alpha)
{
  const int t = threadIdx.x;
  if (t >= 9) return;
  const int i = t / 3, j = t % 3;
  float p[3], c[3];
#pragma unroll
  for (int jj = 0; jj < 3; ++jj) {
    p[jj] = esum[i * 3 + jj] * (1.0f / 8388608.0f);
    c[jj] = esum[9 + i * 3 + jj] * (1.0f / 32768.0f);
  }
  const float mp = fmaxf(p[0], fmaxf(p[1], p[2]));
  const float mc = fmaxf(c[0], fmaxf(c[1], c[2]));
  float sp = 0.f, sc = 0.f;
#pragma unroll
  for (int jj = 0; jj < 3; ++jj) { sp += __expf(p[jj] - mp); sc += __expf(c[jj] - mc); }
  alpha[t] = 0.5f * (__expf(p[j] - mp) / sp + __expf(c[j] - mc) / sc);
}

// ---------------------------------------------------------------------------
extern "C" void kernel_launch(void* const* d_in, const int* in_sizes, int n_in,
                              void* d_out, int out_size, void* d_ws, size_t ws_size,
                              hipStream_t stream)
{
  const float* src0 = (const float*)d_in[0];
  const float* src1 = (const float*)d_in[1];
  const float* src2 = (const float*)d_in[2];
  const float* tgt0 = (const float*)d_in[3];
  const float* tgt1 = (const float*)d_in[4];
  const float* tgt2 = (const float*)d_in[5];
  const float* fs0_w = (const float*)d_in[6];  const float* fs0_b = (const float*)d_in[7];
  const float* fs1_w = (const float*)d_in[8];  const float* fs1_b = (const float*)d_in[9];
  const float* fs2_w = (const float*)d_in[10]; const float* fs2_b = (const float*)d_in[11];
  const float* ft0_w = (const float*)d_in[12]; const float* ft0_b = (const float*)d_in[13];
  const float* ft1_w = (const float*)d_in[14]; const float* ft1_b = (const float*)d_in[15];
  const float* ft2_w = (const float*)d_in[16]; const float* ft2_b = (const float*)d_in[17];
  const float* pq_w = (const float*)d_in[18];  const float* pq_b = (const float*)d_in[19];
  const float* pk_w = (const float*)d_in[20];  const float* pk_b = (const float*)d_in[21];
  const float* pv_w = (const float*)d_in[22];  const float* pv_b = (const float*)d_in[23];
  const float* cv_w = (const float*)d_in[24];  const float* cv_b = (const float*)d_in[25];

  float* out = (float*)d_out;
  float* S     = out;                 // srcs region doubles as S storage
  float* alpha = out + SZ;            // 9 floats
  float* tgts  = out + SZ + 9;        // [2L][B][PLANE]

  float* ws   = (float*)d_ws;
  float* T    = ws;
  float* qb   = ws + (size_t)SZ;
  float* kb   = ws + (size_t)2 * SZ;
  float* vb   = ws + (size_t)3 * SZ;
  float* vcb  = ws + (size_t)4 * SZ;
  float* ocam = ws + (size_t)5 * SZ;
  float* ecam = ws + (size_t)6 * SZ;                 // 294912
  float* acam = ws + (size_t)6 * SZ + 294912;        // 98304
  float* esum = ws + (size_t)6 * SZ + 393216;        // 18 (pam 9, cam 9)

  // fp16 buffers appended after the fp32 region
  unsigned short* kT = (unsigned short*)(ws + (size_t)6 * SZ + 393216 + 256);
  unsigned short* vh = kT + (size_t)24 * PLANE;
  unsigned short* wh = vh + (size_t)24 * PLANE;      // 98304 ushorts

  // Xh (fp16, transposed fit-GEMM inputs) overlays qb..vcb (dead until
  // projections run; stream order serializes all uses).
  unsigned short* Xs1 = (unsigned short*)qb;         // 8x1024x256
  unsigned short* Xs2 = Xs1 + 2097152;               // 8x1024x512
  unsigned short* Xt1 = Xs1 + 6291456;               // 8x1024x256
  unsigned short* Xt2 = Xs1 + 8388608;               // 8x1024x512

  // Transposed conv0 weights also live in qb (consumed by conv0 before xprep)
  float* wTs = qb;
  float* wTt = qb + 73728;

  hipMemsetAsync(esum, 0, 18 * sizeof(float), stream);

  // Pre-transpose the 3x3 weights for coalesced, math-free LDS staging
  wtrans_kernel<<<dim3(288, 2), 256, 0, stream>>>(fs0_w, ft0_w, wTs, wTt);

  // conv0 (S goes straight into d_out; T dual-written into tgts odd slot 1)
  conv0_kernel<<<dim3(128, 2, 2), 256, 0, stream>>>(
      src0, wTs, fs0_b, S, nullptr,
      tgt0, wTt, ft0_b, T, tgts + (size_t)1 * BPL);

  // fp16 fit GEMMs: transpose/convert inputs + weights, then MFMA
  xprep_kernel<<<dim3(8, 4, 16), 256, 0, stream>>>(src1, Xs1, 256);
  xprep_kernel<<<dim3(8, 8, 16), 256, 0, stream>>>(src2, Xs2, 512);
  xprep_kernel<<<dim3(8, 4, 16), 256, 0, stream>>>(tgt1, Xt1, 256);
  xprep_kernel<<<dim3(8, 8, 16), 256, 0, stream>>>(tgt2, Xt2, 512);
  whconv_kernel<<<192, 256, 0, stream>>>(fs1_w, fs2_w, ft1_w, ft2_w, wh);
  gemmh_kernel<<<dim3(16, 16), 256, 0, stream>>>(
      Xs1, Xt1, wh, wh + 49152, fs1_b, ft1_b,
      S + BPL, T + BPL, tgts + (size_t)3 * BPL, 256);
  gemmh_kernel<<<dim3(16, 16), 256, 0, stream>>>(
      Xs2, Xt2, wh + 16384, wh + 65536, fs2_b, ft2_b,
      S + 2 * BPL, T + 2 * BPL, tgts + (size_t)5 * BPL, 512);

  // Projections q,k,v,vc (K=64, fp32; overwrite the Xh overlay)
  gemm64_kernel<<<dim3(24, 16), 256, 0, stream>>>(pq_w, 4096, 8, T, PLANE, qb, PLANE,
                                                  nullptr, 0, pq_b, 64, 64);
  gemm64_kernel<<<dim3(24, 16), 256, 0, stream>>>(pk_w, 4096, 8, S, PLANE, kb, PLANE,
                                                  nullptr, 0, pk_b, 64, 64);
  gemm64_kernel<<<dim3(24, 16), 256, 0, stream>>>(pv_w, 4096, 8, T, PLANE, vb, PLANE,
                                                  nullptr, 0, pv_b, 64, 64);
  gemm64_kernel<<<dim3(24, 16), 256, 0, stream>>>(cv_w, 4096, 8, T, PLANE, vcb, PLANE,
                                                  nullptr, 0, cv_b, 64, 64);

  // Pack k (transposed fp16) and v (fp16) for the MFMA attention
  kprep_kernel<<<dim3(24, 4), 256, 0, stream>>>(kb, vb, kT, vh);

  // CAM
  ecam_kernel<<<72, 256, 0, stream>>>(T, S, ecam, esum + 9);
  acam_kernel<<<24, 256, 0, stream>>>(ecam, acam);
  gemm64_kernel<<<dim3(24, 16), 256, 0, stream>>>(acam, 4096, 1, vcb, PLANE, ocam, PLANE,
                                                  nullptr, 0, nullptr, 0, 64);

  // PAM + fuse (writes tgts even slots = 0.5*(out_pam + out_cam))
  pam_mfma_kernel<<<1536, 512, 0, stream>>>(qb, kT, vh, ocam, tgts, esum);

  alpha_kernel<<<1, 64, 0, stream>>>(esum, alpha);
}

// Round 11
// 364.782 us; speedup vs baseline: 1.5805x; 1.0986x over previous
//
#include <hip/hip_runtime.h>

// Problem constants
static constexpr int L_ = 3, B_ = 8, C_ = 64, N_ = 1024;
static constexpr int PLANE = C_ * N_;       // 65536
static constexpr int SZ    = L_ * B_ * PLANE; // 1572864
static constexpr int BPL   = B_ * PLANE;    // 524288

#define DI __device__ __forceinline__

typedef _Float16 h8 __attribute__((ext_vector_type(8)));   // 8 fp16 (MFMA A/B frag)
typedef __attribute__((ext_vector_type(4))) float f32x4;   // MFMA C/D frag
typedef unsigned int uint32;

DI float wred_sum(float v) {
#pragma unroll
  for (int m = 1; m < 64; m <<= 1) v += __shfl_xor(v, m, 64);
  return v;
}

DI unsigned short f2h(float f) {
  return __builtin_bit_cast(unsigned short, (_Float16)f);
}
DI uint32 pkh(float a, float b) {
  return (uint32)f2h(a) | ((uint32)f2h(b) << 16);
}
DI h8 bch8(uint4 v) { return __builtin_bit_cast(h8, v); }

DI f32x4 mfmah(h8 a, h8 b, f32x4 c) {
  return __builtin_amdgcn_mfma_f32_16x16x32_f16(a, b, c, 0, 0, 0);
}

// ---------------------------------------------------------------------------
// xprep: transpose+convert in[g][K][N] fp32 -> out[g][N][K] fp16.
// grid (8, K/64, N/64); 64x64 tile per block.
// ---------------------------------------------------------------------------
__global__ __launch_bounds__(256) void xprep_kernel(
    const float* __restrict__ in, unsigned short* __restrict__ out, int K, int N)
{
  const int g = blockIdx.x, kc = blockIdx.y, nc = blockIdx.z;
  const int t = threadIdx.x;
  __shared__ float tl[64][65];
  const float* ing = in + (size_t)g * K * N + (size_t)(kc * 64) * N + nc * 64;
#pragma unroll 4
  for (int r = 0; r < 16; ++r) {
    const int kk = r * 4 + (t >> 6);
    tl[kk][t & 63] = ing[(size_t)kk * N + (t & 63)];
  }
  __syncthreads();
  const int mm = t >> 2, kseg = (t & 3) * 16;
  uint32 hw[8];
#pragma unroll
  for (int ii = 0; ii < 8; ++ii)
    hw[ii] = pkh(tl[kseg + 2 * ii][mm], tl[kseg + 2 * ii + 1][mm]);
  unsigned short* o = out + ((size_t)g * N + nc * 64 + mm) * K + kc * 64 + kseg;
  uint4 h0; h0.x = hw[0]; h0.y = hw[1]; h0.z = hw[2]; h0.w = hw[3];
  uint4 h1; h1.x = hw[4]; h1.y = hw[5]; h1.z = hw[6]; h1.w = hw[7];
  *reinterpret_cast<uint4*>(o)     = h0;
  *reinterpret_cast<uint4*>(o + 8) = h1;
}

// ---------------------------------------------------------------------------
// w9conv: conv weights w[co][ci][k9] fp32 -> w9[k9][co][ci] fp16 (both s,t).
// grid 576.
// ---------------------------------------------------------------------------
__global__ __launch_bounds__(256) void w9conv_kernel(
    const float* __restrict__ w_s, const float* __restrict__ w_t,
    unsigned short* __restrict__ w9_s, unsigned short* __restrict__ w9_t)
{
  const int e = blockIdx.x * 256 + threadIdx.x;  // 0..147455
  const float* w = (e < 73728) ? w_s : w_t;
  unsigned short* o = (e < 73728) ? w9_s : w9_t;
  const int le = (e < 73728) ? e : e - 73728;
  const int ci = le & 127;
  const int q = le >> 7;
  const int co = q & 63;
  const int k9 = q >> 6;
  o[le] = f2h(w[(co * 128 + ci) * 9 + k9]);
}

// ---------------------------------------------------------------------------
// conv0 via MFMA: 3x3 s2 p1, 128->64, using channels-last fp16 inT[b][pix][ci]
// and w9[tap][co][ci]. grid (32 out-rows, 8 b, 2 st), 256 thr = 4 waves
// (wave = co-tile). Per tap x ks: 1 A-load + 2 predicated B-loads + 2 MFMA.
// ---------------------------------------------------------------------------
__global__ __launch_bounds__(256) void conv0_mfma_kernel(
    const unsigned short* __restrict__ inT_s, const unsigned short* __restrict__ inT_t,
    const unsigned short* __restrict__ w9_s, const unsigned short* __restrict__ w9_t,
    const float* __restrict__ b_s, const float* __restrict__ b_t,
    float* __restrict__ Sout, float* __restrict__ Tout, float* __restrict__ tdup)
{
  const int yr = blockIdx.x;          // output row 0..31
  const int b  = blockIdx.y;
  const int st = blockIdx.z;
  const unsigned short* inT = st ? inT_t : inT_s;
  const unsigned short* w9  = st ? w9_t  : w9_s;
  const float* bias = st ? b_t : b_s;
  float* outA = st ? Tout : Sout;

  const int t = threadIdx.x, lane = t & 63;
  const int ct = t >> 6;              // co-tile
  const int nl = lane & 15, g16 = lane >> 4;
  const unsigned short* inb = inT + (size_t)b * (4096 * 128);
  const unsigned short* wbase = w9 + (size_t)(ct * 16 + nl) * 128;

  f32x4 acc0 = f32x4{0.f, 0.f, 0.f, 0.f};
  f32x4 acc1 = f32x4{0.f, 0.f, 0.f, 0.f};
  const uint4 zz = uint4{0u, 0u, 0u, 0u};

#pragma unroll 1
  for (int tap = 0; tap < 9; ++tap) {
    const int ky = tap / 3, kx = tap - 3 * (tap / 3);
    const int py = 2 * yr - 1 + ky;                 // [-1, 63]
    const int px0 = 2 * nl - 1 + kx;                // nt=0: x = nl
    const int px1 = px0 + 32;                       // nt=1: x = 16+nl (>=31)
    const bool v0 = (py >= 0) && (px0 >= 0);
    const bool v1 = (py >= 0);
    const unsigned short* prow = inb + (ptrdiff_t)py * (64 * 128);
#pragma unroll
    for (int ks = 0; ks < 4; ++ks) {
      const h8 a = bch8(*reinterpret_cast<const uint4*>(
          wbase + tap * 8192 + ks * 32 + g16 * 8));
      const uint4 bv0 = v0 ? *reinterpret_cast<const uint4*>(
                                 prow + px0 * 128 + ks * 32 + g16 * 8) : zz;
      const uint4 bv1 = v1 ? *reinterpret_cast<const uint4*>(
                                 prow + px1 * 128 + ks * 32 + g16 * 8) : zz;
      acc0 = mfmah(a, bch8(bv0), acc0);
      acc1 = mfmah(a, bch8(bv1), acc1);
    }
  }

  const int yb = yr * 32;
#pragma unroll
  for (int r = 0; r < 4; ++r) {
    const int co = ct * 16 + g16 * 4 + r;
    const float bv = bias[co];
    const int idx = (b * 64 + co) * 1024 + yb + nl;
    const float o0 = acc0[r] + bv;
    const float o1 = acc1[r] + bv;
    outA[idx] = o0; outA[idx + 16] = o1;
    if (st) { tdup[idx] = o0; tdup[idx + 16] = o1; }
  }
}

// ---------------------------------------------------------------------------
// Generic fp32 out[g][64][1024] = W[g/wdiv][64][K] @ X[g][K][1024] + bias
// (kept for attn_cam @ vc)
// ---------------------------------------------------------------------------
__global__ __launch_bounds__(256) void gemm64_kernel(
    const float* __restrict__ W, int wstride, int wdiv,
    const float* __restrict__ X, int xstride,
    float* __restrict__ out, int ostride,
    const float* __restrict__ bias, int bstride,
    int K)
{
  const int g  = blockIdx.x;
  const int n0 = blockIdx.y * 64;
  const float* Wg = W + (size_t)(g / wdiv) * wstride;
  const float* Xg = X + (size_t)g * xstride;
  const int t = threadIdx.x;
  __shared__ float Xs[32][64];
  __shared__ float Ws[32][64];
  const int tn = t & 15, cgp = t >> 4;
  const int n4 = tn * 4, co4 = cgp * 4;
  float acc[4][4] = {};

  for (int k0 = 0; k0 < K; k0 += 32) {
    {
      const int kk = t >> 4;
      const int nn = (t & 15) * 4;
      *reinterpret_cast<float4*>(&Xs[kk][nn]) =
          *reinterpret_cast<const float4*>(Xg + (size_t)(k0 + kk) * N_ + n0 + nn);
      *reinterpret_cast<float4*>(&Xs[kk + 16][nn]) =
          *reinterpret_cast<const float4*>(Xg + (size_t)(k0 + kk + 16) * N_ + n0 + nn);
    }
    {
      const int co = t & 63, q4 = t >> 6;
      const float* wp = Wg + (size_t)co * K + k0 + q4 * 8;
      const float4 a = *reinterpret_cast<const float4*>(wp);
      const float4 c = *reinterpret_cast<const float4*>(wp + 4);
      const int kb = q4 * 8;
      Ws[kb + 0][co] = a.x; Ws[kb + 1][co] = a.y; Ws[kb + 2][co] = a.z; Ws[kb + 3][co] = a.w;
      Ws[kb + 4][co] = c.x; Ws[kb + 5][co] = c.y; Ws[kb + 6][co] = c.z; Ws[kb + 7][co] = c.w;
    }
    __syncthreads();
#pragma unroll
    for (int kk = 0; kk < 32; ++kk) {
      const float4 xv = *reinterpret_cast<const float4*>(&Xs[kk][n4]);
      const float4 wv = *reinterpret_cast<const float4*>(&Ws[kk][co4]);
      const float xa[4] = {xv.x, xv.y, xv.z, xv.w};
      const float wa[4] = {wv.x, wv.y, wv.z, wv.w};
#pragma unroll
      for (int a = 0; a < 4; ++a)
#pragma unroll
        for (int b2 = 0; b2 < 4; ++b2)
          acc[a][b2] = fmaf(wa[a], xa[b2], acc[a][b2]);
    }
    __syncthreads();
  }

  float bv[4] = {0.f, 0.f, 0.f, 0.f};
  if (bias) {
    const float* bg = bias + (size_t)(g / wdiv) * bstride;
    bv[0] = bg[co4]; bv[1] = bg[co4 + 1]; bv[2] = bg[co4 + 2]; bv[3] = bg[co4 + 3];
  }
#pragma unroll
  for (int ii = 0; ii < 4; ++ii) {
    float4 o4;
    o4.x = acc[ii][0] + bv[ii]; o4.y = acc[ii][1] + bv[ii];
    o4.z = acc[ii][2] + bv[ii]; o4.w = acc[ii][3] + bv[ii];
    *reinterpret_cast<float4*>(out + (size_t)g * ostride + (co4 + ii) * N_ + n0 + n4) = o4;
  }
}

// ---------------------------------------------------------------------------
// proj: all 4 projections (q,k,v,vc) in ONE launch. grid (24, 16, 4):
// z selects weights/bias/input; outputs qb..vcb are contiguous (outbase+z*SZ).
// ---------------------------------------------------------------------------
__global__ __launch_bounds__(256) void proj_kernel(
    const float* __restrict__ Tm, const float* __restrict__ Sm,
    const float* __restrict__ wq, const float* __restrict__ wk,
    const float* __restrict__ wv2, const float* __restrict__ wc,
    const float* __restrict__ bq, const float* __restrict__ bk,
    const float* __restrict__ bv2, const float* __restrict__ bc,
    float* __restrict__ outbase)
{
  const int g  = blockIdx.x;          // i*8+b
  const int n0 = blockIdx.y * 64;
  const int z  = blockIdx.z;          // 0=q 1=k 2=v 3=vc
  const float* W  = (z == 0) ? wq : (z == 1) ? wk : (z == 2) ? wv2 : wc;
  const float* bi = (z == 0) ? bq : (z == 1) ? bk : (z == 2) ? bv2 : bc;
  const float* Xg = ((z == 1) ? Sm : Tm) + (size_t)g * PLANE;
  float* out = outbase + (size_t)z * SZ + (size_t)g * PLANE;
  const float* Wg = W + (g >> 3) * 4096;
  const float* bg = bi + (g >> 3) * 64;

  const int t = threadIdx.x;
  __shared__ float Xs[32][64];
  __shared__ float Ws[32][64];
  const int tn = t & 15, cgp = t >> 4;
  const int n4 = tn * 4, co4 = cgp * 4;
  float acc[4][4] = {};

#pragma unroll 1
  for (int k0 = 0; k0 < 64; k0 += 32) {
    {
      const int kk = t >> 4;
      const int nn = (t & 15) * 4;
      *reinterpret_cast<float4*>(&Xs[kk][nn]) =
          *reinterpret_cast<const float4*>(Xg + (size_t)(k0 + kk) * N_ + n0 + nn);
      *reinterpret_cast<float4*>(&Xs[kk + 16][nn]) =
          *reinterpret_cast<const float4*>(Xg + (size_t)(k0 + kk + 16) * N_ + n0 + nn);
    }
    {
      const int co = t & 63, q4 = t >> 6;
      const float* wp = Wg + (size_t)co * 64 + k0 + q4 * 8;
      const float4 a = *reinterpret_cast<const float4*>(wp);
      const float4 c = *reinterpret_cast<const float4*>(wp + 4);
      const int kb = q4 * 8;
      Ws[kb + 0][co] = a.x; Ws[kb + 1][co] = a.y; Ws[kb + 2][co] = a.z; Ws[kb + 3][co] = a.w;
      Ws[kb + 4][co] = c.x; Ws[kb + 5][co] = c.y; Ws[kb + 6][co] = c.z; Ws[kb + 7][co] = c.w;
    }
    __syncthreads();
#pragma unroll
    for (int kk = 0; kk < 32; ++kk) {
      const float4 xv = *reinterpret_cast<const float4*>(&Xs[kk][n4]);
      const float4 wv = *reinterpret_cast<const float4*>(&Ws[kk][co4]);
      const float xa[4] = {xv.x, xv.y, xv.z, xv.w};
      const float wa[4] = {wv.x, wv.y, wv.z, wv.w};
#pragma unroll
      for (int a = 0; a < 4; ++a)
#pragma unroll
        for (int b2 = 0; b2 < 4; ++b2)
          acc[a][b2] = fmaf(wa[a], xa[b2], acc[a][b2]);
    }
    __syncthreads();
  }

#pragma unroll
  for (int ii = 0; ii < 4; ++ii) {
    const float bv = bg[co4 + ii];
    float4 o4;
    o4.x = acc[ii][0] + bv; o4.y = acc[ii][1] + bv;
    o4.z = acc[ii][2] + bv; o4.w = acc[ii][3] + bv;
    *reinterpret_cast<float4*>(out + (co4 + ii) * N_ + n0 + n4) = o4;
  }
}

// ---------------------------------------------------------------------------
// whconv: fit-GEMM weights to fp16: wh1s@0, wh2s@16384, wh1t@49152, wh2t@65536
// ---------------------------------------------------------------------------
__global__ __launch_bounds__(256) void whconv_kernel(
    const float* __restrict__ w1s, const float* __restrict__ w2s,
    const float* __restrict__ w1t, const float* __restrict__ w2t,
    unsigned short* __restrict__ wh)
{
  const int p = blockIdx.x * 256 + threadIdx.x;  // pair index 0..49151
  const float* in; int local; unsigned short* out;
  if (p < 8192)       { in = w1s; local = p;         out = wh; }
  else if (p < 24576) { in = w2s; local = p - 8192;  out = wh + 16384; }
  else if (p < 32768) { in = w1t; local = p - 24576; out = wh + 49152; }
  else                { in = w2t; local = p - 32768; out = wh + 65536; }
  const float2 v = *reinterpret_cast<const float2*>(in + 2 * local);
  *reinterpret_cast<uint32*>(out + 2 * local) = pkh(v.x, v.y);
}

// ---------------------------------------------------------------------------
// gemmh: fp16 MFMA fit-GEMM. out[g][64co][1024n] = W[64][K] @ Xh[n][K].
// grid (16, 16); g<8 = src, g>=8 = tgt (+dual write).
// ---------------------------------------------------------------------------
__global__ __launch_bounds__(256) void gemmh_kernel(
    const unsigned short* __restrict__ Xa, const unsigned short* __restrict__ Xb,
    const unsigned short* __restrict__ Wa, const unsigned short* __restrict__ Wb,
    const float* __restrict__ ba, const float* __restrict__ bb,
    float* __restrict__ oa, float* __restrict__ ob, float* __restrict__ o2b,
    int K)
{
  const int g = blockIdx.x;
  const bool isb = g >= 8;
  const int gl = g & 7;
  const unsigned short* X = (isb ? Xb : Xa) + (size_t)gl * 1024 * K;
  const unsigned short* W = isb ? Wb : Wa;
  const float* bias = isb ? bb : ba;
  float* out = (isb ? ob : oa) + (size_t)gl * PLANE;
  float* out2 = isb ? o2b + (size_t)gl * PLANE : nullptr;

  const int t = threadIdx.x, lane = t & 63, wv = t >> 6;
  const int nl = lane & 15, g16 = lane >> 4;
  const int n0w = blockIdx.y * 64 + wv * 16;

  const unsigned short* xp = X + (size_t)(n0w + nl) * K + g16 * 8;
  const unsigned short* wp = W + (size_t)nl * K + g16 * 8;

  f32x4 acc[4];
#pragma unroll
  for (int ct = 0; ct < 4; ++ct) acc[ct] = f32x4{0.f, 0.f, 0.f, 0.f};

#pragma unroll 4
  for (int kk = 0; kk < K; kk += 32) {
    const h8 a = bch8(*reinterpret_cast<const uint4*>(xp + kk));
#pragma unroll
    for (int ct = 0; ct < 4; ++ct) {
      const h8 bfr = bch8(*reinterpret_cast<const uint4*>(wp + (size_t)ct * 16 * K + kk));
      acc[ct] = mfmah(a, bfr, acc[ct]);
    }
  }

#pragma unroll
  for (int ct = 0; ct < 4; ++ct) {
    const int co = ct * 16 + nl;
    const float bv = bias[co];
    float4 o4;
    o4.x = acc[ct][0] + bv; o4.y = acc[ct][1] + bv;
    o4.z = acc[ct][2] + bv; o4.w = acc[ct][3] + bv;
    const int idx = co * N_ + n0w + g16 * 4;
    *reinterpret_cast<float4*>(out + idx) = o4;
    if (out2) {
      out2[idx] = o4.x; out2[idx + 1] = o4.y;
      out2[idx + 2] = o4.z; out2[idx + 3] = o4.w;
    }
  }
}

// ---------------------------------------------------------------------------
// kprep: k[g][64c][1024m] -> kT[g][1024m][64c] (fp16); v[g] -> vh[g] (fp16).
// grid (24, 4)
// ---------------------------------------------------------------------------
__global__ __launch_bounds__(256) void kprep_kernel(
    const float* __restrict__ kb, const float* __restrict__ vb,
    unsigned short* __restrict__ kT, unsigned short* __restrict__ vh)
{
  const int g = blockIdx.x;
  const int ch = blockIdx.y;
  const int t = threadIdx.x;
  const float* kg = kb + (size_t)g * PLANE;
  __shared__ float tl[64][65];

#pragma unroll 1
  for (int tile = 0; tile < 4; ++tile) {
    const int m0 = ch * 256 + tile * 64;
    __syncthreads();
#pragma unroll 4
    for (int r = 0; r < 16; ++r) {
      const int c = r * 4 + (t >> 6);
      tl[c][t & 63] = kg[c * N_ + m0 + (t & 63)];
    }
    __syncthreads();
    const int mm = t >> 2, cseg = (t & 3) * 16;
    uint32 hw[8];
#pragma unroll
    for (int ii = 0; ii < 8; ++ii)
      hw[ii] = pkh(tl[cseg + 2 * ii][mm], tl[cseg + 2 * ii + 1][mm]);
    const size_t o = ((size_t)g * 1024 + m0 + mm) * 64 + cseg;
    uint4 h0; h0.x = hw[0]; h0.y = hw[1]; h0.z = hw[2]; h0.w = hw[3];
    uint4 h1; h1.x = hw[4]; h1.y = hw[5]; h1.z = hw[6]; h1.w = hw[7];
    *reinterpret_cast<uint4*>(kT + o)     = h0;
    *reinterpret_cast<uint4*>(kT + o + 8) = h1;
  }

  const float* vg = vb + (size_t)g * PLANE;
  unsigned short* vo = vh + (size_t)g * PLANE;
  for (int e8 = ch * 2048 + t; e8 < (ch + 1) * 2048; e8 += 256) {
    const float4 a = *reinterpret_cast<const float4*>(vg + (size_t)e8 * 8);
    const float4 b = *reinterpret_cast<const float4*>(vg + (size_t)e8 * 8 + 4);
    uint4 u;
    u.x = pkh(a.x, a.y); u.y = pkh(a.z, a.w);
    u.z = pkh(b.x, b.y); u.w = pkh(b.z, b.w);
    *reinterpret_cast<uint4*>(vo + (size_t)e8 * 8) = u;
  }
}

// ---------------------------------------------------------------------------
// e_cam[i,j,b][c][d] = sum_n T[i,b,c,n] * S[j,b,d,n];  also atomic raw-sum.
// ---------------------------------------------------------------------------
__global__ __launch_bounds__(256) void ecam_kernel(
    const float* __restrict__ T, const float* __restrict__ S,
    float* __restrict__ ecam, float* __restrict__ esum_cam)
{
  const int bx = blockIdx.x;
  const int b = bx & 7;
  const int j = (bx >> 3) % 3;
  const int i = bx / 24;
  const float* Tg = T + (size_t)(i * 8 + b) * PLANE;
  const float* Sg = S + (size_t)(j * 8 + b) * PLANE;
  const int t = threadIdx.x;
  __shared__ float Ts[64 * 68];
  __shared__ float Ss[64 * 68];
  __shared__ float rs[4];
  float acc[4][4] = {};
  const int c0 = (t & 15) * 4, d0 = (t >> 4) * 4;

  for (int nb = 0; nb < 1024; nb += 64) {
    __syncthreads();
    {
      const int nn = t & 63, rb = t >> 6;
#pragma unroll
      for (int r = 0; r < 16; ++r) {
        const int row = rb * 16 + r;
        Ts[nn * 68 + row] = Tg[row * N_ + nb + nn];
        Ss[nn * 68 + row] = Sg[row * N_ + nb + nn];
      }
    }
    __syncthreads();
#pragma unroll 8
    for (int nn = 0; nn < 64; ++nn) {
      const float4 tv = *reinterpret_cast<const float4*>(&Ts[nn * 68 + c0]);
      const float4 sv = *reinterpret_cast<const float4*>(&Ss[nn * 68 + d0]);
      const float ta[4] = {tv.x, tv.y, tv.z, tv.w};
      const float sa[4] = {sv.x, sv.y, sv.z, sv.w};
#pragma unroll
      for (int ci = 0; ci < 4; ++ci)
#pragma unroll
        for (int di = 0; di < 4; ++di)
          acc[ci][di] = fmaf(ta[ci], sa[di], acc[ci][di]);
    }
  }
  float s = 0.f;
#pragma unroll
  for (int ci = 0; ci < 4; ++ci)
#pragma unroll
    for (int di = 0; di < 4; ++di) s += acc[ci][di];
  s = wred_sum(s);
  if ((t & 63) == 0) rs[t >> 6] = s;
  __syncthreads();
  if (t == 0) atomicAdd(esum_cam + i * 3 + j, rs[0] + rs[1] + rs[2] + rs[3]);

  float* eo = ecam + (size_t)((i * 3 + j) * 8 + b) * 4096;
#pragma unroll
  for (int ci = 0; ci < 4; ++ci) {
    float4 o4; o4.x = acc[ci][0]; o4.y = acc[ci][1]; o4.z = acc[ci][2]; o4.w = acc[ci][3];
    *reinterpret_cast<float4*>(eo + (c0 + ci) * 64 + d0) = o4;
  }
}

// ---------------------------------------------------------------------------
// attn_cam[i,b][c][d] = sum_j softmax_d(e_cam[i,j,b,c,:])[d]     grid 24
// ---------------------------------------------------------------------------
__global__ __launch_bounds__(256) void acam_kernel(
    const float* __restrict__ ecam, float* __restrict__ acam)
{
  const int bx = blockIdx.x;
  const int b = bx & 7, i = bx >> 3;
  const int t = threadIdx.x;
  const int c = t >> 2, seg = t & 3;
  float acc[16] = {};
#pragma unroll
  for (int j = 0; j < 3; ++j) {
    const float* e = ecam + (size_t)((i * 3 + j) * 8 + b) * 4096 + c * 64 + seg * 16;
    float ev[16];
#pragma unroll
    for (int r = 0; r < 4; ++r) {
      const float4 v4 = *reinterpret_cast<const float4*>(e + r * 4);
      ev[4 * r] = v4.x; ev[4 * r + 1] = v4.y; ev[4 * r + 2] = v4.z; ev[4 * r + 3] = v4.w;
    }
    float mx = ev[0];
#pragma unroll
    for (int r = 1; r < 16; ++r) mx = fmaxf(mx, ev[r]);
    mx = fmaxf(mx, __shfl_xor(mx, 1, 4));
    mx = fmaxf(mx, __shfl_xor(mx, 2, 4));
    float pv[16], ss = 0.f;
#pragma unroll
    for (int r = 0; r < 16; ++r) { pv[r] = __expf(ev[r] - mx); ss += pv[r]; }
    ss += __shfl_xor(ss, 1, 4);
    ss += __shfl_xor(ss, 2, 4);
    const float rc = 1.f / ss;
#pragma unroll
    for (int r = 0; r < 16; ++r) acc[r] += pv[r] * rc;
  }
  float* ao = acam + (size_t)(i * 8 + b) * 4096 + c * 64 + seg * 16;
#pragma unroll
  for (int r = 0; r < 4; ++r) {
    float4 o4; o4.x = acc[4 * r]; o4.y = acc[4 * r + 1]; o4.z = acc[4 * r + 2]; o4.w = acc[4 * r + 3];
    *reinterpret_cast<float4*>(ao + r * 4) = o4;
  }
}

// ---------------------------------------------------------------------------
// PAM via single-pass fp16 MFMA. grid 1536 = (i, b, qt), 512 threads (8 waves
// x 128 m). QK tt loop fully unrolled: 16 loads in flight.
// ---------------------------------------------------------------------------
__global__ __launch_bounds__(512, 4) void pam_mfma_kernel(
    const float* __restrict__ q, const unsigned short* __restrict__ kT,
    const unsigned short* __restrict__ vh,
    const float* __restrict__ ocam, float* __restrict__ tgts, float* __restrict__ esum_pam)
{
  const int bx = blockIdx.x;
  const int qt = bx & 63;
  const int b  = (bx >> 6) & 7;
  const int i  = bx >> 9;
  const int n0 = qt * 16;
  const int t = threadIdx.x;
  const int lane = t & 63;
  const int wv = t >> 6;             // 0..7
  const int nl = lane & 15;
  const int g16 = lane >> 4;

  __shared__ unsigned short Plds[16 * 1024];  // 32 KB fp16, [n][m ^ (8n)]
  __shared__ float qlds[64 * 17];             // q staging; aliased as osum later
  __shared__ float redmx[128];
  __shared__ float redse[128];
  __shared__ float redes[8];
  float* osum = qlds;

  const size_t ibo = (size_t)(i * 8 + b) * PLANE;

  const float* qg = q + ibo;
  for (int e = t; e < 1024; e += 512)
    qlds[(e >> 4) * 17 + (e & 15)] = qg[(e >> 4) * N_ + n0 + (e & 15)];
  __syncthreads();

  h8 qh[2];
#pragma unroll
  for (int ks = 0; ks < 2; ++ks) {
#pragma unroll
    for (int idx = 0; idx < 8; ++idx)
      qh[ks][idx] = (_Float16)qlds[(ks * 32 + g16 * 8 + idx) * 17 + nl];
  }

  const int wm0 = wv * 128;
  const int ct = wv & 3;
  const int mh = wv >> 2;
  const unsigned short* vg = vh + ibo + (size_t)(ct * 16 + nl) * 1024 + mh * 512 + g16 * 8;
  f32x4 oat = f32x4{0.f, 0.f, 0.f, 0.f};

#pragma unroll 1
  for (int j = 0; j < 3; ++j) {
    const unsigned short* kp =
        kT + ((size_t)(j * 8 + b) * 1024 + wm0 + nl) * 64 + g16 * 8;

    f32x4 l4[8];
#pragma unroll
    for (int tt = 0; tt < 8; ++tt) {
      const int off = tt * 1024;
      const uint4 k0 = *reinterpret_cast<const uint4*>(kp + off);
      const uint4 k1 = *reinterpret_cast<const uint4*>(kp + off + 32);
      f32x4 a = f32x4{0.f, 0.f, 0.f, 0.f};
      a = mfmah(bch8(k0), qh[0], a);
      a = mfmah(bch8(k1), qh[1], a);
      l4[tt] = a;
    }

    float pm = -3.4e38f, es = 0.f;
#pragma unroll
    for (int tt = 0; tt < 8; ++tt) {
#pragma unroll
      for (int r = 0; r < 4; ++r) { pm = fmaxf(pm, l4[tt][r]); es += l4[tt][r]; }
    }
    pm = fmaxf(pm, __shfl_xor(pm, 16, 64));
    pm = fmaxf(pm, __shfl_xor(pm, 32, 64));
    es = wred_sum(es);
    if (lane < 16) redmx[wv * 16 + lane] = pm;
    if (lane == 0) redes[wv] = es;
    __syncthreads();
    float mx = redmx[nl];
#pragma unroll
    for (int w = 1; w < 8; ++w) mx = fmaxf(mx, redmx[w * 16 + nl]);
    if (t == 0) {
      float s = 0.f;
#pragma unroll
      for (int w = 0; w < 8; ++w) s += redes[w];
      atomicAdd(esum_pam + i * 3 + j, s);
    }

    float ps = 0.f;
#pragma unroll
    for (int tt = 0; tt < 8; ++tt) {
#pragma unroll
      for (int r = 0; r < 4; ++r) {
        l4[tt][r] = __expf(l4[tt][r] - mx);
        ps += l4[tt][r];
      }
    }
#pragma unroll
    for (int tt = 0; tt < 8; ++tt) {
      const int m = wm0 + tt * 16 + g16 * 4;
      uint2 w2;
      w2.x = pkh(l4[tt][0], l4[tt][1]);
      w2.y = pkh(l4[tt][2], l4[tt][3]);
      *reinterpret_cast<uint2*>(&Plds[nl * 1024 + (m ^ (nl * 8))]) = w2;
    }
    ps += __shfl_xor(ps, 16, 64);
    ps += __shfl_xor(ps, 32, 64);
    if (lane < 16) redse[wv * 16 + lane] = ps;
    __syncthreads();
    float den = redse[nl];
#pragma unroll
    for (int w = 1; w < 8; ++w) den += redse[w * 16 + nl];
    const float rs = 1.f / den;

    f32x4 oa = f32x4{0.f, 0.f, 0.f, 0.f};
    f32x4 ob = f32x4{0.f, 0.f, 0.f, 0.f};
#pragma unroll 4
    for (int ks = 0; ks < 16; ks += 2) {
      const int ml0 = mh * 512 + ks * 32 + g16 * 8;
      const int ml1 = ml0 + 32;
      const uint4 va0 = *reinterpret_cast<const uint4*>(vg + ks * 32);
      const uint4 pf0 = *reinterpret_cast<const uint4*>(&Plds[nl * 1024 + (ml0 ^ (nl * 8))]);
      const uint4 va1 = *reinterpret_cast<const uint4*>(vg + ks * 32 + 32);
      const uint4 pf1 = *reinterpret_cast<const uint4*>(&Plds[nl * 1024 + (ml1 ^ (nl * 8))]);
      oa = mfmah(bch8(va0), bch8(pf0), oa);
      ob = mfmah(bch8(va1), bch8(pf1), ob);
    }
#pragma unroll
    for (int r = 0; r < 4; ++r) oat[r] += rs * (oa[r] + ob[r]);
  }

  if (mh == 0) {
#pragma unroll
    for (int r = 0; r < 4; ++r)
      osum[(ct * 16 + g16 * 4 + r) * 16 + nl] = oat[r];
  }
  __syncthreads();
  if (mh == 1) {
    const float* og = ocam + ibo;
    float* outg = tgts + (size_t)(2 * i * 8 + b) * PLANE;
#pragma unroll
    for (int r = 0; r < 4; ++r) {
      const int c = ct * 16 + g16 * 4 + r;
      const int idx = c * N_ + n0 + nl;
      outg[idx] = 0.5f * (oat[r] + osum[c * 16 + nl] + og[idx]);
    }
  }
}

// ---------------------------------------------------------------------------
// alpha[i][j] = 0.5*(softmax_j(mean e_pam) + softmax_j(mean e_cam))
// ---------------------------------------------------------------------------
__global__ void alpha_kernel(const float* __restrict__ esum, float* __restrict__ alpha)
{
  const int t = threadIdx.x;
  if (t >= 9) return;
  const int i = t / 3, j = t % 3;
  float p[3], c[3];
#pragma unroll
  for (int jj = 0; jj < 3; ++jj) {
    p[jj] = esum[i * 3 + jj] * (1.0f / 8388608.0f);
    c[jj] = esum[9 + i * 3 + jj] * (1.0f / 32768.0f);
  }
  const float mp = fmaxf(p[0], fmaxf(p[1], p[2]));
  const float mc = fmaxf(c[0], fmaxf(c[1], c[2]));
  float sp = 0.f, sc = 0.f;
#pragma unroll
  for (int jj = 0; jj < 3; ++jj) { sp += __expf(p[jj] - mp); sc += __expf(c[jj] - mc); }
  alpha[t] = 0.5f * (__expf(p[j] - mp) / sp + __expf(c[j] - mc) / sc);
}

// ---------------------------------------------------------------------------
extern "C" void kernel_launch(void* const* d_in, const int* in_sizes, int n_in,
                              void* d_out, int out_size, void* d_ws, size_t ws_size,
                              hipStream_t stream)
{
  const float* src0 = (const float*)d_in[0];
  const float* src1 = (const float*)d_in[1];
  const float* src2 = (const float*)d_in[2];
  const float* tgt0 = (const float*)d_in[3];
  const float* tgt1 = (const float*)d_in[4];
  const float* tgt2 = (const float*)d_in[5];
  const float* fs0_w = (const float*)d_in[6];  const float* fs0_b = (const float*)d_in[7];
  const float* fs1_w = (const float*)d_in[8];  const float* fs1_b = (const float*)d_in[9];
  const float* fs2_w = (const float*)d_in[10]; const float* fs2_b = (const float*)d_in[11];
  const float* ft0_w = (const float*)d_in[12]; const float* ft0_b = (const float*)d_in[13];
  const float* ft1_w = (const float*)d_in[14]; const float* ft1_b = (const float*)d_in[15];
  const float* ft2_w = (const float*)d_in[16]; const float* ft2_b = (const float*)d_in[17];
  const float* pq_w = (const float*)d_in[18];  const float* pq_b = (const float*)d_in[19];
  const float* pk_w = (const float*)d_in[20];  const float* pk_b = (const float*)d_in[21];
  const float* pv_w = (const float*)d_in[22];  const float* pv_b = (const float*)d_in[23];
  const float* cv_w = (const float*)d_in[24];  const float* cv_b = (const float*)d_in[25];

  float* out = (float*)d_out;
  float* S     = out;                 // srcs region doubles as S storage
  float* alpha = out + SZ;            // 9 floats
  float* tgts  = out + SZ + 9;        // [2L][B][PLANE]

  float* ws   = (float*)d_ws;
  float* T    = ws;
  float* qb   = ws + (size_t)SZ;
  float* kb   = ws + (size_t)2 * SZ;
  float* vb   = ws + (size_t)3 * SZ;
  float* vcb  = ws + (size_t)4 * SZ;
  float* ocam = ws + (size_t)5 * SZ;
  float* ecam = ws + (size_t)6 * SZ;                 // 294912
  float* acam = ws + (size_t)6 * SZ + 294912;        // 98304
  float* esum = ws + (size_t)6 * SZ + 393216;        // 18 (pam 9, cam 9)

  // fp16 buffers appended after the fp32 region
  unsigned short* kT = (unsigned short*)(ws + (size_t)6 * SZ + 393216 + 256);
  unsigned short* vh = kT + (size_t)24 * PLANE;
  unsigned short* wh = vh + (size_t)24 * PLANE;      // 98304 ushorts
  unsigned short* w9s = wh + 98304;                  // 73728 ushorts
  unsigned short* w9t = w9s + 73728;

  // Overlays in qb..vcb (each consumed before the next producer writes):
  // 1) inTs/inTt (channels-last fp16 conv inputs), consumed by conv0_mfma
  unsigned short* inTs = (unsigned short*)qb;        // 8*4096*128
  unsigned short* inTt = inTs + 4194304;
  // 2) Xh (fp16 transposed fit-GEMM inputs), consumed by gemmh
  unsigned short* Xs1 = (unsigned short*)qb;         // 8x1024x256
  unsigned short* Xs2 = Xs1 + 2097152;               // 8x1024x512
  unsigned short* Xt1 = Xs1 + 6291456;               // 8x1024x256
  unsigned short* Xt2 = Xs1 + 8388608;               // 8x1024x512

  hipMemsetAsync(esum, 0, 18 * sizeof(float), stream);

  // conv0 via MFMA: channels-last fp16 inputs + fp16 tap weights
  w9conv_kernel<<<576, 256, 0, stream>>>(fs0_w, ft0_w, w9s, w9t);
  xprep_kernel<<<dim3(8, 2, 64), 256, 0, stream>>>(src0, inTs, 128, 4096);
  xprep_kernel<<<dim3(8, 2, 64), 256, 0, stream>>>(tgt0, inTt, 128, 4096);
  conv0_mfma_kernel<<<dim3(32, 8, 2), 256, 0, stream>>>(
      inTs, inTt, w9s, w9t, fs0_b, ft0_b, S, T, tgts + (size_t)1 * BPL);

  // fp16 fit GEMMs (overwrite the inT overlay with Xh)
  xprep_kernel<<<dim3(8, 4, 16), 256, 0, stream>>>(src1, Xs1, 256, 1024);
  xprep_kernel<<<dim3(8, 8, 16), 256, 0, stream>>>(src2, Xs2, 512, 1024);
  xprep_kernel<<<dim3(8, 4, 16), 256, 0, stream>>>(tgt1, Xt1, 256, 1024);
  xprep_kernel<<<dim3(8, 8, 16), 256, 0, stream>>>(tgt2, Xt2, 512, 1024);
  whconv_kernel<<<192, 256, 0, stream>>>(fs1_w, fs2_w, ft1_w, ft2_w, wh);
  gemmh_kernel<<<dim3(16, 16), 256, 0, stream>>>(
      Xs1, Xt1, wh, wh + 49152, fs1_b, ft1_b,
      S + BPL, T + BPL, tgts + (size_t)3 * BPL, 256);
  gemmh_kernel<<<dim3(16, 16), 256, 0, stream>>>(
      Xs2, Xt2, wh + 16384, wh + 65536, fs2_b, ft2_b,
      S + 2 * BPL, T + 2 * BPL, tgts + (size_t)5 * BPL, 512);

  // All 4 projections in one launch (writes qb..vcb, overwriting the overlay)
  proj_kernel<<<dim3(24, 16, 4), 256, 0, stream>>>(
      T, S, pq_w, pk_w, pv_w, cv_w, pq_b, pk_b, pv_b, cv_b, qb);

  // Pack k (transposed fp16) and v (fp16) for the MFMA attention
  kprep_kernel<<<dim3(24, 4), 256, 0, stream>>>(kb, vb, kT, vh);

  // CAM
  ecam_kernel<<<72, 256, 0, stream>>>(T, S, ecam, esum + 9);
  acam_kernel<<<24, 256, 0, stream>>>(ecam, acam);
  gemm64_kernel<<<dim3(24, 16), 256, 0, stream>>>(acam, 4096, 1, vcb, PLANE, ocam, PLANE,
                                                  nullptr, 0, 64);

  // PAM + fuse (writes tgts even slots = 0.5*(out_pam + out_cam))
  pam_mfma_kernel<<<1536, 512, 0, stream>>>(qb, kT, vh, ocam, tgts, esum);

  alpha_kernel<<<1, 64, 0, stream>>>(esum, alpha);
}

// Round 12
// 364.200 us; speedup vs baseline: 1.5831x; 1.0016x over previous
//
#include <hip/hip_runtime.h>

// Problem constants
static constexpr int L_ = 3, B_ = 8, C_ = 64, N_ = 1024;
static constexpr int PLANE = C_ * N_;       // 65536
static constexpr int SZ    = L_ * B_ * PLANE; // 1572864
static constexpr int BPL   = B_ * PLANE;    // 524288

#define DI __device__ __forceinline__

typedef _Float16 h8 __attribute__((ext_vector_type(8)));   // 8 fp16 (MFMA A/B frag)
typedef __attribute__((ext_vector_type(4))) float f32x4;   // MFMA C/D frag
typedef unsigned int uint32;

DI float wred_sum(float v) {
#pragma unroll
  for (int m = 1; m < 64; m <<= 1) v += __shfl_xor(v, m, 64);
  return v;
}

DI unsigned short f2h(float f) {
  return __builtin_bit_cast(unsigned short, (_Float16)f);
}
DI uint32 pkh(float a, float b) {
  return (uint32)f2h(a) | ((uint32)f2h(b) << 16);
}
DI h8 bch8(uint4 v) { return __builtin_bit_cast(h8, v); }

DI f32x4 mfmah(h8 a, h8 b, f32x4 c) {
  return __builtin_amdgcn_mfma_f32_16x16x32_f16(a, b, c, 0, 0, 0);
}

// ---------------------------------------------------------------------------
// xprep: transpose+convert in[g][K][N] fp32 -> out[g][N][K] fp16.
// grid (8, K/64, N/64); 64x64 tile per block.
// ---------------------------------------------------------------------------
__global__ __launch_bounds__(256) void xprep_kernel(
    const float* __restrict__ in, unsigned short* __restrict__ out, int K, int N)
{
  const int g = blockIdx.x, kc = blockIdx.y, nc = blockIdx.z;
  const int t = threadIdx.x;
  __shared__ float tl[64][65];
  const float* ing = in + (size_t)g * K * N + (size_t)(kc * 64) * N + nc * 64;
#pragma unroll 4
  for (int r = 0; r < 16; ++r) {
    const int kk = r * 4 + (t >> 6);
    tl[kk][t & 63] = ing[(size_t)kk * N + (t & 63)];
  }
  __syncthreads();
  const int mm = t >> 2, kseg = (t & 3) * 16;
  uint32 hw[8];
#pragma unroll
  for (int ii = 0; ii < 8; ++ii)
    hw[ii] = pkh(tl[kseg + 2 * ii][mm], tl[kseg + 2 * ii + 1][mm]);
  unsigned short* o = out + ((size_t)g * N + nc * 64 + mm) * K + kc * 64 + kseg;
  uint4 h0; h0.x = hw[0]; h0.y = hw[1]; h0.z = hw[2]; h0.w = hw[3];
  uint4 h1; h1.x = hw[4]; h1.y = hw[5]; h1.z = hw[6]; h1.w = hw[7];
  *reinterpret_cast<uint4*>(o)     = h0;
  *reinterpret_cast<uint4*>(o + 8) = h1;
}

// ---------------------------------------------------------------------------
// w9conv: conv weights w[co][ci][k9] fp32 -> w9[k9][co][ci] fp16 (both s,t).
// grid 576.
// ---------------------------------------------------------------------------
__global__ __launch_bounds__(256) void w9conv_kernel(
    const float* __restrict__ w_s, const float* __restrict__ w_t,
    unsigned short* __restrict__ w9_s, unsigned short* __restrict__ w9_t)
{
  const int e = blockIdx.x * 256 + threadIdx.x;  // 0..147455
  const float* w = (e < 73728) ? w_s : w_t;
  unsigned short* o = (e < 73728) ? w9_s : w9_t;
  const int le = (e < 73728) ? e : e - 73728;
  const int ci = le & 127;
  const int q = le >> 7;
  const int co = q & 63;
  const int k9 = q >> 6;
  o[le] = f2h(w[(co * 128 + ci) * 9 + k9]);
}

// ---------------------------------------------------------------------------
// conv0 via MFMA: 3x3 s2 p1, 128->64, using channels-last fp16 inT[b][pix][ci]
// and w9[tap][co][ci]. grid (32 out-rows, 8 b, 2 st), 256 thr = 4 waves
// (wave = co-tile). Per tap x ks: 1 A-load + 2 predicated B-loads + 2 MFMA.
// ---------------------------------------------------------------------------
__global__ __launch_bounds__(256) void conv0_mfma_kernel(
    const unsigned short* __restrict__ inT_s, const unsigned short* __restrict__ inT_t,
    const unsigned short* __restrict__ w9_s, const unsigned short* __restrict__ w9_t,
    const float* __restrict__ b_s, const float* __restrict__ b_t,
    float* __restrict__ Sout, float* __restrict__ Tout, float* __restrict__ tdup)
{
  const int yr = blockIdx.x;          // output row 0..31
  const int b  = blockIdx.y;
  const int st = blockIdx.z;
  const unsigned short* inT = st ? inT_t : inT_s;
  const unsigned short* w9  = st ? w9_t  : w9_s;
  const float* bias = st ? b_t : b_s;
  float* outA = st ? Tout : Sout;

  const int t = threadIdx.x, lane = t & 63;
  const int ct = t >> 6;              // co-tile
  const int nl = lane & 15, g16 = lane >> 4;
  const unsigned short* inb = inT + (size_t)b * (4096 * 128);
  const unsigned short* wbase = w9 + (size_t)(ct * 16 + nl) * 128;

  f32x4 acc0 = f32x4{0.f, 0.f, 0.f, 0.f};
  f32x4 acc1 = f32x4{0.f, 0.f, 0.f, 0.f};
  const uint4 zz = uint4{0u, 0u, 0u, 0u};

#pragma unroll 1
  for (int tap = 0; tap < 9; ++tap) {
    const int ky = tap / 3, kx = tap - 3 * (tap / 3);
    const int py = 2 * yr - 1 + ky;                 // [-1, 63]
    const int px0 = 2 * nl - 1 + kx;                // nt=0: x = nl
    const int px1 = px0 + 32;                       // nt=1: x = 16+nl (>=31)
    const bool v0 = (py >= 0) && (px0 >= 0);
    const bool v1 = (py >= 0);
    const unsigned short* prow = inb + (ptrdiff_t)py * (64 * 128);
#pragma unroll
    for (int ks = 0; ks < 4; ++ks) {
      const h8 a = bch8(*reinterpret_cast<const uint4*>(
          wbase + tap * 8192 + ks * 32 + g16 * 8));
      const uint4 bv0 = v0 ? *reinterpret_cast<const uint4*>(
                                 prow + px0 * 128 + ks * 32 + g16 * 8) : zz;
      const uint4 bv1 = v1 ? *reinterpret_cast<const uint4*>(
                                 prow + px1 * 128 + ks * 32 + g16 * 8) : zz;
      acc0 = mfmah(a, bch8(bv0), acc0);
      acc1 = mfmah(a, bch8(bv1), acc1);
    }
  }

  const int yb = yr * 32;
#pragma unroll
  for (int r = 0; r < 4; ++r) {
    const int co = ct * 16 + g16 * 4 + r;
    const float bv = bias[co];
    const int idx = (b * 64 + co) * 1024 + yb + nl;
    const float o0 = acc0[r] + bv;
    const float o1 = acc1[r] + bv;
    outA[idx] = o0; outA[idx + 16] = o1;
    if (st) { tdup[idx] = o0; tdup[idx + 16] = o1; }
  }
}

// ---------------------------------------------------------------------------
// Generic fp32 out[g][64][1024] = W[g/wdiv][64][K] @ X[g][K][1024] + bias
// (kept for attn_cam @ vc)
// ---------------------------------------------------------------------------
__global__ __launch_bounds__(256) void gemm64_kernel(
    const float* __restrict__ W, int wstride, int wdiv,
    const float* __restrict__ X, int xstride,
    float* __restrict__ out, int ostride,
    const float* __restrict__ bias, int bstride,
    int K)
{
  const int g  = blockIdx.x;
  const int n0 = blockIdx.y * 64;
  const float* Wg = W + (size_t)(g / wdiv) * wstride;
  const float* Xg = X + (size_t)g * xstride;
  const int t = threadIdx.x;
  __shared__ float Xs[32][64];
  __shared__ float Ws[32][64];
  const int tn = t & 15, cgp = t >> 4;
  const int n4 = tn * 4, co4 = cgp * 4;
  float acc[4][4] = {};

  for (int k0 = 0; k0 < K; k0 += 32) {
    {
      const int kk = t >> 4;
      const int nn = (t & 15) * 4;
      *reinterpret_cast<float4*>(&Xs[kk][nn]) =
          *reinterpret_cast<const float4*>(Xg + (size_t)(k0 + kk) * N_ + n0 + nn);
      *reinterpret_cast<float4*>(&Xs[kk + 16][nn]) =
          *reinterpret_cast<const float4*>(Xg + (size_t)(k0 + kk + 16) * N_ + n0 + nn);
    }
    {
      const int co = t & 63, q4 = t >> 6;
      const float* wp = Wg + (size_t)co * K + k0 + q4 * 8;
      const float4 a = *reinterpret_cast<const float4*>(wp);
      const float4 c = *reinterpret_cast<const float4*>(wp + 4);
      const int kb = q4 * 8;
      Ws[kb + 0][co] = a.x; Ws[kb + 1][co] = a.y; Ws[kb + 2][co] = a.z; Ws[kb + 3][co] = a.w;
      Ws[kb + 4][co] = c.x; Ws[kb + 5][co] = c.y; Ws[kb + 6][co] = c.z; Ws[kb + 7][co] = c.w;
    }
    __syncthreads();
#pragma unroll
    for (int kk = 0; kk < 32; ++kk) {
      const float4 xv = *reinterpret_cast<const float4*>(&Xs[kk][n4]);
      const float4 wv = *reinterpret_cast<const float4*>(&Ws[kk][co4]);
      const float xa[4] = {xv.x, xv.y, xv.z, xv.w};
      const float wa[4] = {wv.x, wv.y, wv.z, wv.w};
#pragma unroll
      for (int a = 0; a < 4; ++a)
#pragma unroll
        for (int b2 = 0; b2 < 4; ++b2)
          acc[a][b2] = fmaf(wa[a], xa[b2], acc[a][b2]);
    }
    __syncthreads();
  }

  float bv[4] = {0.f, 0.f, 0.f, 0.f};
  if (bias) {
    const float* bg = bias + (size_t)(g / wdiv) * bstride;
    bv[0] = bg[co4]; bv[1] = bg[co4 + 1]; bv[2] = bg[co4 + 2]; bv[3] = bg[co4 + 3];
  }
#pragma unroll
  for (int ii = 0; ii < 4; ++ii) {
    float4 o4;
    o4.x = acc[ii][0] + bv[ii]; o4.y = acc[ii][1] + bv[ii];
    o4.z = acc[ii][2] + bv[ii]; o4.w = acc[ii][3] + bv[ii];
    *reinterpret_cast<float4*>(out + (size_t)g * ostride + (co4 + ii) * N_ + n0 + n4) = o4;
  }
}

// ---------------------------------------------------------------------------
// proj: all 4 projections (q,k,v,vc) in ONE launch. grid (24, 16, 4):
// z selects weights/bias/input; outputs qb..vcb are contiguous (outbase+z*SZ).
// ---------------------------------------------------------------------------
__global__ __launch_bounds__(256) void proj_kernel(
    const float* __restrict__ Tm, const float* __restrict__ Sm,
    const float* __restrict__ wq, const float* __restrict__ wk,
    const float* __restrict__ wv2, const float* __restrict__ wc,
    const float* __restrict__ bq, const float* __restrict__ bk,
    const float* __restrict__ bv2, const float* __restrict__ bc,
    float* __restrict__ outbase)
{
  const int g  = blockIdx.x;          // i*8+b
  const int n0 = blockIdx.y * 64;
  const int z  = blockIdx.z;          // 0=q 1=k 2=v 3=vc
  const float* W  = (z == 0) ? wq : (z == 1) ? wk : (z == 2) ? wv2 : wc;
  const float* bi = (z == 0) ? bq : (z == 1) ? bk : (z == 2) ? bv2 : bc;
  const float* Xg = ((z == 1) ? Sm : Tm) + (size_t)g * PLANE;
  float* out = outbase + (size_t)z * SZ + (size_t)g * PLANE;
  const float* Wg = W + (g >> 3) * 4096;
  const float* bg = bi + (g >> 3) * 64;

  const int t = threadIdx.x;
  __shared__ float Xs[32][64];
  __shared__ float Ws[32][64];
  const int tn = t & 15, cgp = t >> 4;
  const int n4 = tn * 4, co4 = cgp * 4;
  float acc[4][4] = {};

#pragma unroll 1
  for (int k0 = 0; k0 < 64; k0 += 32) {
    {
      const int kk = t >> 4;
      const int nn = (t & 15) * 4;
      *reinterpret_cast<float4*>(&Xs[kk][nn]) =
          *reinterpret_cast<const float4*>(Xg + (size_t)(k0 + kk) * N_ + n0 + nn);
      *reinterpret_cast<float4*>(&Xs[kk + 16][nn]) =
          *reinterpret_cast<const float4*>(Xg + (size_t)(k0 + kk + 16) * N_ + n0 + nn);
    }
    {
      const int co = t & 63, q4 = t >> 6;
      const float* wp = Wg + (size_t)co * 64 + k0 + q4 * 8;
      const float4 a = *reinterpret_cast<const float4*>(wp);
      const float4 c = *reinterpret_cast<const float4*>(wp + 4);
      const int kb = q4 * 8;
      Ws[kb + 0][co] = a.x; Ws[kb + 1][co] = a.y; Ws[kb + 2][co] = a.z; Ws[kb + 3][co] = a.w;
      Ws[kb + 4][co] = c.x; Ws[kb + 5][co] = c.y; Ws[kb + 6][co] = c.z; Ws[kb + 7][co] = c.w;
    }
    __syncthreads();
#pragma unroll
    for (int kk = 0; kk < 32; ++kk) {
      const float4 xv = *reinterpret_cast<const float4*>(&Xs[kk][n4]);
      const float4 wv = *reinterpret_cast<const float4*>(&Ws[kk][co4]);
      const float xa[4] = {xv.x, xv.y, xv.z, xv.w};
      const float wa[4] = {wv.x, wv.y, wv.z, wv.w};
#pragma unroll
      for (int a = 0; a < 4; ++a)
#pragma unroll
        for (int b2 = 0; b2 < 4; ++b2)
          acc[a][b2] = fmaf(wa[a], xa[b2], acc[a][b2]);
    }
    __syncthreads();
  }

#pragma unroll
  for (int ii = 0; ii < 4; ++ii) {
    const float bv = bg[co4 + ii];
    float4 o4;
    o4.x = acc[ii][0] + bv; o4.y = acc[ii][1] + bv;
    o4.z = acc[ii][2] + bv; o4.w = acc[ii][3] + bv;
    *reinterpret_cast<float4*>(out + (co4 + ii) * N_ + n0 + n4) = o4;
  }
}

// ---------------------------------------------------------------------------
// whconv: fit-GEMM weights to fp16: wh1s@0, wh2s@16384, wh1t@49152, wh2t@65536
// ---------------------------------------------------------------------------
__global__ __launch_bounds__(256) void whconv_kernel(
    const float* __restrict__ w1s, const float* __restrict__ w2s,
    const float* __restrict__ w1t, const float* __restrict__ w2t,
    unsigned short* __restrict__ wh)
{
  const int p = blockIdx.x * 256 + threadIdx.x;  // pair index 0..49151
  const float* in; int local; unsigned short* out;
  if (p < 8192)       { in = w1s; local = p;         out = wh; }
  else if (p < 24576) { in = w2s; local = p - 8192;  out = wh + 16384; }
  else if (p < 32768) { in = w1t; local = p - 24576; out = wh + 49152; }
  else                { in = w2t; local = p - 32768; out = wh + 65536; }
  const float2 v = *reinterpret_cast<const float2*>(in + 2 * local);
  *reinterpret_cast<uint32*>(out + 2 * local) = pkh(v.x, v.y);
}

// ---------------------------------------------------------------------------
// gemmh: fp16 MFMA fit-GEMM. out[g][64co][1024n] = W[64][K] @ Xh[n][K].
// grid (16, 16); g<8 = src, g>=8 = tgt (+dual write).
// ---------------------------------------------------------------------------
__global__ __launch_bounds__(256) void gemmh_kernel(
    const unsigned short* __restrict__ Xa, const unsigned short* __restrict__ Xb,
    const unsigned short* __restrict__ Wa, const unsigned short* __restrict__ Wb,
    const float* __restrict__ ba, const float* __restrict__ bb,
    float* __restrict__ oa, float* __restrict__ ob, float* __restrict__ o2b,
    int K)
{
  const int g = blockIdx.x;
  const bool isb = g >= 8;
  const int gl = g & 7;
  const unsigned short* X = (isb ? Xb : Xa) + (size_t)gl * 1024 * K;
  const unsigned short* W = isb ? Wb : Wa;
  const float* bias = isb ? bb : ba;
  float* out = (isb ? ob : oa) + (size_t)gl * PLANE;
  float* out2 = isb ? o2b + (size_t)gl * PLANE : nullptr;

  const int t = threadIdx.x, lane = t & 63, wv = t >> 6;
  const int nl = lane & 15, g16 = lane >> 4;
  const int n0w = blockIdx.y * 64 + wv * 16;

  const unsigned short* xp = X + (size_t)(n0w + nl) * K + g16 * 8;
  const unsigned short* wp = W + (size_t)nl * K + g16 * 8;

  f32x4 acc[4];
#pragma unroll
  for (int ct = 0; ct < 4; ++ct) acc[ct] = f32x4{0.f, 0.f, 0.f, 0.f};

#pragma unroll 4
  for (int kk = 0; kk < K; kk += 32) {
    const h8 a = bch8(*reinterpret_cast<const uint4*>(xp + kk));
#pragma unroll
    for (int ct = 0; ct < 4; ++ct) {
      const h8 bfr = bch8(*reinterpret_cast<const uint4*>(wp + (size_t)ct * 16 * K + kk));
      acc[ct] = mfmah(a, bfr, acc[ct]);
    }
  }

#pragma unroll
  for (int ct = 0; ct < 4; ++ct) {
    const int co = ct * 16 + nl;
    const float bv = bias[co];
    float4 o4;
    o4.x = acc[ct][0] + bv; o4.y = acc[ct][1] + bv;
    o4.z = acc[ct][2] + bv; o4.w = acc[ct][3] + bv;
    const int idx = co * N_ + n0w + g16 * 4;
    *reinterpret_cast<float4*>(out + idx) = o4;
    if (out2) {
      out2[idx] = o4.x; out2[idx + 1] = o4.y;
      out2[idx + 2] = o4.z; out2[idx + 3] = o4.w;
    }
  }
}

// ---------------------------------------------------------------------------
// kprep: k[g][64c][1024m] -> kT[g][1024m][64c] (fp16); v[g] -> vh[g] (fp16).
// grid (24, 4)
// ---------------------------------------------------------------------------
__global__ __launch_bounds__(256) void kprep_kernel(
    const float* __restrict__ kb, const float* __restrict__ vb,
    unsigned short* __restrict__ kT, unsigned short* __restrict__ vh)
{
  const int g = blockIdx.x;
  const int ch = blockIdx.y;
  const int t = threadIdx.x;
  const float* kg = kb + (size_t)g * PLANE;
  __shared__ float tl[64][65];

#pragma unroll 1
  for (int tile = 0; tile < 4; ++tile) {
    const int m0 = ch * 256 + tile * 64;
    __syncthreads();
#pragma unroll 4
    for (int r = 0; r < 16; ++r) {
      const int c = r * 4 + (t >> 6);
      tl[c][t & 63] = kg[c * N_ + m0 + (t & 63)];
    }
    __syncthreads();
    const int mm = t >> 2, cseg = (t & 3) * 16;
    uint32 hw[8];
#pragma unroll
    for (int ii = 0; ii < 8; ++ii)
      hw[ii] = pkh(tl[cseg + 2 * ii][mm], tl[cseg + 2 * ii + 1][mm]);
    const size_t o = ((size_t)g * 1024 + m0 + mm) * 64 + cseg;
    uint4 h0; h0.x = hw[0]; h0.y = hw[1]; h0.z = hw[2]; h0.w = hw[3];
    uint4 h1; h1.x = hw[4]; h1.y = hw[5]; h1.z = hw[6]; h1.w = hw[7];
    *reinterpret_cast<uint4*>(kT + o)     = h0;
    *reinterpret_cast<uint4*>(kT + o + 8) = h1;
  }

  const float* vg = vb + (size_t)g * PLANE;
  unsigned short* vo = vh + (size_t)g * PLANE;
  for (int e8 = ch * 2048 + t; e8 < (ch + 1) * 2048; e8 += 256) {
    const float4 a = *reinterpret_cast<const float4*>(vg + (size_t)e8 * 8);
    const float4 b = *reinterpret_cast<const float4*>(vg + (size_t)e8 * 8 + 4);
    uint4 u;
    u.x = pkh(a.x, a.y); u.y = pkh(a.z, a.w);
    u.z = pkh(b.x, b.y); u.w = pkh(b.z, b.w);
    *reinterpret_cast<uint4*>(vo + (size_t)e8 * 8) = u;
  }
}

// ---------------------------------------------------------------------------
// e_cam[i,j,b][c][d] = sum_n T[i,b,c,n] * S[j,b,d,n];  also atomic raw-sum.
// ---------------------------------------------------------------------------
__global__ __launch_bounds__(256) void ecam_kernel(
    const float* __restrict__ T, const float* __restrict__ S,
    float* __restrict__ ecam, float* __restrict__ esum_cam)
{
  const int bx = blockIdx.x;
  const int b = bx & 7;
  const int j = (bx >> 3) % 3;
  const int i = bx / 24;
  const float* Tg = T + (size_t)(i * 8 + b) * PLANE;
  const float* Sg = S + (size_t)(j * 8 + b) * PLANE;
  const int t = threadIdx.x;
  __shared__ float Ts[64 * 68];
  __shared__ float Ss[64 * 68];
  __shared__ float rs[4];
  float acc[4][4] = {};
  const int c0 = (t & 15) * 4, d0 = (t >> 4) * 4;

  for (int nb = 0; nb < 1024; nb += 64) {
    __syncthreads();
    {
      const int nn = t & 63, rb = t >> 6;
#pragma unroll
      for (int r = 0; r < 16; ++r) {
        const int row = rb * 16 + r;
        Ts[nn * 68 + row] = Tg[row * N_ + nb + nn];
        Ss[nn * 68 + row] = Sg[row * N_ + nb + nn];
      }
    }
    __syncthreads();
#pragma unroll 8
    for (int nn = 0; nn < 64; ++nn) {
      const float4 tv = *reinterpret_cast<const float4*>(&Ts[nn * 68 + c0]);
      const float4 sv = *reinterpret_cast<const float4*>(&Ss[nn * 68 + d0]);
      const float ta[4] = {tv.x, tv.y, tv.z, tv.w};
      const float sa[4] = {sv.x, sv.y, sv.z, sv.w};
#pragma unroll
      for (int ci = 0; ci < 4; ++ci)
#pragma unroll
        for (int di = 0; di < 4; ++di)
          acc[ci][di] = fmaf(ta[ci], sa[di], acc[ci][di]);
    }
  }
  float s = 0.f;
#pragma unroll
  for (int ci = 0; ci < 4; ++ci)
#pragma unroll
    for (int di = 0; di < 4; ++di) s += acc[ci][di];
  s = wred_sum(s);
  if ((t & 63) == 0) rs[t >> 6] = s;
  __syncthreads();
  if (t == 0) atomicAdd(esum_cam + i * 3 + j, rs[0] + rs[1] + rs[2] + rs[3]);

  float* eo = ecam + (size_t)((i * 3 + j) * 8 + b) * 4096;
#pragma unroll
  for (int ci = 0; ci < 4; ++ci) {
    float4 o4; o4.x = acc[ci][0]; o4.y = acc[ci][1]; o4.z = acc[ci][2]; o4.w = acc[ci][3];
    *reinterpret_cast<float4*>(eo + (c0 + ci) * 64 + d0) = o4;
  }
}

// ---------------------------------------------------------------------------
// attn_cam[i,b][c][d] = sum_j softmax_d(e_cam[i,j,b,c,:])[d]     grid 24
// ---------------------------------------------------------------------------
__global__ __launch_bounds__(256) void acam_kernel(
    const float* __restrict__ ecam, float* __restrict__ acam)
{
  const int bx = blockIdx.x;
  const int b = bx & 7, i = bx >> 3;
  const int t = threadIdx.x;
  const int c = t >> 2, seg = t & 3;
  float acc[16] = {};
#pragma unroll
  for (int j = 0; j < 3; ++j) {
    const float* e = ecam + (size_t)((i * 3 + j) * 8 + b) * 4096 + c * 64 + seg * 16;
    float ev[16];
#pragma unroll
    for (int r = 0; r < 4; ++r) {
      const float4 v4 = *reinterpret_cast<const float4*>(e + r * 4);
      ev[4 * r] = v4.x; ev[4 * r + 1] = v4.y; ev[4 * r + 2] = v4.z; ev[4 * r + 3] = v4.w;
    }
    float mx = ev[0];
#pragma unroll
    for (int r = 1; r < 16; ++r) mx = fmaxf(mx, ev[r]);
    mx = fmaxf(mx, __shfl_xor(mx, 1, 4));
    mx = fmaxf(mx, __shfl_xor(mx, 2, 4));
    float pv[16], ss = 0.f;
#pragma unroll
    for (int r = 0; r < 16; ++r) { pv[r] = __expf(ev[r] - mx); ss += pv[r]; }
    ss += __shfl_xor(ss, 1, 4);
    ss += __shfl_xor(ss, 2, 4);
    const float rc = 1.f / ss;
#pragma unroll
    for (int r = 0; r < 16; ++r) acc[r] += pv[r] * rc;
  }
  float* ao = acam + (size_t)(i * 8 + b) * 4096 + c * 64 + seg * 16;
#pragma unroll
  for (int r = 0; r < 4; ++r) {
    float4 o4; o4.x = acc[4 * r]; o4.y = acc[4 * r + 1]; o4.z = acc[4 * r + 2]; o4.w = acc[4 * r + 3];
    *reinterpret_cast<float4*>(ao + r * 4) = o4;
  }
}

// ---------------------------------------------------------------------------
// PAM via single-pass fp16 MFMA. grid 1536 = (i, b, qt), 512 threads (8 waves
// x 128 m). QK tt loop fully unrolled: 16 loads in flight.
// ---------------------------------------------------------------------------
__global__ __launch_bounds__(512, 4) void pam_mfma_kernel(
    const float* __restrict__ q, const unsigned short* __restrict__ kT,
    const unsigned short* __restrict__ vh,
    const float* __restrict__ ocam, float* __restrict__ tgts, float* __restrict__ esum_pam)
{
  const int bx = blockIdx.x;
  const int qt = bx & 63;
  const int b  = (bx >> 6) & 7;
  const int i  = bx >> 9;
  const int n0 = qt * 16;
  const int t = threadIdx.x;
  const int lane = t & 63;
  const int wv = t >> 6;             // 0..7
  const int nl = lane & 15;
  const int g16 = lane >> 4;

  __shared__ unsigned short Plds[16 * 1024];  // 32 KB fp16, [n][m ^ (8n)]
  __shared__ float qlds[64 * 17];             // q staging; aliased as osum later
  __shared__ float redmx[128];
  __shared__ float redse[128];
  __shared__ float redes[8];
  float* osum = qlds;

  const size_t ibo = (size_t)(i * 8 + b) * PLANE;

  const float* qg = q + ibo;
  for (int e = t; e < 1024; e += 512)
    qlds[(e >> 4) * 17 + (e & 15)] = qg[(e >> 4) * N_ + n0 + (e & 15)];
  __syncthreads();

  h8 qh[2];
#pragma unroll
  for (int ks = 0; ks < 2; ++ks) {
#pragma unroll
    for (int idx = 0; idx < 8; ++idx)
      qh[ks][idx] = (_Float16)qlds[(ks * 32 + g16 * 8 + idx) * 17 + nl];
  }

  const int wm0 = wv * 128;
  const int ct = wv & 3;
  const int mh = wv >> 2;
  const unsigned short* vg = vh + ibo + (size_t)(ct * 16 + nl) * 1024 + mh * 512 + g16 * 8;
  f32x4 oat = f32x4{0.f, 0.f, 0.f, 0.f};

#pragma unroll 1
  for (int j = 0; j < 3; ++j) {
    const unsigned short* kp =
        kT + ((size_t)(j * 8 + b) * 1024 + wm0 + nl) * 64 + g16 * 8;

    f32x4 l4[8];
#pragma unroll
    for (int tt = 0; tt < 8; ++tt) {
      const int off = tt * 1024;
      const uint4 k0 = *reinterpret_cast<const uint4*>(kp + off);
      const uint4 k1 = *reinterpret_cast<const uint4*>(kp + off + 32);
      f32x4 a = f32x4{0.f, 0.f, 0.f, 0.f};
      a = mfmah(bch8(k0), qh[0], a);
      a = mfmah(bch8(k1), qh[1], a);
      l4[tt] = a;
    }

    float pm = -3.4e38f, es = 0.f;
#pragma unroll
    for (int tt = 0; tt < 8; ++tt) {
#pragma unroll
      for (int r = 0; r < 4; ++r) { pm = fmaxf(pm, l4[tt][r]); es += l4[tt][r]; }
    }
    pm = fmaxf(pm, __shfl_xor(pm, 16, 64));
    pm = fmaxf(pm, __shfl_xor(pm, 32, 64));
    es = wred_sum(es);
    if (lane < 16) redmx[wv * 16 + lane] = pm;
    if (lane == 0) redes[wv] = es;
    __syncthreads();
    float mx = redmx[nl];
#pragma unroll
    for (int w = 1; w < 8; ++w) mx = fmaxf(mx, redmx[w * 16 + nl]);
    if (t == 0) {
      float s = 0.f;
#pragma unroll
      for (int w = 0; w < 8; ++w) s += redes[w];
      atomicAdd(esum_pam + i * 3 + j, s);
    }

    float ps = 0.f;
#pragma unroll
    for (int tt = 0; tt < 8; ++tt) {
#pragma unroll
      for (int r = 0; r < 4; ++r) {
        l4[tt][r] = __expf(l4[tt][r] - mx);
        ps += l4[tt][r];
      }
    }
#pragma unroll
    for (int tt = 0; tt < 8; ++tt) {
      const int m = wm0 + tt * 16 + g16 * 4;
      uint2 w2;
      w2.x = pkh(l4[tt][0], l4[tt][1]);
      w2.y = pkh(l4[tt][2], l4[tt][3]);
      *reinterpret_cast<uint2*>(&Plds[nl * 1024 + (m ^ (nl * 8))]) = w2;
    }
    ps += __shfl_xor(ps, 16, 64);
    ps += __shfl_xor(ps, 32, 64);
    if (lane < 16) redse[wv * 16 + lane] = ps;
    __syncthreads();
    float den = redse[nl];
#pragma unroll
    for (int w = 1; w < 8; ++w) den += redse[w * 16 + nl];
    const float rs = 1.f / den;

    f32x4 oa = f32x4{0.f, 0.f, 0.f, 0.f};
    f32x4 ob = f32x4{0.f, 0.f, 0.f, 0.f};
#pragma unroll 4
    for (int ks = 0; ks < 16; ks += 2) {
      const int ml0 = mh * 512 + ks * 32 + g16 * 8;
      const int ml1 = ml0 + 32;
      const uint4 va0 = *reinterpret_cast<const uint4*>(vg + ks * 32);
      const uint4 pf0 = *reinterpret_cast<const uint4*>(&Plds[nl * 1024 + (ml0 ^ (nl * 8))]);
      const uint4 va1 = *reinterpret_cast<const uint4*>(vg + ks * 32 + 32);
      const uint4 pf1 = *reinterpret_cast<const uint4*>(&Plds[nl * 1024 + (ml1 ^ (nl * 8))]);
      oa = mfmah(bch8(va0), bch8(pf0), oa);
      ob = mfmah(bch8(va1), bch8(pf1), ob);
    }
#pragma unroll
    for (int r = 0; r < 4; ++r) oat[r] += rs * (oa[r] + ob[r]);
  }

  if (mh == 0) {
#pragma unroll
    for (int r = 0; r < 4; ++r)
      osum[(ct * 16 + g16 * 4 + r) * 16 + nl] = oat[r];
  }
  __syncthreads();
  if (mh == 1) {
    const float* og = ocam + ibo;
    float* outg = tgts + (size_t)(2 * i * 8 + b) * PLANE;
#pragma unroll
    for (int r = 0; r < 4; ++r) {
      const int c = ct * 16 + g16 * 4 + r;
      const int idx = c * N_ + n0 + nl;
      outg[idx] = 0.5f * (oat[r] + osum[c * 16 + nl] + og[idx]);
    }
  }
}

// ---------------------------------------------------------------------------
// alpha[i][j] = 0.5*(softmax_j(mean e_pam) + softmax_j(mean e_cam))
// ---------------------------------------------------------------------------
__global__ void alpha_kernel(const float* __restrict__ esum, float* __restrict__ alpha)
{
  const int t = threadIdx.x;
  if (t >= 9) return;
  const int i = t / 3, j = t % 3;
  float p[3], c[3];
#pragma unroll
  for (int jj = 0; jj < 3; ++jj) {
    p[jj] = esum[i * 3 + jj] * (1.0f / 8388608.0f);
    c[jj] = esum[9 + i * 3 + jj] * (1.0f / 32768.0f);
  }
  const float mp = fmaxf(p[0], fmaxf(p[1], p[2]));
  const float mc = fmaxf(c[0], fmaxf(c[1], c[2]));
  float sp = 0.f, sc = 0.f;
#pragma unroll
  for (int jj = 0; jj < 3; ++jj) { sp += __expf(p[jj] - mp); sc += __expf(c[jj] - mc); }
  alpha[t] = 0.5f * (__expf(p[j] - mp) / sp + __expf(c[j] - mc) / sc);
}

// ---------------------------------------------------------------------------
extern "C" void kernel_launch(void* const* d_in, const int* in_sizes, int n_in,
                              void* d_out, int out_size, void* d_ws, size_t ws_size,
                              hipStream_t stream)
{
  const float* src0 = (const float*)d_in[0];
  const float* src1 = (const float*)d_in[1];
  const float* src2 = (const float*)d_in[2];
  const float* tgt0 = (const float*)d_in[3];
  const float* tgt1 = (const float*)d_in[4];
  const float* tgt2 = (const float*)d_in[5];
  const float* fs0_w = (const float*)d_in[6];  const float* fs0_b = (const float*)d_in[7];
  const float* fs1_w = (const float*)d_in[8];  const float* fs1_b = (const float*)d_in[9];
  const float* fs2_w = (const float*)d_in[10]; const float* fs2_b = (const float*)d_in[11];
  const float* ft0_w = (const float*)d_in[12]; const float* ft0_b = (const float*)d_in[13];
  const float* ft1_w = (const float*)d_in[14]; const float* ft1_b = (const float*)d_in[15];
  const float* ft2_w = (const float*)d_in[16]; const float* ft2_b = (const float*)d_in[17];
  const float* pq_w = (const float*)d_in[18];  const float* pq_b = (const float*)d_in[19];
  const float* pk_w = (const float*)d_in[20];  const float* pk_b = (const float*)d_in[21];
  const float* pv_w = (const float*)d_in[22];  const float* pv_b = (const float*)d_in[23];
  const float* cv_w = (const float*)d_in[24];  const float* cv_b = (const float*)d_in[25];

  float* out = (float*)d_out;
  float* S     = out;                 // srcs region doubles as S storage
  float* alpha = out + SZ;            // 9 floats
  float* tgts  = out + SZ + 9;        // [2L][B][PLANE]

  float* ws   = (float*)d_ws;
  float* T    = ws;
  float* qb   = ws + (size_t)SZ;
  float* kb   = ws + (size_t)2 * SZ;
  float* vb   = ws + (size_t)3 * SZ;
  float* vcb  = ws + (size_t)4 * SZ;
  float* ocam = ws + (size_t)5 * SZ;
  float* ecam = ws + (size_t)6 * SZ;                 // 294912
  float* acam = ws + (size_t)6 * SZ + 294912;        // 98304
  float* esum = ws + (size_t)6 * SZ + 393216;        // 18 (pam 9, cam 9)

  // fp16 buffers appended after the fp32 region
  unsigned short* kT = (unsigned short*)(ws + (size_t)6 * SZ + 393216 + 256);
  unsigned short* vh = kT + (size_t)24 * PLANE;
  unsigned short* wh = vh + (size_t)24 * PLANE;      // 98304 ushorts
  unsigned short* w9s = wh + 98304;                  // 73728 ushorts
  unsigned short* w9t = w9s + 73728;

  // Overlays in qb..vcb (each consumed before the next producer writes):
  // 1) inTs/inTt (channels-last fp16 conv inputs), consumed by conv0_mfma
  unsigned short* inTs = (unsigned short*)qb;        // 8*4096*128
  unsigned short* inTt = inTs + 4194304;
  // 2) Xh (fp16 transposed fit-GEMM inputs), consumed by gemmh
  unsigned short* Xs1 = (unsigned short*)qb;         // 8x1024x256
  unsigned short* Xs2 = Xs1 + 2097152;               // 8x1024x512
  unsigned short* Xt1 = Xs1 + 6291456;               // 8x1024x256
  unsigned short* Xt2 = Xs1 + 8388608;               // 8x1024x512

  hipMemsetAsync(esum, 0, 18 * sizeof(float), stream);

  // conv0 via MFMA: channels-last fp16 inputs + fp16 tap weights
  w9conv_kernel<<<576, 256, 0, stream>>>(fs0_w, ft0_w, w9s, w9t);
  xprep_kernel<<<dim3(8, 2, 64), 256, 0, stream>>>(src0, inTs, 128, 4096);
  xprep_kernel<<<dim3(8, 2, 64), 256, 0, stream>>>(tgt0, inTt, 128, 4096);
  conv0_mfma_kernel<<<dim3(32, 8, 2), 256, 0, stream>>>(
      inTs, inTt, w9s, w9t, fs0_b, ft0_b, S, T, tgts + (size_t)1 * BPL);

  // fp16 fit GEMMs (overwrite the inT overlay with Xh)
  xprep_kernel<<<dim3(8, 4, 16), 256, 0, stream>>>(src1, Xs1, 256, 1024);
  xprep_kernel<<<dim3(8, 8, 16), 256, 0, stream>>>(src2, Xs2, 512, 1024);
  xprep_kernel<<<dim3(8, 4, 16), 256, 0, stream>>>(tgt1, Xt1, 256, 1024);
  xprep_kernel<<<dim3(8, 8, 16), 256, 0, stream>>>(tgt2, Xt2, 512, 1024);
  whconv_kernel<<<192, 256, 0, stream>>>(fs1_w, fs2_w, ft1_w, ft2_w, wh);
  gemmh_kernel<<<dim3(16, 16), 256, 0, stream>>>(
      Xs1, Xt1, wh, wh + 49152, fs1_b, ft1_b,
      S + BPL, T + BPL, tgts + (size_t)3 * BPL, 256);
  gemmh_kernel<<<dim3(16, 16), 256, 0, stream>>>(
      Xs2, Xt2, wh + 16384, wh + 65536, fs2_b, ft2_b,
      S + 2 * BPL, T + 2 * BPL, tgts + (size_t)5 * BPL, 512);

  // All 4 projections in one launch (writes qb..vcb, overwriting the overlay)
  proj_kernel<<<dim3(24, 16, 4), 256, 0, stream>>>(
      T, S, pq_w, pk_w, pv_w, cv_w, pq_b, pk_b, pv_b, cv_b, qb);

  // Pack k (transposed fp16) and v (fp16) for the MFMA attention
  kprep_kernel<<<dim3(24, 4), 256, 0, stream>>>(kb, vb, kT, vh);

  // CAM
  ecam_kernel<<<72, 256, 0, stream>>>(T, S, ecam, esum + 9);
  acam_kernel<<<24, 256, 0, stream>>>(ecam, acam);
  gemm64_kernel<<<dim3(24, 16), 256, 0, stream>>>(acam, 4096, 1, vcb, PLANE, ocam, PLANE,
                                                  nullptr, 0, 64);

  // PAM + fuse (writes tgts even slots = 0.5*(out_pam + out_cam))
  pam_mfma_kernel<<<1536, 512, 0, stream>>>(qb, kT, vh, ocam, tgts, esum);

  alpha_kernel<<<1, 64, 0, stream>>>(esum, alpha);
}